// Round 3
// baseline (3609.073 us; speedup 1.0000x reference)
//
#include <hip/hip_runtime.h>
#include <hip/hip_bf16.h>

typedef unsigned short u16;
typedef unsigned int   u32;

// ---------- bf16 helpers ----------
__device__ __forceinline__ float b2f(u16 u) { return __uint_as_float(((u32)u) << 16); }
__device__ __forceinline__ u16 f2b(float f) {
    u32 u = __float_as_uint(f);
    u += 0x7FFF + ((u >> 16) & 1);   // RTNE
    return (u16)(u >> 16);
}
__device__ __forceinline__ void unpack8(uint4 p, float* f) {
    u32 w[4] = {p.x, p.y, p.z, p.w};
#pragma unroll
    for (int q = 0; q < 4; q++) {
        f[2*q]   = b2f((u16)(w[q] & 0xFFFFu));
        f[2*q+1] = b2f((u16)(w[q] >> 16));
    }
}
__device__ __forceinline__ void unpack4(uint2 p, float* f) {
    f[0] = b2f((u16)(p.x & 0xFFFF)); f[1] = b2f((u16)(p.x >> 16));
    f[2] = b2f((u16)(p.y & 0xFFFF)); f[3] = b2f((u16)(p.y >> 16));
}

// ---------- LayerNorm (row = 1024 fp32 elems, 256 threads) ----------
template<bool OUT_BF16>
__global__ __launch_bounds__(256) void ln_k(const float* __restrict__ X,
                                            const float* __restrict__ w,
                                            const float* __restrict__ bb,
                                            void* __restrict__ out) {
    const long row = blockIdx.x;
    const int t = threadIdx.x;
    float4 p = ((const float4*)(X + row * 1024))[t];
    float x[4] = { p.x, p.y, p.z, p.w };
    float s = x[0]+x[1]+x[2]+x[3];
    float q = x[0]*x[0]+x[1]*x[1]+x[2]*x[2]+x[3]*x[3];
#pragma unroll
    for (int o = 32; o > 0; o >>= 1) { s += __shfl_down(s, o, 64); q += __shfl_down(q, o, 64); }
    __shared__ float aS[4], aQ[4];
    if ((t & 63) == 0) { aS[t >> 6] = s; aQ[t >> 6] = q; }
    __syncthreads();
    s = aS[0]+aS[1]+aS[2]+aS[3];
    q = aQ[0]+aQ[1]+aQ[2]+aQ[3];
    float mean = s * (1.f/1024.f);
    float var  = q * (1.f/1024.f) - mean*mean;
    float rstd = rsqrtf(var + 1e-5f);
    float4 wv = ((const float4*)w)[t];
    float4 bv = ((const float4*)bb)[t];
    float y[4];
    y[0] = (x[0]-mean)*rstd*wv.x + bv.x;
    y[1] = (x[1]-mean)*rstd*wv.y + bv.y;
    y[2] = (x[2]-mean)*rstd*wv.z + bv.z;
    y[3] = (x[3]-mean)*rstd*wv.w + bv.w;
    if (OUT_BF16) {
        uint2 r;
        r.x = (u32)f2b(y[0]) | ((u32)f2b(y[1]) << 16);
        r.y = (u32)f2b(y[2]) | ((u32)f2b(y[3]) << 16);
        ((uint2*)((u16*)out + row * 1024))[t] = r;
    } else {
        ((float4*)((float*)out + row * 1024))[t] = make_float4(y[0], y[1], y[2], y[3]);
    }
}

// ---------- generic 128x128 tiled GEMM, fp32 accumulate ----------
// A: ours (fp32 or bf16, compile-time). B/bias/resid: fp32.
// C addr = z*czStride + (r/RPB)*cbStride + (r%RPB)*rowStride + col
enum { EPI_NONE = 0, EPI_RESID = 1, EPI_GELU_BIAS = 2, EPI_BIAS_RESID = 3 };

template<int EPI, bool OUT_BF16, bool A_BF16>
__global__ __launch_bounds__(256) void gemm128(
    const void* __restrict__ Av, const float* __restrict__ Bv, void* __restrict__ Cv,
    int M, int N, int K,
    long bzStride, long czStride, long cbStride, int rowStride, int RPB,
    const float* __restrict__ bias, const float* __restrict__ resid) {
    __shared__ float As[16][132];
    __shared__ float Bs[16][132];
    const int t = threadIdx.x;
    const int nb = blockIdx.x, mb = blockIdx.y, z = blockIdx.z;
    const int row0 = mb * 128, col0 = nb * 128;
    const int tx = t & 15, ty = t >> 4;
    const int ar = t >> 1, ak = (t & 1) * 8;
    const int bk = t >> 4, bc = (t & 15) * 8;

    float acc[8][8];
#pragma unroll
    for (int i = 0; i < 8; i++)
#pragma unroll
        for (int j = 0; j < 8; j++) acc[i][j] = 0.f;

    for (int k0 = 0; k0 < K; k0 += 16) {
        float af[8], bf8v[8];
        long aoff = (long)(row0 + ar) * K + (k0 + ak);
        if (A_BF16) {
            uint4 ap = *(const uint4*)((const u16*)Av + aoff);
            unpack8(ap, af);
        } else {
            const float* Af = (const float*)Av + aoff;
            float4 a0 = *(const float4*)Af;
            float4 a1 = *(const float4*)(Af + 4);
            af[0]=a0.x; af[1]=a0.y; af[2]=a0.z; af[3]=a0.w;
            af[4]=a1.x; af[5]=a1.y; af[6]=a1.z; af[7]=a1.w;
        }
        {
            const float* Bf = Bv + (long)z * bzStride + (long)(k0 + bk) * N + (col0 + bc);
            float4 b0 = *(const float4*)Bf;
            float4 b1 = *(const float4*)(Bf + 4);
            bf8v[0]=b0.x; bf8v[1]=b0.y; bf8v[2]=b0.z; bf8v[3]=b0.w;
            bf8v[4]=b1.x; bf8v[5]=b1.y; bf8v[6]=b1.z; bf8v[7]=b1.w;
        }
#pragma unroll
        for (int i = 0; i < 8; i++) As[ak + i][ar] = af[i];
        *(float4*)&Bs[bk][bc]     = make_float4(bf8v[0], bf8v[1], bf8v[2], bf8v[3]);
        *(float4*)&Bs[bk][bc + 4] = make_float4(bf8v[4], bf8v[5], bf8v[6], bf8v[7]);
        __syncthreads();
#pragma unroll
        for (int kk = 0; kk < 16; kk++) {
            float4 a0 = *(const float4*)&As[kk][ty * 4];
            float4 a1 = *(const float4*)&As[kk][64 + ty * 4];
            float4 b0 = *(const float4*)&Bs[kk][tx * 4];
            float4 b1 = *(const float4*)&Bs[kk][64 + tx * 4];
            float av[8] = {a0.x, a0.y, a0.z, a0.w, a1.x, a1.y, a1.z, a1.w};
            float bv[8] = {b0.x, b0.y, b0.z, b0.w, b1.x, b1.y, b1.z, b1.w};
#pragma unroll
            for (int i = 0; i < 8; i++)
#pragma unroll
                for (int j = 0; j < 8; j++)
                    acc[i][j] = fmaf(av[i], bv[j], acc[i][j]);
        }
        __syncthreads();
    }

#pragma unroll
    for (int i = 0; i < 8; i++) {
        int r = row0 + ((i < 4) ? (ty * 4 + i) : (64 + ty * 4 + (i - 4)));
        long cbase = (long)z * czStride + (long)(r / RPB) * cbStride + (long)(r % RPB) * rowStride;
#pragma unroll
        for (int half = 0; half < 2; half++) {
            int c0 = col0 + half * 64 + tx * 4;
            float v4[4];
#pragma unroll
            for (int j = 0; j < 4; j++) {
                float v = acc[i][half * 4 + j];
                int c = c0 + j;
                if constexpr (EPI == EPI_RESID) {
                    v += resid[(long)r * N + c];
                } else if constexpr (EPI == EPI_GELU_BIAS) {
                    v += bias[c];
                    v = 0.5f * v * (1.f + erff(v * 0.70710678118654752f));
                } else if constexpr (EPI == EPI_BIAS_RESID) {
                    v += bias[c] + resid[(long)r * N + c];
                }
                v4[j] = v;
            }
            if constexpr (OUT_BF16) {
                uint2 pk;
                pk.x = (u32)f2b(v4[0]) | ((u32)f2b(v4[1]) << 16);
                pk.y = (u32)f2b(v4[2]) | ((u32)f2b(v4[3]) << 16);
                *(uint2*)((u16*)Cv + cbase + c0) = pk;
            } else {
                *(float4*)((float*)Cv + cbase + c0) = make_float4(v4[0], v4[1], v4[2], v4[3]);
            }
        }
    }
}

// ---------- xPos rotary (in-place on fp32 (B,H,S,128)) ----------
__global__ __launch_bounds__(256) void xpos_kernel(float* __restrict__ X, int downscale) {
    long idx = (long)blockIdx.x * 256 + threadIdx.x;   // B*H*S*64 pairs
    int j = (int)(idx & 63);
    int s = (int)((idx >> 6) & 2047);
    long bh = idx >> 17;
    float* p = X + (bh * 2048 + s) * 128 + 2 * j;
    float2 xv = *(float2*)p;
    float sv = (2.f * j + 51.2f) / 179.2f;            // (2j + 0.4*128)/(1.4*128)
    float scale = exp2f(log2f(sv) * ((float)s * (1.f / 512.f)));
    if (downscale) scale = 1.f / scale;
    float inv_freq = exp2f((float)j * (-13.287712379549449f / 64.f)); // 10000^{-j/64}
    float ang = (float)s * inv_freq;
    float sn = sinf(ang) * scale;
    float cs = cosf(ang) * scale;
    float y0 = xv.x * cs - xv.y * sn;
    float y1 = xv.y * cs + xv.x * sn;
    *(float2*)p = make_float2(y0, y1);
}

// ---------- streaming causal retention + fused per-head groupnorm ----------
// grid (S/32, H, B); block 256.  Q,K fp32 (B,H,S,128); V bf16 (B,H,S,256)
__global__ __launch_bounds__(256) void retention_kernel(
    const float* __restrict__ Q, const float* __restrict__ Kb,
    const u16* __restrict__ V, const float* __restrict__ gnw, const float* __restrict__ gnb,
    u16* __restrict__ Yn) {
    const int tile = blockIdx.x;
    const int h = blockIdx.y;
    const int b = blockIdx.z;
    __shared__ float Qs[32][132];
    __shared__ float Ks[32][132];
    __shared__ u16   Vs[32][264];
    __shared__ float sc[32][36];
    __shared__ float redS[32][8], redQ[32][8];
    const int t = threadIdx.x;
    const int ty = t >> 3, tx = t & 7;

    float g = 1.f - expf(-3.4657359027997265f + (-0.3960841031771116f) * (float)h);
    float log2g = log2f(g);

    const long bh = (long)b * 8 + h;
    const float* Qbase = Q + bh * 2048 * 128;
    const float* Kbase = Kb + bh * 2048 * 128;
    const u16* Vbase = V + bh * 2048 * 256;

    for (int i = t; i < 1024; i += 256) {
        int r = i >> 5, c4 = i & 31;
        *(float4*)&Qs[r][c4 * 4] = *(const float4*)(Qbase + (long)(tile * 32 + r) * 128 + c4 * 4);
    }

    float4 acc4[8];
#pragma unroll
    for (int i = 0; i < 8; i++) acc4[i] = make_float4(0.f, 0.f, 0.f, 0.f);

    for (int jt = 0; jt <= tile; jt++) {
        for (int i = t; i < 1024; i += 256) {
            int r = i >> 5, c4 = i & 31;
            *(float4*)&Ks[r][c4 * 4] = *(const float4*)(Kbase + (long)(jt * 32 + r) * 128 + c4 * 4);
        }
        for (int i = t; i < 1024; i += 256) {
            int r = i >> 5, pk = i & 31;
            uint4 pv = *(const uint4*)(Vbase + (long)(jt * 32 + r) * 256 + pk * 8);
            *(uint4*)&Vs[r][pk * 8] = pv;
        }
        __syncthreads();
        // scores: thread computes row ty, cols tx*4..tx*4+3
        {
            int c0 = tx * 4;
            float d0 = 0, d1 = 0, d2 = 0, d3 = 0;
            for (int k4 = 0; k4 < 32; k4++) {
                float4 qv  = *(const float4*)&Qs[ty][k4 * 4];
                float4 k0v = *(const float4*)&Ks[c0 + 0][k4 * 4];
                float4 k1v = *(const float4*)&Ks[c0 + 1][k4 * 4];
                float4 k2v = *(const float4*)&Ks[c0 + 2][k4 * 4];
                float4 k3v = *(const float4*)&Ks[c0 + 3][k4 * 4];
                d0 += qv.x*k0v.x + qv.y*k0v.y + qv.z*k0v.z + qv.w*k0v.w;
                d1 += qv.x*k1v.x + qv.y*k1v.y + qv.z*k1v.z + qv.w*k1v.w;
                d2 += qv.x*k2v.x + qv.y*k2v.y + qv.z*k2v.z + qv.w*k2v.w;
                d3 += qv.x*k3v.x + qv.y*k3v.y + qv.z*k3v.z + qv.w*k3v.w;
            }
            int srow = tile * 32 + ty;
            float dd[4] = {d0, d1, d2, d3};
#pragma unroll
            for (int j2 = 0; j2 < 4; j2++) {
                int tcol = jt * 32 + c0 + j2;
                float wgt = (tcol <= srow) ? exp2f(log2g * (float)(srow - tcol)) : 0.f;
                sc[ty][c0 + j2] = dd[j2] * wgt;
            }
        }
        __syncthreads();
        // PV: thread owns v-cols {i*32 + tx*4 .. +3}, i=0..7
        for (int c = 0; c < 32; c++) {
            float s = sc[ty][c];
#pragma unroll
            for (int i = 0; i < 8; i++) {
                uint2 pv = *(const uint2*)&Vs[c][i * 32 + tx * 4];
                float f[4];
                unpack4(pv, f);
                acc4[i].x = fmaf(s, f[0], acc4[i].x);
                acc4[i].y = fmaf(s, f[1], acc4[i].y);
                acc4[i].z = fmaf(s, f[2], acc4[i].z);
                acc4[i].w = fmaf(s, f[3], acc4[i].w);
            }
        }
        __syncthreads();
    }

    // groupnorm over the 256 values of row ty (8 threads x 32 vals)
    float s = 0.f, q = 0.f;
#pragma unroll
    for (int i = 0; i < 8; i++) {
        s += acc4[i].x + acc4[i].y + acc4[i].z + acc4[i].w;
        q += acc4[i].x*acc4[i].x + acc4[i].y*acc4[i].y + acc4[i].z*acc4[i].z + acc4[i].w*acc4[i].w;
    }
    redS[ty][tx] = s; redQ[ty][tx] = q;
    __syncthreads();
    float S = 0.f, Qq = 0.f;
#pragma unroll
    for (int i = 0; i < 8; i++) { S += redS[ty][i]; Qq += redQ[ty][i]; }
    float mean = S * (1.f / 256.f);
    float var  = Qq * (1.f / 256.f) - mean * mean;
    float rstd = rsqrtf(var + 1e-5f);
    long orow = ((long)b * 2048 + tile * 32 + ty) * 2048 + h * 256;
#pragma unroll
    for (int i = 0; i < 8; i++) {
        int v0 = i * 32 + tx * 4;
        float vals[4] = {acc4[i].x, acc4[i].y, acc4[i].z, acc4[i].w};
        u16 ob[4];
#pragma unroll
        for (int j = 0; j < 4; j++) {
            int vc = v0 + j;
            float y = (vals[j] - mean) * rstd * gnw[h * 256 + vc] + gnb[h * 256 + vc];
            ob[j] = f2b(y);
        }
        uint2 pk;
        pk.x = (u32)ob[0] | ((u32)ob[1] << 16);
        pk.y = (u32)ob[2] | ((u32)ob[3] << 16);
        *(uint2*)(Yn + orow + v0) = pk;
    }
}

// ---------- gated = G*sigmoid(G)*Yn, in-place on G (both bf16) ----------
__global__ __launch_bounds__(256) void gate_kernel(u16* __restrict__ G, const u16* __restrict__ Y) {
    long i = ((long)blockIdx.x * 256 + threadIdx.x) * 4;
    uint2 gp = *(const uint2*)(G + i);
    uint2 yp = *(const uint2*)(Y + i);
    float gv[4], yv[4];
    unpack4(gp, gv);
    unpack4(yp, yv);
    u16 ob[4];
#pragma unroll
    for (int j = 0; j < 4; j++) {
        float g = gv[j];
        float sg = 1.f / (1.f + expf(-g));
        ob[j] = f2b(g * sg * yv[j]);
    }
    uint2 r;
    r.x = (u32)ob[0] | ((u32)ob[1] << 16);
    r.y = (u32)ob[2] | ((u32)ob[3] << 16);
    *(uint2*)(G + i) = r;
}

extern "C" void kernel_launch(void* const* d_in, const int* in_sizes, int n_in,
                              void* d_out, int out_size, void* d_ws, size_t ws_size,
                              hipStream_t stream) {
    (void)in_sizes; (void)n_in; (void)out_size; (void)ws_size;
    const float* X    = (const float*)d_in[0];
    const float* Wq   = (const float*)d_in[1];
    const float* Wk   = (const float*)d_in[2];
    const float* Wv   = (const float*)d_in[3];
    const float* WG   = (const float*)d_in[4];
    const float* WO   = (const float*)d_in[5];
    const float* gnw  = (const float*)d_in[6];
    const float* gnb  = (const float*)d_in[7];
    const float* ln1w = (const float*)d_in[8];
    const float* ln1b = (const float*)d_in[9];
    const float* ln2w = (const float*)d_in[10];
    const float* ln2b = (const float*)d_in[11];
    const float* fw1  = (const float*)d_in[12];
    const float* fb1  = (const float*)d_in[13];
    const float* fw2  = (const float*)d_in[14];
    const float* fb2  = (const float*)d_in[15];

    constexpr int S = 2048, D = 1024, H = 8, DK = 128, DV = 256, VD = 2048, FFN = 4096;
    constexpr int M = 2 * S; // 4096 rows (b,s)
    constexpr long MB = 1048576;

    char* ws = (char*)d_ws;
    // layout (96 MB peak), lifetime-based reuse:
    float* Xn   = (float*)(ws);            // [0,16)  fp32 LN1 out   [1..5]
    float* Qf   = (float*)(ws + 16*MB);    // [16,32) fp32           [2..7]
    float* Kf   = (float*)(ws + 32*MB);    // [32,48) fp32           [3..7]
    u16*   Vb   = (u16*)  (ws + 48*MB);    // [48,64) bf16           [4..7]
    u16*   Gb   = (u16*)  (ws + 64*MB);    // [64,80) bf16           [5..9]
    u16*   Ynb  = (u16*)  (ws + 80*MB);    // [80,96) bf16           [7..8]
    float* X2   = (float*)(ws + 16*MB);    // reuse Qf               [9..12]
    u16*   hb   = (u16*)  (ws);            // reuse Xn               [10..11]
    u16*   mid  = (u16*)  (ws + 32*MB);    // reuse Kf+Vb (32MB)     [11..12]

    // 1. LN1 (fp32 out)
    ln_k<false><<<M, 256, 0, stream>>>(X, ln1w, ln1b, Xn);
    // 2-4. Q, K fp32 (B,H,S,DK); V bf16 (B,H,S,DV)
    gemm128<EPI_NONE, false, false><<<dim3(1, 32, 8), 256, 0, stream>>>(
        Xn, Wq, Qf, M, DK, D, (long)D * DK, (long)S * DK, (long)H * S * DK, DK, S, nullptr, nullptr);
    gemm128<EPI_NONE, false, false><<<dim3(1, 32, 8), 256, 0, stream>>>(
        Xn, Wk, Kf, M, DK, D, (long)D * DK, (long)S * DK, (long)H * S * DK, DK, S, nullptr, nullptr);
    gemm128<EPI_NONE, true, false><<<dim3(2, 32, 8), 256, 0, stream>>>(
        Xn, Wv, Vb, M, DV, D, (long)D * DV, (long)S * DV, (long)H * S * DV, DV, S, nullptr, nullptr);
    // 5. G = Xn @ W_G (bf16 (B,S,VD))
    gemm128<EPI_NONE, true, false><<<dim3(16, 32, 1), 256, 0, stream>>>(
        Xn, WG, Gb, M, VD, D, 0, 0, 0, VD, M, nullptr, nullptr);
    // 6. xPos on Q (up) and K (down)
    xpos_kernel<<<8192, 256, 0, stream>>>(Qf, 0);
    xpos_kernel<<<8192, 256, 0, stream>>>(Kf, 1);
    // 7. retention + groupnorm -> Ynb (B,S,VD) bf16
    retention_kernel<<<dim3(64, 8, 2), 256, 0, stream>>>(Qf, Kf, Vb, gnw, gnb, Ynb);
    // 8. gated = silu(G) * Yn (in place on G)
    gate_kernel<<<8192, 256, 0, stream>>>(Gb, Ynb);
    // 9. X2 = gated @ W_O + X  (fp32)
    gemm128<EPI_RESID, false, true><<<dim3(8, 32, 1), 256, 0, stream>>>(
        Gb, WO, X2, M, D, VD, 0, 0, 0, D, M, nullptr, X);
    // 10. LN2 (fp32 in, bf16 out)
    ln_k<true><<<M, 256, 0, stream>>>(X2, ln2w, ln2b, hb);
    // 11. mid = gelu(h @ W1 + b1)  (bf16)
    gemm128<EPI_GELU_BIAS, true, true><<<dim3(32, 32, 1), 256, 0, stream>>>(
        hb, fw1, mid, M, FFN, D, 0, 0, 0, FFN, M, fb1, nullptr);
    // 12. out = mid @ W2 + b2 + X2  (fp32 -> d_out)
    gemm128<EPI_BIAS_RESID, false, true><<<dim3(8, 32, 1), 256, 0, stream>>>(
        mid, fw2, (float*)d_out, M, D, FFN, 0, 0, 0, D, M, fb2, X2);
}

// Round 4
// 642.043 us; speedup vs baseline: 5.6212x; 5.6212x over previous
//
#include <hip/hip_runtime.h>
#include <hip/hip_bf16.h>

typedef unsigned short u16;
typedef unsigned int   u32;
typedef short short8 __attribute__((ext_vector_type(8)));
typedef float f32x4  __attribute__((ext_vector_type(4)));

// ---------- bf16 helpers ----------
__device__ __forceinline__ float b2f(u16 u) { return __uint_as_float(((u32)u) << 16); }
__device__ __forceinline__ u16 f2b(float f) {
    u32 u = __float_as_uint(f);
    u += 0x7FFF + ((u >> 16) & 1);   // RTNE
    return (u16)(u >> 16);
}

// ---------- LayerNorm (row = 1024 fp32 elems, 256 threads) ----------
template<bool OUT_BF16>
__global__ __launch_bounds__(256) void ln_k(const float* __restrict__ X,
                                            const float* __restrict__ w,
                                            const float* __restrict__ bb,
                                            void* __restrict__ out) {
    const long row = blockIdx.x;
    const int t = threadIdx.x;
    float4 p = ((const float4*)(X + row * 1024))[t];
    float x[4] = { p.x, p.y, p.z, p.w };
    float s = x[0]+x[1]+x[2]+x[3];
    float q = x[0]*x[0]+x[1]*x[1]+x[2]*x[2]+x[3]*x[3];
#pragma unroll
    for (int o = 32; o > 0; o >>= 1) { s += __shfl_down(s, o, 64); q += __shfl_down(q, o, 64); }
    __shared__ float aS[4], aQ[4];
    if ((t & 63) == 0) { aS[t >> 6] = s; aQ[t >> 6] = q; }
    __syncthreads();
    s = aS[0]+aS[1]+aS[2]+aS[3];
    q = aQ[0]+aQ[1]+aQ[2]+aQ[3];
    float mean = s * (1.f/1024.f);
    float var  = q * (1.f/1024.f) - mean*mean;
    float rstd = rsqrtf(var + 1e-5f);
    float4 wv = ((const float4*)w)[t];
    float4 bv = ((const float4*)bb)[t];
    float y[4];
    y[0] = (x[0]-mean)*rstd*wv.x + bv.x;
    y[1] = (x[1]-mean)*rstd*wv.y + bv.y;
    y[2] = (x[2]-mean)*rstd*wv.z + bv.z;
    y[3] = (x[3]-mean)*rstd*wv.w + bv.w;
    if (OUT_BF16) {
        uint2 r;
        r.x = (u32)f2b(y[0]) | ((u32)f2b(y[1]) << 16);
        r.y = (u32)f2b(y[2]) | ((u32)f2b(y[3]) << 16);
        ((uint2*)((u16*)out + row * 1024))[t] = r;
    } else {
        ((float4*)((float*)out + row * 1024))[t] = make_float4(y[0], y[1], y[2], y[3]);
    }
}

// ---------- weight transpose+convert: W [z][K][N] fp32 -> Wt [z][N][K] bf16 ----------
__global__ __launch_bounds__(256) void wtrans(const float* __restrict__ W, u16* __restrict__ Wt,
                                              int K, int N) {
    __shared__ u16 tile[32][36];
    const int k0 = blockIdx.x * 32, n0 = blockIdx.y * 32, z = blockIdx.z;
    const float* Wz = W + (long)z * K * N;
    u16* Wtz = Wt + (long)z * K * N;
    const int t = threadIdx.x;
    const int r = t >> 3, c = (t & 7) * 4;
    float4 v = *(const float4*)(Wz + (long)(k0 + r) * N + n0 + c);
    tile[r][c+0] = f2b(v.x); tile[r][c+1] = f2b(v.y);
    tile[r][c+2] = f2b(v.z); tile[r][c+3] = f2b(v.w);
    __syncthreads();
    u16 o0 = tile[c+0][r], o1 = tile[c+1][r], o2 = tile[c+2][r], o3 = tile[c+3][r];
    uint2 pk;
    pk.x = (u32)o0 | ((u32)o1 << 16);
    pk.y = (u32)o2 | ((u32)o3 << 16);
    *(uint2*)(Wtz + (long)(n0 + r) * K + k0 + c) = pk;
}

// ---------- V transpose (bf16): (16, S, 256) -> (16, 256, S) ----------
__global__ __launch_bounds__(256) void vtrans(const u16* __restrict__ V, u16* __restrict__ Vt) {
    __shared__ u16 tile[32][36];
    const int s0 = blockIdx.x * 32, v0 = blockIdx.y * 32, z = blockIdx.z;
    const u16* Vz = V + (long)z * 2048 * 256;
    u16* Vtz = Vt + (long)z * 256 * 2048;
    const int t = threadIdx.x;
    const int r = t >> 3, c = (t & 7) * 4;
    uint2 ld = *(const uint2*)(Vz + (long)(s0 + r) * 256 + v0 + c);
    tile[r][c+0] = (u16)(ld.x & 0xFFFF); tile[r][c+1] = (u16)(ld.x >> 16);
    tile[r][c+2] = (u16)(ld.y & 0xFFFF); tile[r][c+3] = (u16)(ld.y >> 16);
    __syncthreads();
    uint2 pk;
    pk.x = (u32)tile[c+0][r] | ((u32)tile[c+1][r] << 16);
    pk.y = (u32)tile[c+2][r] | ((u32)tile[c+3][r] << 16);
    *(uint2*)(Vtz + (long)(v0 + r) * 2048 + s0 + c) = pk;
}

// ---------- MFMA GEMM: C[M][N] = A[M][K](bf16) @ Bt[N][K]^T(bf16), fp32 acc ----------
// C addr = z*czStride + (r/RPB)*cbStride + (r%RPB)*rowStride + col
enum { EPI_NONE = 0, EPI_RESID = 1, EPI_GELU_BIAS = 2, EPI_BIAS_RESID = 3 };

template<int EPI, bool OUT_BF16>
__global__ __launch_bounds__(256) void mgemm(
    const u16* __restrict__ A, const u16* __restrict__ Bt, void* __restrict__ Cv,
    int M, int N, int K,
    long bzStride, long czStride, long cbStride, int rowStride, int RPB,
    const float* __restrict__ bias, const float* __restrict__ resid) {
    __shared__ __align__(16) u16 As[128][40];
    __shared__ __align__(16) u16 Bs[128][40];
    const int t = threadIdx.x;
    const int nb = blockIdx.x, mb = blockIdx.y, z = blockIdx.z;
    const int row0 = mb * 128, col0 = nb * 128;
    const u16* Bz = Bt + (long)z * bzStride;
    const int wave = t >> 6, lane = t & 63;
    const int wm = wave >> 1, wn = wave & 1;
    const int quad = lane >> 4, l16 = lane & 15;

    f32x4 acc[4][4];
#pragma unroll
    for (int i = 0; i < 4; i++)
#pragma unroll
        for (int j = 0; j < 4; j++) acc[i][j] = (f32x4){0.f, 0.f, 0.f, 0.f};

    for (int k0 = 0; k0 < K; k0 += 32) {
#pragma unroll
        for (int i = 0; i < 2; i++) {
            int c = t + i * 256;                 // 0..511
            int row = c >> 2, kc = (c & 3) * 8;
            *(uint4*)&As[row][kc] = *(const uint4*)(A  + (long)(row0 + row) * K + k0 + kc);
            *(uint4*)&Bs[row][kc] = *(const uint4*)(Bz + (long)(col0 + row) * K + k0 + kc);
        }
        __syncthreads();
        short8 af[4], bf[4];
#pragma unroll
        for (int mt = 0; mt < 4; mt++)
            af[mt] = *(const short8*)&As[wm*64 + mt*16 + l16][quad*8];
#pragma unroll
        for (int nt = 0; nt < 4; nt++)
            bf[nt] = *(const short8*)&Bs[wn*64 + nt*16 + l16][quad*8];
#pragma unroll
        for (int mt = 0; mt < 4; mt++)
#pragma unroll
            for (int nt = 0; nt < 4; nt++)
                acc[mt][nt] = __builtin_amdgcn_mfma_f32_16x16x32_bf16(af[mt], bf[nt], acc[mt][nt], 0, 0, 0);
        __syncthreads();
    }

#pragma unroll
    for (int mt = 0; mt < 4; mt++) {
#pragma unroll
        for (int reg = 0; reg < 4; reg++) {
            int r = row0 + wm*64 + mt*16 + quad*4 + reg;
            long cbase = (long)z * czStride + (long)(r / RPB) * cbStride + (long)(r % RPB) * rowStride;
#pragma unroll
            for (int nt = 0; nt < 4; nt++) {
                int c = col0 + wn*64 + nt*16 + l16;
                float v = acc[mt][nt][reg];
                if constexpr (EPI == EPI_RESID) {
                    v += resid[(long)r * N + c];
                } else if constexpr (EPI == EPI_GELU_BIAS) {
                    v += bias[c];
                    v = 0.5f * v * (1.f + erff(v * 0.70710678118654752f));
                } else if constexpr (EPI == EPI_BIAS_RESID) {
                    v += bias[c] + resid[(long)r * N + c];
                }
                if constexpr (OUT_BF16) ((u16*)Cv)[cbase + c] = f2b(v);
                else                    ((float*)Cv)[cbase + c] = v;
            }
        }
    }
}

// ---------- xPos rotary (in-place, bf16 (B,H,S,128)) ----------
__global__ __launch_bounds__(256) void xpos_bf16(u16* __restrict__ X, int downscale) {
    long idx = (long)blockIdx.x * 256 + threadIdx.x;   // B*H*S*64 pairs
    int j = (int)(idx & 63);
    int s = (int)((idx >> 6) & 2047);
    long bh = idx >> 17;
    u16* p = X + (bh * 2048 + s) * 128 + 2 * j;
    u32 w = *(u32*)p;
    float x0 = b2f((u16)(w & 0xFFFF)), x1 = b2f((u16)(w >> 16));
    float sv = (2.f * j + 51.2f) / 179.2f;            // (2j + 0.4*128)/(1.4*128)
    float scale = exp2f(log2f(sv) * ((float)s * (1.f / 512.f)));
    if (downscale) scale = 1.f / scale;
    float inv_freq = exp2f((float)j * (-13.287712379549449f / 64.f)); // 10000^{-j/64}
    float ang = (float)s * inv_freq;
    float sn = sinf(ang) * scale;
    float cs = cosf(ang) * scale;
    float y0 = x0 * cs - x1 * sn;
    float y1 = x1 * cs + x0 * sn;
    *(u32*)p = (u32)f2b(y0) | ((u32)f2b(y1) << 16);
}

// ---------- MFMA retention + fused groupnorm ----------
// grid (S/64, H, B), 256 thr. Q,K bf16 (B,H,S,128); Vt bf16 (B,H,256,S); Yn bf16 (B,S,2048)
__global__ __launch_bounds__(256) void retention_mfma(
    const u16* __restrict__ Q, const u16* __restrict__ Kg,
    const u16* __restrict__ Vt, const float* __restrict__ gnw, const float* __restrict__ gnb,
    u16* __restrict__ Yn) {
    __shared__ __align__(16) u16 Qs[64][136];
    __shared__ __align__(16) u16 Ks[32][136];
    __shared__ __align__(16) u16 Vs[256][40];
    __shared__ __align__(16) u16 Ss[64][40];
    const int tile = blockIdx.x, h = blockIdx.y, b = blockIdx.z;
    const int t = threadIdx.x;
    const int wave = t >> 6, lane = t & 63, quad = lane >> 4, l16 = lane & 15;
    const long bh = (long)b * 8 + h;
    const u16* Qbase = Q  + bh * 2048 * 128;
    const u16* Kbase = Kg + bh * 2048 * 128;
    const u16* Vbase = Vt + bh * 256 * 2048;

    float g = 1.f - expf(-3.4657359027997265f + (-0.3960841031771116f) * (float)h);
    float log2g = log2f(g);

#pragma unroll
    for (int i = 0; i < 4; i++) {
        int c = t + i * 256;               // 0..1023
        int row = c >> 4, kc = (c & 15) * 8;
        *(uint4*)&Qs[row][kc] = *(const uint4*)(Qbase + (long)(tile*64 + row) * 128 + kc);
    }
    float gw[16], gbv[16];
#pragma unroll
    for (int nt = 0; nt < 16; nt++) {
        gw[nt]  = gnw[h*256 + nt*16 + l16];
        gbv[nt] = gnb[h*256 + nt*16 + l16];
    }
    f32x4 oacc[16];
#pragma unroll
    for (int nt = 0; nt < 16; nt++) oacc[nt] = (f32x4){0.f, 0.f, 0.f, 0.f};

    const int njt = 2 * tile + 2;
    for (int jt = 0; jt < njt; jt++) {
#pragma unroll
        for (int i = 0; i < 2; i++) {
            int c = t + i * 256;           // 0..511
            int row = c >> 4, kc = (c & 15) * 8;
            *(uint4*)&Ks[row][kc] = *(const uint4*)(Kbase + (long)(jt*32 + row) * 128 + kc);
        }
#pragma unroll
        for (int i = 0; i < 4; i++) {
            int c = t + i * 256;           // 0..1023
            int row = c >> 2, kc = (c & 3) * 8;
            *(uint4*)&Vs[row][kc] = *(const uint4*)(Vbase + (long)row * 2048 + jt*32 + kc);
        }
        __syncthreads();
        // QK^T: wave computes its 16-row m-tile vs 2 n-tiles of 16 key-cols
        f32x4 s0 = (f32x4){0.f,0.f,0.f,0.f}, s1 = (f32x4){0.f,0.f,0.f,0.f};
#pragma unroll
        for (int ks = 0; ks < 4; ks++) {
            short8 aq = *(const short8*)&Qs[wave*16 + l16][ks*32 + quad*8];
            short8 b0 = *(const short8*)&Ks[l16][ks*32 + quad*8];
            short8 b1 = *(const short8*)&Ks[16 + l16][ks*32 + quad*8];
            s0 = __builtin_amdgcn_mfma_f32_16x16x32_bf16(aq, b0, s0, 0, 0, 0);
            s1 = __builtin_amdgcn_mfma_f32_16x16x32_bf16(aq, b1, s1, 0, 0, 0);
        }
        // decay + causal mask, write scores to LDS in A-operand layout
#pragma unroll
        for (int reg = 0; reg < 4; reg++) {
            int srow = tile*64 + wave*16 + quad*4 + reg;
            int tc0 = jt*32 + l16;
            int tc1 = tc0 + 16;
            float d0 = (srow >= tc0) ? exp2f(log2g * (float)(srow - tc0)) : 0.f;
            float d1 = (srow >= tc1) ? exp2f(log2g * (float)(srow - tc1)) : 0.f;
            Ss[wave*16 + quad*4 + reg][l16]      = f2b(s0[reg] * d0);
            Ss[wave*16 + quad*4 + reg][16 + l16] = f2b(s1[reg] * d1);
        }
        __syncthreads();
        // PV: O[64x256] += S[64x32] @ V[32x256]
        short8 as = *(const short8*)&Ss[wave*16 + l16][quad*8];
#pragma unroll
        for (int nt = 0; nt < 16; nt++) {
            short8 bv = *(const short8*)&Vs[nt*16 + l16][quad*8];
            oacc[nt] = __builtin_amdgcn_mfma_f32_16x16x32_bf16(as, bv, oacc[nt], 0, 0, 0);
        }
        __syncthreads();
    }

    // fused groupnorm over 256 v-dims per row + write
#pragma unroll
    for (int reg = 0; reg < 4; reg++) {
        float s = 0.f, q = 0.f;
#pragma unroll
        for (int nt = 0; nt < 16; nt++) { float v = oacc[nt][reg]; s += v; q += v*v; }
#pragma unroll
        for (int m = 1; m < 16; m <<= 1) { s += __shfl_xor(s, m, 16); q += __shfl_xor(q, m, 16); }
        float mean = s * (1.f/256.f);
        float var  = q * (1.f/256.f) - mean*mean;
        float rstd = rsqrtf(var + 1e-5f);
        int srow = tile*64 + wave*16 + quad*4 + reg;
        long obase = ((long)b * 2048 + srow) * 2048 + h * 256;
#pragma unroll
        for (int nt = 0; nt < 16; nt++) {
            float y = (oacc[nt][reg] - mean) * rstd * gw[nt] + gbv[nt];
            Yn[obase + nt*16 + l16] = f2b(y);
        }
    }
}

// ---------- gated = G*sigmoid(G)*Yn, in-place on G (both bf16) ----------
__global__ __launch_bounds__(256) void gate_kernel(u16* __restrict__ G, const u16* __restrict__ Y) {
    long i = ((long)blockIdx.x * 256 + threadIdx.x) * 4;
    uint2 gp = *(const uint2*)(G + i);
    uint2 yp = *(const uint2*)(Y + i);
    float gv[4] = { b2f((u16)(gp.x & 0xFFFF)), b2f((u16)(gp.x >> 16)),
                    b2f((u16)(gp.y & 0xFFFF)), b2f((u16)(gp.y >> 16)) };
    float yv[4] = { b2f((u16)(yp.x & 0xFFFF)), b2f((u16)(yp.x >> 16)),
                    b2f((u16)(yp.y & 0xFFFF)), b2f((u16)(yp.y >> 16)) };
    u16 ob[4];
#pragma unroll
    for (int j = 0; j < 4; j++) {
        float gg = gv[j];
        float sg = 1.f / (1.f + expf(-gg));
        ob[j] = f2b(gg * sg * yv[j]);
    }
    uint2 r;
    r.x = (u32)ob[0] | ((u32)ob[1] << 16);
    r.y = (u32)ob[2] | ((u32)ob[3] << 16);
    *(uint2*)(G + i) = r;
}

extern "C" void kernel_launch(void* const* d_in, const int* in_sizes, int n_in,
                              void* d_out, int out_size, void* d_ws, size_t ws_size,
                              hipStream_t stream) {
    (void)in_sizes; (void)n_in; (void)out_size; (void)ws_size;
    const float* X    = (const float*)d_in[0];
    const float* Wq   = (const float*)d_in[1];
    const float* Wk   = (const float*)d_in[2];
    const float* Wv   = (const float*)d_in[3];
    const float* WG   = (const float*)d_in[4];
    const float* WO   = (const float*)d_in[5];
    const float* gnw  = (const float*)d_in[6];
    const float* gnb  = (const float*)d_in[7];
    const float* ln1w = (const float*)d_in[8];
    const float* ln1b = (const float*)d_in[9];
    const float* ln2w = (const float*)d_in[10];
    const float* ln2b = (const float*)d_in[11];
    const float* fw1  = (const float*)d_in[12];
    const float* fb1  = (const float*)d_in[13];
    const float* fw2  = (const float*)d_in[14];
    const float* fb2  = (const float*)d_in[15];

    constexpr int S = 2048, D = 1024, H = 8, DK = 128, DV = 256, VD = 2048, FFN = 4096;
    constexpr int M = 2 * S; // 4096 rows (b,s)
    constexpr long MB = 1048576;

    char* ws = (char*)d_ws;
    // weights (bf16, transposed to [N][K]) [0,32) MB — persistent
    u16* WqT  = (u16*)(ws + 0*MB);    // (H,DK,D)   2 MB
    u16* WkT  = (u16*)(ws + 2*MB);    // (H,DK,D)   2 MB
    u16* WvT  = (u16*)(ws + 4*MB);    // (H,DV,D)   4 MB
    u16* WGT  = (u16*)(ws + 8*MB);    // (VD,D)     4 MB
    u16* WOT  = (u16*)(ws + 12*MB);   // (D,VD)     4 MB
    u16* fw1T = (u16*)(ws + 16*MB);   // (FFN,D)    8 MB
    u16* fw2T = (u16*)(ws + 24*MB);   // (D,FFN)    8 MB
    // activations, lifetime-packed (peak 96 MB):
    u16*   Qb  = (u16*)(ws + 32*MB);  // bf16 (B,H,S,DK)  8 MB   [Qproj..retention]
    u16*   Kb  = (u16*)(ws + 40*MB);  // bf16 (B,H,S,DK)  8 MB   [Kproj..retention]
    u16*   Vb  = (u16*)(ws + 48*MB);  // bf16 (B,H,S,DV) 16 MB   [Vproj..vtrans]
    u16*   Gb  = (u16*)(ws + 64*MB);  // bf16 (B,S,VD)   16 MB   [Gproj..WO]
    u16*   Xn  = (u16*)(ws + 80*MB);  // bf16 (B,S,D)     8 MB   [LN1..Gproj]
    u16*   Vt  = (u16*)(ws + 80*MB);  // bf16 (B,H,DV,S) 16 MB   [vtrans..retention] (reuses Xn)
    u16*   Ynb = (u16*)(ws + 48*MB);  // bf16 (B,S,VD)   16 MB   [retention..gate]   (reuses Vb)
    float* X2  = (float*)(ws + 32*MB);// fp32 (B,S,D)    16 MB   [WO..final]         (reuses Qb+Kb)
    u16*   hb  = (u16*)(ws + 48*MB);  // bf16 (B,S,D)     8 MB   [LN2..FFN1]         (reuses Ynb)
    u16*   mid = (u16*)(ws + 64*MB);  // bf16 (B,S,FFN)  32 MB   [FFN1..FFN2]        (reuses Gb+Vt)

    // 0. weight transpose + bf16 convert
    wtrans<<<dim3(32, 4, 8),   256, 0, stream>>>(Wq,  WqT,  D, DK);
    wtrans<<<dim3(32, 4, 8),   256, 0, stream>>>(Wk,  WkT,  D, DK);
    wtrans<<<dim3(32, 8, 8),   256, 0, stream>>>(Wv,  WvT,  D, DV);
    wtrans<<<dim3(32, 64, 1),  256, 0, stream>>>(WG,  WGT,  D, VD);
    wtrans<<<dim3(64, 32, 1),  256, 0, stream>>>(WO,  WOT,  VD, D);
    wtrans<<<dim3(32, 128, 1), 256, 0, stream>>>(fw1, fw1T, D, FFN);
    wtrans<<<dim3(128, 32, 1), 256, 0, stream>>>(fw2, fw2T, FFN, D);
    // 1. LN1 -> Xn bf16
    ln_k<true><<<M, 256, 0, stream>>>(X, ln1w, ln1b, Xn);
    // 2-4. Q,K (B,H,S,DK) bf16; V (B,H,S,DV) bf16
    mgemm<EPI_NONE, true><<<dim3(1, 32, 8), 256, 0, stream>>>(
        Xn, WqT, Qb, M, DK, D, (long)DK * D, (long)S * DK, (long)H * S * DK, DK, S, nullptr, nullptr);
    mgemm<EPI_NONE, true><<<dim3(1, 32, 8), 256, 0, stream>>>(
        Xn, WkT, Kb, M, DK, D, (long)DK * D, (long)S * DK, (long)H * S * DK, DK, S, nullptr, nullptr);
    mgemm<EPI_NONE, true><<<dim3(2, 32, 8), 256, 0, stream>>>(
        Xn, WvT, Vb, M, DV, D, (long)DV * D, (long)S * DV, (long)H * S * DV, DV, S, nullptr, nullptr);
    // 5. G = Xn @ W_G bf16 (B,S,VD)
    mgemm<EPI_NONE, true><<<dim3(16, 32, 1), 256, 0, stream>>>(
        Xn, WGT, Gb, M, VD, D, 0, 0, 0, VD, M, nullptr, nullptr);
    // 6. V^T (B,H,DV,S)
    vtrans<<<dim3(64, 8, 16), 256, 0, stream>>>(Vb, Vt);
    // 7. xPos on Q (up) and K (down)
    xpos_bf16<<<8192, 256, 0, stream>>>(Qb, 0);
    xpos_bf16<<<8192, 256, 0, stream>>>(Kb, 1);
    // 8. retention + groupnorm -> Ynb (B,S,VD) bf16
    retention_mfma<<<dim3(32, 8, 2), 256, 0, stream>>>(Qb, Kb, Vt, gnw, gnb, Ynb);
    // 9. gated = silu(G) * Yn (in place on G)
    gate_kernel<<<8192, 256, 0, stream>>>(Gb, Ynb);
    // 10. X2 = gated @ W_O + X  (fp32)
    mgemm<EPI_RESID, false><<<dim3(8, 32, 1), 256, 0, stream>>>(
        Gb, WOT, X2, M, D, VD, 0, 0, 0, D, M, nullptr, X);
    // 11. LN2 (fp32 in, bf16 out)
    ln_k<true><<<M, 256, 0, stream>>>(X2, ln2w, ln2b, hb);
    // 12. mid = gelu(h @ W1 + b1)  bf16
    mgemm<EPI_GELU_BIAS, true><<<dim3(32, 32, 1), 256, 0, stream>>>(
        hb, fw1T, mid, M, FFN, D, 0, 0, 0, FFN, M, fb1, nullptr);
    // 13. out = mid @ W2 + b2 + X2  (fp32 -> d_out)
    mgemm<EPI_BIAS_RESID, false><<<dim3(8, 32, 1), 256, 0, stream>>>(
        mid, fw2T, (float*)d_out, M, D, FFN, 0, 0, 0, D, M, fb2, X2);
}

// Round 5
// 633.307 us; speedup vs baseline: 5.6988x; 1.0138x over previous
//
#include <hip/hip_runtime.h>
#include <hip/hip_bf16.h>

typedef unsigned short u16;
typedef unsigned int   u32;
typedef short short8 __attribute__((ext_vector_type(8)));
typedef float f32x4  __attribute__((ext_vector_type(4)));

// ---------- bf16 helpers ----------
__device__ __forceinline__ float b2f(u16 u) { return __uint_as_float(((u32)u) << 16); }
__device__ __forceinline__ u16 f2b(float f) {
    u32 u = __float_as_uint(f);
    u += 0x7FFF + ((u >> 16) & 1);   // RTNE
    return (u16)(u >> 16);
}

// ---------- async global->LDS 16B (wave-uniform LDS base + lane*16) ----------
typedef const unsigned int __attribute__((address_space(1)))* gas1;
typedef unsigned int __attribute__((address_space(3)))* las3;
__device__ __forceinline__ void async_ld16(const void* g, const void* l) {
    __builtin_amdgcn_global_load_lds((gas1)(unsigned long long)g,
                                     (las3)(unsigned int)(unsigned long long)l,
                                     16, 0, 0);
}

// ---------- LayerNorm (row = 1024 fp32 elems, 256 threads) ----------
template<bool OUT_BF16>
__global__ __launch_bounds__(256) void ln_k(const float* __restrict__ X,
                                            const float* __restrict__ w,
                                            const float* __restrict__ bb,
                                            void* __restrict__ out) {
    const long row = blockIdx.x;
    const int t = threadIdx.x;
    float4 p = ((const float4*)(X + row * 1024))[t];
    float x[4] = { p.x, p.y, p.z, p.w };
    float s = x[0]+x[1]+x[2]+x[3];
    float q = x[0]*x[0]+x[1]*x[1]+x[2]*x[2]+x[3]*x[3];
#pragma unroll
    for (int o = 32; o > 0; o >>= 1) { s += __shfl_down(s, o, 64); q += __shfl_down(q, o, 64); }
    __shared__ float aS[4], aQ[4];
    if ((t & 63) == 0) { aS[t >> 6] = s; aQ[t >> 6] = q; }
    __syncthreads();
    s = aS[0]+aS[1]+aS[2]+aS[3];
    q = aQ[0]+aQ[1]+aQ[2]+aQ[3];
    float mean = s * (1.f/1024.f);
    float var  = q * (1.f/1024.f) - mean*mean;
    float rstd = rsqrtf(var + 1e-5f);
    float4 wv = ((const float4*)w)[t];
    float4 bv = ((const float4*)bb)[t];
    float y[4];
    y[0] = (x[0]-mean)*rstd*wv.x + bv.x;
    y[1] = (x[1]-mean)*rstd*wv.y + bv.y;
    y[2] = (x[2]-mean)*rstd*wv.z + bv.z;
    y[3] = (x[3]-mean)*rstd*wv.w + bv.w;
    if (OUT_BF16) {
        uint2 r;
        r.x = (u32)f2b(y[0]) | ((u32)f2b(y[1]) << 16);
        r.y = (u32)f2b(y[2]) | ((u32)f2b(y[3]) << 16);
        ((uint2*)((u16*)out + row * 1024))[t] = r;
    } else {
        ((float4*)((float*)out + row * 1024))[t] = make_float4(y[0], y[1], y[2], y[3]);
    }
}

// ---------- weight transpose+convert: W [z][K][N] fp32 -> Wt [z][N][K] bf16 ----------
__global__ __launch_bounds__(256) void wtrans(const float* __restrict__ W, u16* __restrict__ Wt,
                                              int K, int N) {
    __shared__ u16 tile[32][36];
    const int k0 = blockIdx.x * 32, n0 = blockIdx.y * 32, z = blockIdx.z;
    const float* Wz = W + (long)z * K * N;
    u16* Wtz = Wt + (long)z * K * N;
    const int t = threadIdx.x;
    const int r = t >> 3, c = (t & 7) * 4;
    float4 v = *(const float4*)(Wz + (long)(k0 + r) * N + n0 + c);
    tile[r][c+0] = f2b(v.x); tile[r][c+1] = f2b(v.y);
    tile[r][c+2] = f2b(v.z); tile[r][c+3] = f2b(v.w);
    __syncthreads();
    u16 o0 = tile[c+0][r], o1 = tile[c+1][r], o2 = tile[c+2][r], o3 = tile[c+3][r];
    uint2 pk;
    pk.x = (u32)o0 | ((u32)o1 << 16);
    pk.y = (u32)o2 | ((u32)o3 << 16);
    *(uint2*)(Wtz + (long)(n0 + r) * K + k0 + c) = pk;
}

// ---------- V transpose (bf16): (16, S, 256) -> (16, 256, S) ----------
__global__ __launch_bounds__(256) void vtrans(const u16* __restrict__ V, u16* __restrict__ Vt) {
    __shared__ u16 tile[32][36];
    const int s0 = blockIdx.x * 32, v0 = blockIdx.y * 32, z = blockIdx.z;
    const u16* Vz = V + (long)z * 2048 * 256;
    u16* Vtz = Vt + (long)z * 256 * 2048;
    const int t = threadIdx.x;
    const int r = t >> 3, c = (t & 7) * 4;
    uint2 ld = *(const uint2*)(Vz + (long)(s0 + r) * 256 + v0 + c);
    tile[r][c+0] = (u16)(ld.x & 0xFFFF); tile[r][c+1] = (u16)(ld.x >> 16);
    tile[r][c+2] = (u16)(ld.y & 0xFFFF); tile[r][c+3] = (u16)(ld.y >> 16);
    __syncthreads();
    uint2 pk;
    pk.x = (u32)tile[c+0][r] | ((u32)tile[c+1][r] << 16);
    pk.y = (u32)tile[c+2][r] | ((u32)tile[c+3][r] << 16);
    *(uint2*)(Vtz + (long)(v0 + r) * 2048 + s0 + c) = pk;
}

// ---------- MFMA GEMM (m97 structure): C = A[M][K] @ Bt[N][K]^T, bf16->fp32 ----------
// If GN>0: 1D grouped-swizzle grid (group of 8 mb per nb sweep; pins mb%8 per XCD).
// C addr = z*czStride + (r/RPB)*cbStride + (r%RPB)*rowStride + col
enum { EPI_NONE = 0, EPI_RESID = 1, EPI_GELU_BIAS = 2, EPI_BIAS_RESID = 3 };

template<int EPI, bool OUT_BF16>
__global__ __launch_bounds__(256) void mgemm(
    const u16* __restrict__ A, const u16* __restrict__ Bt, void* __restrict__ Cv,
    int N, int K, int GN,
    long bzStride, long czStride, long cbStride, int rowStride, int RPB,
    const float* __restrict__ bias, const float* __restrict__ resid) {
    __shared__ __align__(16) u16 As[128 * 32];
    __shared__ __align__(16) u16 Bs[128 * 32];
    int nb, mb, z;
    if (GN > 0) {
        int pid = blockIdx.x;
        int group = GN << 3;
        int gid = pid / group;
        int rem = pid - gid * group;
        mb = (gid << 3) + (rem & 7);
        nb = rem >> 3;
        z = 0;
    } else {
        nb = blockIdx.x; mb = blockIdx.y; z = blockIdx.z;
    }
    const int t = threadIdx.x;
    const int row0 = mb * 128, col0 = nb * 128;
    const int wave = t >> 6, lane = t & 63;
    const int wm = wave >> 1, wn = wave & 1;
    const int quad = lane >> 4, l16 = lane & 15;
    // staging addresses: chunk t covers tile row t/4, k-cols (t&3)*8..+7 (16 B)
    const u16* Ag = A + (long)(row0 + (t >> 2)) * K + ((t & 3) * 8);
    const u16* Bg = Bt + (long)z * bzStride + (long)(col0 + (t >> 2)) * K + ((t & 3) * 8);
    const long rowjump = (long)64 * K;
    const u32 lo = __builtin_amdgcn_readfirstlane((u32)(wave * 1024));

    f32x4 acc[4][4];
#pragma unroll
    for (int i = 0; i < 4; i++)
#pragma unroll
        for (int j = 0; j < 4; j++) acc[i][j] = (f32x4){0.f, 0.f, 0.f, 0.f};

    for (int k0 = 0; k0 < K; k0 += 32) {
        async_ld16(Ag + k0,           (const char*)As + lo);
        async_ld16(Ag + k0 + rowjump, (const char*)As + 4096 + lo);
        async_ld16(Bg + k0,           (const char*)Bs + lo);
        async_ld16(Bg + k0 + rowjump, (const char*)Bs + 4096 + lo);
        __syncthreads();
        short8 af[4], bf[4];
#pragma unroll
        for (int mt = 0; mt < 4; mt++)
            af[mt] = *(const short8*)(As + (wm*64 + mt*16 + l16) * 32 + quad*8);
#pragma unroll
        for (int nt = 0; nt < 4; nt++)
            bf[nt] = *(const short8*)(Bs + (wn*64 + nt*16 + l16) * 32 + quad*8);
#pragma unroll
        for (int mt = 0; mt < 4; mt++)
#pragma unroll
            for (int nt = 0; nt < 4; nt++)
                acc[mt][nt] = __builtin_amdgcn_mfma_f32_16x16x32_bf16(af[mt], bf[nt], acc[mt][nt], 0, 0, 0);
        __syncthreads();
    }

#pragma unroll
    for (int mt = 0; mt < 4; mt++) {
#pragma unroll
        for (int reg = 0; reg < 4; reg++) {
            int r = row0 + wm*64 + mt*16 + quad*4 + reg;
            long cbase = (long)z * czStride + (long)(r / RPB) * cbStride + (long)(r % RPB) * rowStride;
#pragma unroll
            for (int nt = 0; nt < 4; nt++) {
                int c = col0 + wn*64 + nt*16 + l16;
                float v = acc[mt][nt][reg];
                if constexpr (EPI == EPI_RESID) {
                    v += resid[(long)r * N + c];
                } else if constexpr (EPI == EPI_GELU_BIAS) {
                    v += bias[c];
                    v = 0.5f * v * (1.f + erff(v * 0.70710678118654752f));
                } else if constexpr (EPI == EPI_BIAS_RESID) {
                    v += bias[c] + resid[(long)r * N + c];
                }
                if constexpr (OUT_BF16) ((u16*)Cv)[cbase + c] = f2b(v);
                else                    ((float*)Cv)[cbase + c] = v;
            }
        }
    }
}

// ---------- xPos rotary (in-place, bf16 (B,H,S,128)) ----------
__global__ __launch_bounds__(256) void xpos_bf16(u16* __restrict__ X, int downscale) {
    long idx = (long)blockIdx.x * 256 + threadIdx.x;   // B*H*S*64 pairs
    int j = (int)(idx & 63);
    int s = (int)((idx >> 6) & 2047);
    long bh = idx >> 17;
    u16* p = X + (bh * 2048 + s) * 128 + 2 * j;
    u32 w = *(u32*)p;
    float x0 = b2f((u16)(w & 0xFFFF)), x1 = b2f((u16)(w >> 16));
    float sv = (2.f * j + 51.2f) / 179.2f;            // (2j + 0.4*128)/(1.4*128)
    float scale = exp2f(log2f(sv) * ((float)s * (1.f / 512.f)));
    if (downscale) scale = 1.f / scale;
    float inv_freq = exp2f((float)j * (-13.287712379549449f / 64.f)); // 10000^{-j/64}
    float ang = (float)s * inv_freq;
    float sn = sinf(ang) * scale;
    float cs = cosf(ang) * scale;
    float y0 = x0 * cs - x1 * sn;
    float y1 = x1 * cs + x0 * sn;
    *(u32*)p = (u32)f2b(y0) | ((u32)f2b(y1) << 16);
}

// ---------- MFMA retention + fused groupnorm ----------
// grid (S/64, H, B), 256 thr. Q,K bf16 (B,H,S,128); Vt bf16 (B,H,256,S); Yn bf16 (B,S,2048)
__global__ __launch_bounds__(256) void retention_mfma(
    const u16* __restrict__ Q, const u16* __restrict__ Kg,
    const u16* __restrict__ Vt, const float* __restrict__ gnw, const float* __restrict__ gnb,
    u16* __restrict__ Yn) {
    __shared__ __align__(16) u16 Qs[64][136];
    __shared__ __align__(16) u16 Ks[32][136];
    __shared__ __align__(16) u16 Vs[256][40];
    __shared__ __align__(16) u16 Ss[64][40];
    // longest-running tiles (largest causal extent) first
    const int tile = (int)gridDim.x - 1 - (int)blockIdx.x;
    const int h = blockIdx.y, b = blockIdx.z;
    const int t = threadIdx.x;
    const int wave = t >> 6, lane = t & 63, quad = lane >> 4, l16 = lane & 15;
    const long bh = (long)b * 8 + h;
    const u16* Qbase = Q  + bh * 2048 * 128;
    const u16* Kbase = Kg + bh * 2048 * 128;
    const u16* Vbase = Vt + bh * 256 * 2048;

    float g = 1.f - expf(-3.4657359027997265f + (-0.3960841031771116f) * (float)h);
    float log2g = log2f(g);

#pragma unroll
    for (int i = 0; i < 4; i++) {
        int c = t + i * 256;               // 0..1023
        int row = c >> 4, kc = (c & 15) * 8;
        *(uint4*)&Qs[row][kc] = *(const uint4*)(Qbase + (long)(tile*64 + row) * 128 + kc);
    }
    float gw[16], gbv[16];
#pragma unroll
    for (int nt = 0; nt < 16; nt++) {
        gw[nt]  = gnw[h*256 + nt*16 + l16];
        gbv[nt] = gnb[h*256 + nt*16 + l16];
    }
    f32x4 oacc[16];
#pragma unroll
    for (int nt = 0; nt < 16; nt++) oacc[nt] = (f32x4){0.f, 0.f, 0.f, 0.f};

    const int njt = 2 * tile + 2;
    for (int jt = 0; jt < njt; jt++) {
#pragma unroll
        for (int i = 0; i < 2; i++) {
            int c = t + i * 256;           // 0..511
            int row = c >> 4, kc = (c & 15) * 8;
            *(uint4*)&Ks[row][kc] = *(const uint4*)(Kbase + (long)(jt*32 + row) * 128 + kc);
        }
#pragma unroll
        for (int i = 0; i < 4; i++) {
            int c = t + i * 256;           // 0..1023
            int row = c >> 2, kc = (c & 3) * 8;
            *(uint4*)&Vs[row][kc] = *(const uint4*)(Vbase + (long)row * 2048 + jt*32 + kc);
        }
        __syncthreads();
        // QK^T: wave computes its 16-row m-tile vs 2 n-tiles of 16 key-cols
        f32x4 s0 = (f32x4){0.f,0.f,0.f,0.f}, s1 = (f32x4){0.f,0.f,0.f,0.f};
#pragma unroll
        for (int ks = 0; ks < 4; ks++) {
            short8 aq = *(const short8*)&Qs[wave*16 + l16][ks*32 + quad*8];
            short8 b0 = *(const short8*)&Ks[l16][ks*32 + quad*8];
            short8 b1 = *(const short8*)&Ks[16 + l16][ks*32 + quad*8];
            s0 = __builtin_amdgcn_mfma_f32_16x16x32_bf16(aq, b0, s0, 0, 0, 0);
            s1 = __builtin_amdgcn_mfma_f32_16x16x32_bf16(aq, b1, s1, 0, 0, 0);
        }
        // decay + causal mask, write scores to LDS in A-operand layout
#pragma unroll
        for (int reg = 0; reg < 4; reg++) {
            int srow = tile*64 + wave*16 + quad*4 + reg;
            int tc0 = jt*32 + l16;
            int tc1 = tc0 + 16;
            float d0 = (srow >= tc0) ? exp2f(log2g * (float)(srow - tc0)) : 0.f;
            float d1 = (srow >= tc1) ? exp2f(log2g * (float)(srow - tc1)) : 0.f;
            Ss[wave*16 + quad*4 + reg][l16]      = f2b(s0[reg] * d0);
            Ss[wave*16 + quad*4 + reg][16 + l16] = f2b(s1[reg] * d1);
        }
        __syncthreads();
        // PV: O[64x256] += S[64x32] @ V[32x256]
        short8 as = *(const short8*)&Ss[wave*16 + l16][quad*8];
#pragma unroll
        for (int nt = 0; nt < 16; nt++) {
            short8 bv = *(const short8*)&Vs[nt*16 + l16][quad*8];
            oacc[nt] = __builtin_amdgcn_mfma_f32_16x16x32_bf16(as, bv, oacc[nt], 0, 0, 0);
        }
        __syncthreads();
    }

    // fused groupnorm over 256 v-dims per row + write
#pragma unroll
    for (int reg = 0; reg < 4; reg++) {
        float s = 0.f, q = 0.f;
#pragma unroll
        for (int nt = 0; nt < 16; nt++) { float v = oacc[nt][reg]; s += v; q += v*v; }
#pragma unroll
        for (int m = 1; m < 16; m <<= 1) { s += __shfl_xor(s, m, 16); q += __shfl_xor(q, m, 16); }
        float mean = s * (1.f/256.f);
        float var  = q * (1.f/256.f) - mean*mean;
        float rstd = rsqrtf(var + 1e-5f);
        int srow = tile*64 + wave*16 + quad*4 + reg;
        long obase = ((long)b * 2048 + srow) * 2048 + h * 256;
#pragma unroll
        for (int nt = 0; nt < 16; nt++) {
            float y = (oacc[nt][reg] - mean) * rstd * gw[nt] + gbv[nt];
            Yn[obase + nt*16 + l16] = f2b(y);
        }
    }
}

// ---------- gated = G*sigmoid(G)*Yn, in-place on G (both bf16) ----------
__global__ __launch_bounds__(256) void gate_kernel(u16* __restrict__ G, const u16* __restrict__ Y) {
    long i = ((long)blockIdx.x * 256 + threadIdx.x) * 4;
    uint2 gp = *(const uint2*)(G + i);
    uint2 yp = *(const uint2*)(Y + i);
    float gv[4] = { b2f((u16)(gp.x & 0xFFFF)), b2f((u16)(gp.x >> 16)),
                    b2f((u16)(gp.y & 0xFFFF)), b2f((u16)(gp.y >> 16)) };
    float yv[4] = { b2f((u16)(yp.x & 0xFFFF)), b2f((u16)(yp.x >> 16)),
                    b2f((u16)(yp.y & 0xFFFF)), b2f((u16)(yp.y >> 16)) };
    u16 ob[4];
#pragma unroll
    for (int j = 0; j < 4; j++) {
        float gg = gv[j];
        float sg = 1.f / (1.f + expf(-gg));
        ob[j] = f2b(gg * sg * yv[j]);
    }
    uint2 r;
    r.x = (u32)ob[0] | ((u32)ob[1] << 16);
    r.y = (u32)ob[2] | ((u32)ob[3] << 16);
    *(uint2*)(G + i) = r;
}

extern "C" void kernel_launch(void* const* d_in, const int* in_sizes, int n_in,
                              void* d_out, int out_size, void* d_ws, size_t ws_size,
                              hipStream_t stream) {
    (void)in_sizes; (void)n_in; (void)out_size; (void)ws_size;
    const float* X    = (const float*)d_in[0];
    const float* Wq   = (const float*)d_in[1];
    const float* Wk   = (const float*)d_in[2];
    const float* Wv   = (const float*)d_in[3];
    const float* WG   = (const float*)d_in[4];
    const float* WO   = (const float*)d_in[5];
    const float* gnw  = (const float*)d_in[6];
    const float* gnb  = (const float*)d_in[7];
    const float* ln1w = (const float*)d_in[8];
    const float* ln1b = (const float*)d_in[9];
    const float* ln2w = (const float*)d_in[10];
    const float* ln2b = (const float*)d_in[11];
    const float* fw1  = (const float*)d_in[12];
    const float* fb1  = (const float*)d_in[13];
    const float* fw2  = (const float*)d_in[14];
    const float* fb2  = (const float*)d_in[15];

    constexpr int S = 2048, D = 1024, H = 8, DK = 128, DV = 256, VD = 2048, FFN = 4096;
    constexpr int M = 2 * S; // 4096 rows (b,s)
    constexpr long MB = 1048576;

    char* ws = (char*)d_ws;
    // weights (bf16, transposed to [N][K]) [0,32) MB — persistent
    u16* WqT  = (u16*)(ws + 0*MB);    // (H,DK,D)   2 MB
    u16* WkT  = (u16*)(ws + 2*MB);    // (H,DK,D)   2 MB
    u16* WvT  = (u16*)(ws + 4*MB);    // (H,DV,D)   4 MB
    u16* WGT  = (u16*)(ws + 8*MB);    // (VD,D)     4 MB
    u16* WOT  = (u16*)(ws + 12*MB);   // (D,VD)     4 MB
    u16* fw1T = (u16*)(ws + 16*MB);   // (FFN,D)    8 MB
    u16* fw2T = (u16*)(ws + 24*MB);   // (D,FFN)    8 MB
    // activations, lifetime-packed (peak 96 MB):
    u16*   Qb  = (u16*)(ws + 32*MB);  // bf16 (B,H,S,DK)  8 MB   [Qproj..retention]
    u16*   Kb  = (u16*)(ws + 40*MB);  // bf16 (B,H,S,DK)  8 MB   [Kproj..retention]
    u16*   Vb  = (u16*)(ws + 48*MB);  // bf16 (B,H,S,DV) 16 MB   [Vproj..vtrans]
    u16*   Gb  = (u16*)(ws + 64*MB);  // bf16 (B,S,VD)   16 MB   [Gproj..WO]
    u16*   Xn  = (u16*)(ws + 80*MB);  // bf16 (B,S,D)     8 MB   [LN1..Gproj]
    u16*   Vt  = (u16*)(ws + 80*MB);  // bf16 (B,H,DV,S) 16 MB   [vtrans..retention] (reuses Xn)
    u16*   Ynb = (u16*)(ws + 48*MB);  // bf16 (B,S,VD)   16 MB   [retention..gate]   (reuses Vb)
    float* X2  = (float*)(ws + 32*MB);// fp32 (B,S,D)    16 MB   [WO..final]         (reuses Qb+Kb)
    u16*   hb  = (u16*)(ws + 48*MB);  // bf16 (B,S,D)     8 MB   [LN2..FFN1]         (reuses Ynb)
    u16*   mid = (u16*)(ws + 64*MB);  // bf16 (B,S,FFN)  32 MB   [FFN1..FFN2]        (reuses Gb+Vt)

    // 0. weight transpose + bf16 convert
    wtrans<<<dim3(32, 4, 8),   256, 0, stream>>>(Wq,  WqT,  D, DK);
    wtrans<<<dim3(32, 4, 8),   256, 0, stream>>>(Wk,  WkT,  D, DK);
    wtrans<<<dim3(32, 8, 8),   256, 0, stream>>>(Wv,  WvT,  D, DV);
    wtrans<<<dim3(32, 64, 1),  256, 0, stream>>>(WG,  WGT,  D, VD);
    wtrans<<<dim3(64, 32, 1),  256, 0, stream>>>(WO,  WOT,  VD, D);
    wtrans<<<dim3(32, 128, 1), 256, 0, stream>>>(fw1, fw1T, D, FFN);
    wtrans<<<dim3(128, 32, 1), 256, 0, stream>>>(fw2, fw2T, FFN, D);
    // 1. LN1 -> Xn bf16
    ln_k<true><<<M, 256, 0, stream>>>(X, ln1w, ln1b, Xn);
    // 2-4. Q,K (B,H,S,DK) bf16; V (B,H,S,DV) bf16  (z-batched, small grids: no swizzle)
    mgemm<EPI_NONE, true><<<dim3(1, 32, 8), 256, 0, stream>>>(
        Xn, WqT, Qb, DK, D, 0, (long)DK * D, (long)S * DK, (long)H * S * DK, DK, S, nullptr, nullptr);
    mgemm<EPI_NONE, true><<<dim3(1, 32, 8), 256, 0, stream>>>(
        Xn, WkT, Kb, DK, D, 0, (long)DK * D, (long)S * DK, (long)H * S * DK, DK, S, nullptr, nullptr);
    mgemm<EPI_NONE, true><<<dim3(2, 32, 8), 256, 0, stream>>>(
        Xn, WvT, Vb, DV, D, 0, (long)DV * D, (long)S * DV, (long)H * S * DV, DV, S, nullptr, nullptr);
    // 5. G = Xn @ W_G bf16 (B,S,VD) — swizzled 1D grid (32 mb x 16 nb)
    mgemm<EPI_NONE, true><<<512, 256, 0, stream>>>(
        Xn, WGT, Gb, VD, D, 16, 0, 0, 0, VD, M, nullptr, nullptr);
    // 6. V^T (B,H,DV,S)
    vtrans<<<dim3(64, 8, 16), 256, 0, stream>>>(Vb, Vt);
    // 7. xPos on Q (up) and K (down)
    xpos_bf16<<<8192, 256, 0, stream>>>(Qb, 0);
    xpos_bf16<<<8192, 256, 0, stream>>>(Kb, 1);
    // 8. retention + groupnorm -> Ynb (B,S,VD) bf16
    retention_mfma<<<dim3(32, 8, 2), 256, 0, stream>>>(Qb, Kb, Vt, gnw, gnb, Ynb);
    // 9. gated = silu(G) * Yn (in place on G)
    gate_kernel<<<8192, 256, 0, stream>>>(Gb, Ynb);
    // 10. X2 = gated @ W_O + X  (fp32) — swizzled (32 mb x 8 nb)
    mgemm<EPI_RESID, false><<<256, 256, 0, stream>>>(
        Gb, WOT, X2, D, VD, 8, 0, 0, 0, D, M, nullptr, X);
    // 11. LN2 (fp32 in, bf16 out)
    ln_k<true><<<M, 256, 0, stream>>>(X2, ln2w, ln2b, hb);
    // 12. mid = gelu(h @ W1 + b1)  bf16 — swizzled (32 mb x 32 nb)
    mgemm<EPI_GELU_BIAS, true><<<1024, 256, 0, stream>>>(
        hb, fw1T, mid, FFN, D, 32, 0, 0, 0, FFN, M, fb1, nullptr);
    // 13. out = mid @ W2 + b2 + X2  (fp32 -> d_out) — swizzled (32 mb x 8 nb)
    mgemm<EPI_BIAS_RESID, false><<<256, 256, 0, stream>>>(
        mid, fw2T, (float*)d_out, D, FFN, 8, 0, 0, 0, D, M, fb2, X2);
}

// Round 6
// 589.984 us; speedup vs baseline: 6.1172x; 1.0734x over previous
//
#include <hip/hip_runtime.h>
#include <hip/hip_bf16.h>

typedef unsigned short u16;
typedef unsigned int   u32;
typedef short short8 __attribute__((ext_vector_type(8)));
typedef float f32x4  __attribute__((ext_vector_type(4)));

// ---------- bf16 helpers ----------
__device__ __forceinline__ float b2f(u16 u) { return __uint_as_float(((u32)u) << 16); }
__device__ __forceinline__ u16 f2b(float f) {
    u32 u = __float_as_uint(f);
    u += 0x7FFF + ((u >> 16) & 1);   // RTNE
    return (u16)(u >> 16);
}

// ---------- async global->LDS 16B (wave-uniform LDS base + lane*16) ----------
typedef const unsigned int __attribute__((address_space(1)))* gas1;
typedef unsigned int __attribute__((address_space(3)))* las3;
__device__ __forceinline__ void async_ld16(const void* g, const void* l) {
    __builtin_amdgcn_global_load_lds((gas1)(unsigned long long)g,
                                     (las3)(unsigned int)(unsigned long long)l,
                                     16, 0, 0);
}

// ---------- LayerNorm (row = 1024 fp32 elems, 256 threads) ----------
__global__ __launch_bounds__(256) void ln_k(const float* __restrict__ X,
                                            const float* __restrict__ w,
                                            const float* __restrict__ bb,
                                            u16* __restrict__ out) {
    const long row = blockIdx.x;
    const int t = threadIdx.x;
    float4 p = ((const float4*)(X + row * 1024))[t];
    float x[4] = { p.x, p.y, p.z, p.w };
    float s = x[0]+x[1]+x[2]+x[3];
    float q = x[0]*x[0]+x[1]*x[1]+x[2]*x[2]+x[3]*x[3];
#pragma unroll
    for (int o = 32; o > 0; o >>= 1) { s += __shfl_down(s, o, 64); q += __shfl_down(q, o, 64); }
    __shared__ float aS[4], aQ[4];
    if ((t & 63) == 0) { aS[t >> 6] = s; aQ[t >> 6] = q; }
    __syncthreads();
    s = aS[0]+aS[1]+aS[2]+aS[3];
    q = aQ[0]+aQ[1]+aQ[2]+aQ[3];
    float mean = s * (1.f/1024.f);
    float var  = q * (1.f/1024.f) - mean*mean;
    float rstd = rsqrtf(var + 1e-5f);
    float4 wv = ((const float4*)w)[t];
    float4 bv = ((const float4*)bb)[t];
    float y[4];
    y[0] = (x[0]-mean)*rstd*wv.x + bv.x;
    y[1] = (x[1]-mean)*rstd*wv.y + bv.y;
    y[2] = (x[2]-mean)*rstd*wv.z + bv.z;
    y[3] = (x[3]-mean)*rstd*wv.w + bv.w;
    uint2 r;
    r.x = (u32)f2b(y[0]) | ((u32)f2b(y[1]) << 16);
    r.y = (u32)f2b(y[2]) | ((u32)f2b(y[3]) << 16);
    ((uint2*)(out + row * 1024))[t] = r;
}

// ---------- weight transpose+convert: W [z][K][N] fp32 -> Wt [z][N][K] bf16 ----------
__global__ __launch_bounds__(256) void wtrans(const float* __restrict__ W, u16* __restrict__ Wt,
                                              int K, int N) {
    __shared__ u16 tile[32][36];
    const int k0 = blockIdx.x * 32, n0 = blockIdx.y * 32, z = blockIdx.z;
    const float* Wz = W + (long)z * K * N;
    u16* Wtz = Wt + (long)z * K * N;
    const int t = threadIdx.x;
    const int r = t >> 3, c = (t & 7) * 4;
    float4 v = *(const float4*)(Wz + (long)(k0 + r) * N + n0 + c);
    tile[r][c+0] = f2b(v.x); tile[r][c+1] = f2b(v.y);
    tile[r][c+2] = f2b(v.z); tile[r][c+3] = f2b(v.w);
    __syncthreads();
    u16 o0 = tile[c+0][r], o1 = tile[c+1][r], o2 = tile[c+2][r], o3 = tile[c+3][r];
    uint2 pk;
    pk.x = (u32)o0 | ((u32)o1 << 16);
    pk.y = (u32)o2 | ((u32)o3 << 16);
    *(uint2*)(Wtz + (long)(n0 + r) * K + k0 + c) = pk;
}

// ---------- V transpose (bf16): QKVG V-segment (B,S,6144)+2048 -> Vt (B,H,256,S) ----------
__global__ __launch_bounds__(256) void vtrans(const u16* __restrict__ Vseg, u16* __restrict__ Vt) {
    __shared__ u16 tile[32][36];
    const int s0 = blockIdx.x * 32, v0 = blockIdx.y * 32, z = blockIdx.z; // z = b*8+h
    const int b = z >> 3, h = z & 7;
    const u16* Vz = Vseg + (long)b * 2048 * 6144 + h * 256;
    u16* Vtz = Vt + (long)z * 256 * 2048;
    const int t = threadIdx.x;
    const int r = t >> 3, c = (t & 7) * 4;
    uint2 ld = *(const uint2*)(Vz + (long)(s0 + r) * 6144 + v0 + c);
    tile[r][c+0] = (u16)(ld.x & 0xFFFF); tile[r][c+1] = (u16)(ld.x >> 16);
    tile[r][c+2] = (u16)(ld.y & 0xFFFF); tile[r][c+3] = (u16)(ld.y >> 16);
    __syncthreads();
    uint2 pk;
    pk.x = (u32)tile[c+0][r] | ((u32)tile[c+1][r] << 16);
    pk.y = (u32)tile[c+2][r] | ((u32)tile[c+3][r] << 16);
    *(uint2*)(Vtz + (long)(v0 + r) * 2048 + s0 + c) = pk;
}

// ---------- MFMA GEMM (m97 structure): C = A[M][K] @ Bt[N][K]^T, bf16->fp32 ----------
// 1D grouped-swizzle grid: groups of 8 mb per nb sweep (pins mb%8 per XCD).
// C elem addr = r*cStride + c (+ cOff). A row stride = aStride elems.
enum { EPI_NONE = 0, EPI_RESID = 1, EPI_GELU_BIAS = 2, EPI_BIAS_RESID = 3, EPI_QKVG = 4 };

template<int EPI, bool OUT_BF16>
__global__ __launch_bounds__(256) void mgemm(
    const u16* __restrict__ A, const u16* __restrict__ Bt, void* __restrict__ Cv,
    int N, int K, int GN, int aStride, long cStride,
    const float* __restrict__ bias, const float* __restrict__ resid) {
    __shared__ __align__(16) u16 As[128 * 32];
    __shared__ __align__(16) u16 Bs[128 * 32];
    int pid = blockIdx.x;
    int group = GN << 3;
    int gid = pid / group;
    int rem = pid - gid * group;
    int mb = (gid << 3) + (rem & 7);
    int nb = rem >> 3;
    const int t = threadIdx.x;
    const int row0 = mb * 128, col0 = nb * 128;
    const int wave = t >> 6, lane = t & 63;
    const int wm = wave >> 1, wn = wave & 1;
    const int quad = lane >> 4, l16 = lane & 15;
    const u16* Ag = A + (long)(row0 + (t >> 2)) * aStride + ((t & 3) * 8);
    const u16* Bg = Bt + (long)(col0 + (t >> 2)) * K + ((t & 3) * 8);
    const long aj = (long)64 * aStride;
    const long bj = (long)64 * K;
    const u32 lo = __builtin_amdgcn_readfirstlane((u32)(wave * 1024));

    f32x4 acc[4][4];
#pragma unroll
    for (int i = 0; i < 4; i++)
#pragma unroll
        for (int j = 0; j < 4; j++) acc[i][j] = (f32x4){0.f, 0.f, 0.f, 0.f};

    for (int k0 = 0; k0 < K; k0 += 32) {
        async_ld16(Ag + k0,      (const char*)As + lo);
        async_ld16(Ag + k0 + aj, (const char*)As + 4096 + lo);
        async_ld16(Bg + k0,      (const char*)Bs + lo);
        async_ld16(Bg + k0 + bj, (const char*)Bs + 4096 + lo);
        __syncthreads();
        short8 af[4], bf[4];
#pragma unroll
        for (int mt = 0; mt < 4; mt++)
            af[mt] = *(const short8*)(As + (wm*64 + mt*16 + l16) * 32 + quad*8);
#pragma unroll
        for (int nt = 0; nt < 4; nt++)
            bf[nt] = *(const short8*)(Bs + (wn*64 + nt*16 + l16) * 32 + quad*8);
#pragma unroll
        for (int mt = 0; mt < 4; mt++)
#pragma unroll
            for (int nt = 0; nt < 4; nt++)
                acc[mt][nt] = __builtin_amdgcn_mfma_f32_16x16x32_bf16(af[mt], bf[nt], acc[mt][nt], 0, 0, 0);
        __syncthreads();
    }

#pragma unroll
    for (int mt = 0; mt < 4; mt++) {
#pragma unroll
        for (int reg = 0; reg < 4; reg++) {
            int r = row0 + wm*64 + mt*16 + quad*4 + reg;
#pragma unroll
            for (int nt = 0; nt < 4; nt++) {
                int c = col0 + wn*64 + nt*16 + l16;
                float v = acc[mt][nt][reg];
                if constexpr (EPI == EPI_RESID) {
                    v += resid[(long)r * N + c];
                } else if constexpr (EPI == EPI_GELU_BIAS) {
                    v += bias[c];
                    v = 0.5f * v * (1.f + erff(v * 0.70710678118654752f));
                } else if constexpr (EPI == EPI_BIAS_RESID) {
                    v += bias[c] + resid[(long)r * N + c];
                } else if constexpr (EPI == EPI_QKVG) {
                    if (c < 2048) {  // xPos rotary on Q (c<1024, up) / K (else, down)
                        int j = (c & 127) >> 1;
                        int s = r & 2047;
                        float sv = (2.f * j + 51.2f) / 179.2f;
                        float scale = exp2f(log2f(sv) * ((float)s * (1.f / 512.f)));
                        if (c >= 1024) scale = 1.f / scale;
                        float inv_freq = exp2f((float)j * (-13.287712379549449f / 64.f));
                        float ang = (float)s * inv_freq;
                        float sn = sinf(ang) * scale;
                        float cs = cosf(ang) * scale;
                        float partner = __shfl_xor(v, 1, 64);
                        v = v * cs + ((c & 1) ? partner : -partner) * sn;
                    }
                }
                long caddr = (long)r * cStride + c;
                if constexpr (OUT_BF16) ((u16*)Cv)[caddr] = f2b(v);
                else                    ((float*)Cv)[caddr] = v;
            }
        }
    }
}

// ---------- MFMA retention + fused groupnorm (dbuf async staging, paired grid) ----------
// grid 512 (1D). QKVG (B,S,6144): Q cols 0..1023, K 1024..2047, Yn written to 2048..4095.
// Vt (B,H,256,S).
__global__ __launch_bounds__(256) void retention_mfma(
    u16* __restrict__ QKVG, const u16* __restrict__ Vt,
    const float* __restrict__ gnw, const float* __restrict__ gnb) {
    __shared__ __align__(16) u16 Qs[4][64][32];
    __shared__ __align__(16) u16 Ks[2][4][32][32];
    __shared__ __align__(16) u16 Vs[2][256][32];
    __shared__ u16 Ss[64][40];
    const int id = blockIdx.x;
    const int halfg = id >> 8, r5 = id & 255;
    const int bh = r5 >> 4, i16 = r5 & 15;
    const int tile = halfg ? i16 : 31 - i16;   // pair (i, i+256) work = 68 steps const
    const int b = bh >> 3, h = bh & 7;
    const int t = threadIdx.x;
    const int wave = t >> 6, lane = t & 63, quad = lane >> 4, l16 = lane & 15;
    const u32 lo = __builtin_amdgcn_readfirstlane((u32)(wave * 1024));
    const u16* Qbase = QKVG + (long)b * 2048 * 6144 + h * 128;
    const u16* Kbase = Qbase + 1024;
    const u16* Vbase = Vt + (long)(b * 8 + h) * 256 * 2048;
    u16* Yn = QKVG + (long)b * 2048 * 6144 + 2048 + h * 256;

    float g = 1.f - expf(-3.4657359027997265f + (-0.3960841031771116f) * (float)h);
    float log2g = log2f(g);

    auto issueKV = [&](int jt, int buf) {
#pragma unroll
        for (int i = 0; i < 2; i++) {
            int c = t + i * 256;
            int ks = c >> 7, row = (c >> 2) & 31, cb = c & 3;
            async_ld16(Kbase + (long)(jt*32 + row) * 6144 + ks*32 + cb*8,
                       (const char*)Ks + buf*8192 + i*4096 + lo);
        }
#pragma unroll
        for (int i = 0; i < 4; i++) {
            int c = t + i * 256;
            int row = c >> 2, cb = c & 3;
            async_ld16(Vbase + (long)row * 2048 + jt*32 + cb*8,
                       (const char*)Vs + buf*16384 + i*4096 + lo);
        }
    };

    // prologue: Q tile + (K,V) for jt=0 into buf 0
#pragma unroll
    for (int i = 0; i < 4; i++) {
        int c = t + i * 256;
        int ks = c >> 8, row = (c >> 2) & 63, cb = c & 3;
        async_ld16(Qbase + (long)(tile*64 + row) * 6144 + ks*32 + cb*8,
                   (const char*)Qs + i*4096 + lo);
    }
    issueKV(0, 0);

    float gw[16], gbv[16];
#pragma unroll
    for (int nt = 0; nt < 16; nt++) {
        gw[nt]  = gnw[h*256 + nt*16 + l16];
        gbv[nt] = gnb[h*256 + nt*16 + l16];
    }
    f32x4 oacc[16];
#pragma unroll
    for (int nt = 0; nt < 16; nt++) oacc[nt] = (f32x4){0.f, 0.f, 0.f, 0.f};
    __syncthreads();

    const int njt = 2 * tile + 2;
    for (int jt = 0; jt < njt; jt++) {
        const int cur = jt & 1;
        if (jt + 1 < njt) issueKV(jt + 1, cur ^ 1);   // prefetch overlaps compute
        // QK^T
        f32x4 s0 = (f32x4){0.f,0.f,0.f,0.f}, s1 = (f32x4){0.f,0.f,0.f,0.f};
#pragma unroll
        for (int ks = 0; ks < 4; ks++) {
            short8 aq = *(const short8*)&Qs[ks][wave*16 + l16][quad*8];
            short8 b0 = *(const short8*)&Ks[cur][ks][l16][quad*8];
            short8 b1 = *(const short8*)&Ks[cur][ks][16 + l16][quad*8];
            s0 = __builtin_amdgcn_mfma_f32_16x16x32_bf16(aq, b0, s0, 0, 0, 0);
            s1 = __builtin_amdgcn_mfma_f32_16x16x32_bf16(aq, b1, s1, 0, 0, 0);
        }
        // decay + causal mask -> Ss (wave-private rows: no barrier needed)
#pragma unroll
        for (int reg = 0; reg < 4; reg++) {
            int srow = tile*64 + wave*16 + quad*4 + reg;
            int tc0 = jt*32 + l16, tc1 = tc0 + 16;
            float d0 = (srow >= tc0) ? exp2f(log2g * (float)(srow - tc0)) : 0.f;
            float d1 = (srow >= tc1) ? exp2f(log2g * (float)(srow - tc1)) : 0.f;
            Ss[wave*16 + quad*4 + reg][l16]      = f2b(s0[reg] * d0);
            Ss[wave*16 + quad*4 + reg][16 + l16] = f2b(s1[reg] * d1);
        }
        // PV: O[64x256] += S[64x32] @ V[32x256]
        short8 as = *(const short8*)&Ss[wave*16 + l16][quad*8];
#pragma unroll
        for (int nt = 0; nt < 16; nt++) {
            short8 bv = *(const short8*)&Vs[cur][nt*16 + l16][quad*8];
            oacc[nt] = __builtin_amdgcn_mfma_f32_16x16x32_bf16(as, bv, oacc[nt], 0, 0, 0);
        }
        __syncthreads();   // drains prefetch + guards buf reuse
    }

    // fused groupnorm over 256 v-dims per row + strided write into V-segment
#pragma unroll
    for (int reg = 0; reg < 4; reg++) {
        float s = 0.f, q = 0.f;
#pragma unroll
        for (int nt = 0; nt < 16; nt++) { float v = oacc[nt][reg]; s += v; q += v*v; }
#pragma unroll
        for (int m = 1; m < 16; m <<= 1) { s += __shfl_xor(s, m, 16); q += __shfl_xor(q, m, 16); }
        float mean = s * (1.f/256.f);
        float var  = q * (1.f/256.f) - mean*mean;
        float rstd = rsqrtf(var + 1e-5f);
        int srow = tile*64 + wave*16 + quad*4 + reg;
        u16* yrow = Yn + (long)srow * 6144;
#pragma unroll
        for (int nt = 0; nt < 16; nt++) {
            float y = (oacc[nt][reg] - mean) * rstd * gw[nt] + gbv[nt];
            yrow[nt*16 + l16] = f2b(y);
        }
    }
}

// ---------- gated = G*sigmoid(G)*Yn, in-place on G-segment of QKVG ----------
__global__ __launch_bounds__(256) void gate_kernel(u16* __restrict__ QKVG) {
    long base = (long)blockIdx.x * 6144;
    int c = threadIdx.x * 8;
    uint4 gp = *(const uint4*)(QKVG + base + 4096 + c);
    uint4 yp = *(const uint4*)(QKVG + base + 2048 + c);
    u32 gv[4] = {gp.x, gp.y, gp.z, gp.w};
    u32 yv[4] = {yp.x, yp.y, yp.z, yp.w};
    u32 ov[4];
#pragma unroll
    for (int j = 0; j < 4; j++) {
        float g0 = b2f((u16)(gv[j] & 0xFFFF)), g1 = b2f((u16)(gv[j] >> 16));
        float y0 = b2f((u16)(yv[j] & 0xFFFF)), y1 = b2f((u16)(yv[j] >> 16));
        float r0 = g0 * (1.f / (1.f + expf(-g0))) * y0;
        float r1 = g1 * (1.f / (1.f + expf(-g1))) * y1;
        ov[j] = (u32)f2b(r0) | ((u32)f2b(r1) << 16);
    }
    *(uint4*)(QKVG + base + 4096 + c) = make_uint4(ov[0], ov[1], ov[2], ov[3]);
}

extern "C" void kernel_launch(void* const* d_in, const int* in_sizes, int n_in,
                              void* d_out, int out_size, void* d_ws, size_t ws_size,
                              hipStream_t stream) {
    (void)in_sizes; (void)n_in; (void)out_size; (void)ws_size;
    const float* X    = (const float*)d_in[0];
    const float* Wq   = (const float*)d_in[1];
    const float* Wk   = (const float*)d_in[2];
    const float* Wv   = (const float*)d_in[3];
    const float* WG   = (const float*)d_in[4];
    const float* WO   = (const float*)d_in[5];
    const float* gnw  = (const float*)d_in[6];
    const float* gnb  = (const float*)d_in[7];
    const float* ln1w = (const float*)d_in[8];
    const float* ln1b = (const float*)d_in[9];
    const float* ln2w = (const float*)d_in[10];
    const float* ln2b = (const float*)d_in[11];
    const float* fw1  = (const float*)d_in[12];
    const float* fb1  = (const float*)d_in[13];
    const float* fw2  = (const float*)d_in[14];
    const float* fb2  = (const float*)d_in[15];

    constexpr int D = 1024, FFN = 4096;
    constexpr int M = 4096; // B*S rows
    constexpr long MB = 1048576;

    char* ws = (char*)d_ws;
    // [0,32) MB: combined transposed weights (persistent)
    //   rows 0..1023 Wq^T (8 heads x128), 1024..2047 Wk^T, 2048..4095 Wv^T, 4096..6143 WG^T
    u16* WT   = (u16*)(ws + 0*MB);
    u16* WOT  = (u16*)(ws + 12*MB);   // (1024, 2048)
    u16* fw1T = (u16*)(ws + 16*MB);   // (4096, 1024)
    u16* fw2T = (u16*)(ws + 24*MB);   // (1024, 4096)
    // activations:
    u16*   QKVG = (u16*)(ws + 32*MB); // bf16 (B,S,6144) 48 MB  [QKVG gemm .. WO]
    u16*   Xn   = (u16*)(ws + 80*MB); // bf16 (B,S,D)     8 MB  [LN1 .. QKVG gemm]
    u16*   Vt   = (u16*)(ws + 80*MB); // bf16 (B,H,256,S)16 MB  [vtrans .. retention] (reuses Xn)
    float* X2   = (float*)(ws + 80*MB);//fp32 (B,S,D)    16 MB  [WO .. final]         (reuses Vt)
    u16*   hb   = (u16*)(ws + 32*MB); // bf16 (B,S,D)     8 MB  [LN2 .. FFN1]         (reuses QKVG)
    u16*   mid  = (u16*)(ws + 40*MB); // bf16 (B,S,FFN)  32 MB  [FFN1 .. FFN2]

    // 0. weight transpose + bf16 convert (into combined WT + separates)
    wtrans<<<dim3(32, 4, 8),   256, 0, stream>>>(Wq,  WT,            D, 128);
    wtrans<<<dim3(32, 4, 8),   256, 0, stream>>>(Wk,  WT + 1048576,  D, 128);
    wtrans<<<dim3(32, 8, 8),   256, 0, stream>>>(Wv,  WT + 2097152,  D, 256);
    wtrans<<<dim3(32, 64, 1),  256, 0, stream>>>(WG,  WT + 4194304,  D, 2048);
    wtrans<<<dim3(64, 32, 1),  256, 0, stream>>>(WO,  WOT,  2048, D);
    wtrans<<<dim3(32, 128, 1), 256, 0, stream>>>(fw1, fw1T, D, FFN);
    wtrans<<<dim3(128, 32, 1), 256, 0, stream>>>(fw2, fw2T, FFN, D);
    // 1. LN1 -> Xn bf16
    ln_k<<<M, 256, 0, stream>>>(X, ln1w, ln1b, Xn);
    // 2. fused QKVG projection + xPos epilogue -> QKVG (B,S,6144)
    mgemm<EPI_QKVG, true><<<1536, 256, 0, stream>>>(
        Xn, WT, QKVG, 6144, D, 48, D, 6144, nullptr, nullptr);
    // 3. V^T (B,H,256,S)
    vtrans<<<dim3(64, 8, 16), 256, 0, stream>>>(QKVG + 2048, Vt);
    // 4. retention + groupnorm -> Yn in V-segment of QKVG
    retention_mfma<<<512, 256, 0, stream>>>(QKVG, Vt, gnw, gnb);
    // 5. gated = silu(G) * Yn, in-place on G-segment
    gate_kernel<<<M, 256, 0, stream>>>(QKVG);
    // 6. X2 = gated @ W_O + X  (fp32)
    mgemm<EPI_RESID, false><<<256, 256, 0, stream>>>(
        QKVG + 4096, WOT, X2, D, 2048, 8, 6144, D, nullptr, X);
    // 7. LN2 (fp32 in, bf16 out)
    ln_k<<<M, 256, 0, stream>>>(X2, ln2w, ln2b, hb);
    // 8. mid = gelu(h @ W1 + b1)  bf16
    mgemm<EPI_GELU_BIAS, true><<<1024, 256, 0, stream>>>(
        hb, fw1T, mid, FFN, D, 32, D, FFN, fb1, nullptr);
    // 9. out = mid @ W2 + b2 + X2  (fp32 -> d_out)
    mgemm<EPI_BIAS_RESID, false><<<256, 256, 0, stream>>>(
        mid, fw2T, (float*)d_out, D, FFN, 8, FFN, D, fb2, X2);
}

// Round 7
// 550.613 us; speedup vs baseline: 6.5546x; 1.0715x over previous
//
#include <hip/hip_runtime.h>
#include <hip/hip_bf16.h>

typedef unsigned short u16;
typedef unsigned int   u32;
typedef short short8 __attribute__((ext_vector_type(8)));
typedef float f32x4  __attribute__((ext_vector_type(4)));

// ---------- bf16 helpers ----------
__device__ __forceinline__ float b2f(u16 u) { return __uint_as_float(((u32)u) << 16); }
__device__ __forceinline__ u16 f2b(float f) {
    u32 u = __float_as_uint(f);
    u += 0x7FFF + ((u >> 16) & 1);   // RTNE
    return (u16)(u >> 16);
}

// ---------- async global->LDS 16B (wave-uniform LDS base + lane*16) ----------
typedef const unsigned int __attribute__((address_space(1)))* gas1;
typedef unsigned int __attribute__((address_space(3)))* las3;
__device__ __forceinline__ void async_ld16(const void* g, const void* l) {
    __builtin_amdgcn_global_load_lds((gas1)(unsigned long long)g,
                                     (las3)(unsigned int)(unsigned long long)l,
                                     16, 0, 0);
}

// ---------- xPos table: (2048 s) x (64 j) x {cs*sc, sn*sc, cs/sc, sn/sc} ----------
__global__ __launch_bounds__(256) void xtab_k(float4* __restrict__ tab) {
    int idx = blockIdx.x * 256 + threadIdx.x;   // 0..131071
    int j = idx & 63, s = idx >> 6;
    float sv = (2.f * j + 51.2f) / 179.2f;
    float scale = exp2f(log2f(sv) * ((float)s * (1.f / 512.f)));
    float inv_freq = exp2f((float)j * (-13.287712379549449f / 64.f));
    float ang = (float)s * inv_freq;
    float sn = sinf(ang), cs = cosf(ang);
    tab[idx] = make_float4(cs * scale, sn * scale, cs / scale, sn / scale);
}

// ---------- LayerNorm (row = 1024 fp32 elems, 256 threads) ----------
__global__ __launch_bounds__(256) void ln_k(const float* __restrict__ X,
                                            const float* __restrict__ w,
                                            const float* __restrict__ bb,
                                            u16* __restrict__ out) {
    const long row = blockIdx.x;
    const int t = threadIdx.x;
    float4 p = ((const float4*)(X + row * 1024))[t];
    float x[4] = { p.x, p.y, p.z, p.w };
    float s = x[0]+x[1]+x[2]+x[3];
    float q = x[0]*x[0]+x[1]*x[1]+x[2]*x[2]+x[3]*x[3];
#pragma unroll
    for (int o = 32; o > 0; o >>= 1) { s += __shfl_down(s, o, 64); q += __shfl_down(q, o, 64); }
    __shared__ float aS[4], aQ[4];
    if ((t & 63) == 0) { aS[t >> 6] = s; aQ[t >> 6] = q; }
    __syncthreads();
    s = aS[0]+aS[1]+aS[2]+aS[3];
    q = aQ[0]+aQ[1]+aQ[2]+aQ[3];
    float mean = s * (1.f/1024.f);
    float var  = q * (1.f/1024.f) - mean*mean;
    float rstd = rsqrtf(var + 1e-5f);
    float4 wv = ((const float4*)w)[t];
    float4 bv = ((const float4*)bb)[t];
    float y[4];
    y[0] = (x[0]-mean)*rstd*wv.x + bv.x;
    y[1] = (x[1]-mean)*rstd*wv.y + bv.y;
    y[2] = (x[2]-mean)*rstd*wv.z + bv.z;
    y[3] = (x[3]-mean)*rstd*wv.w + bv.w;
    uint2 r;
    r.x = (u32)f2b(y[0]) | ((u32)f2b(y[1]) << 16);
    r.y = (u32)f2b(y[2]) | ((u32)f2b(y[3]) << 16);
    ((uint2*)(out + row * 1024))[t] = r;
}

// ---------- weight transpose+convert: W [z][K][N] fp32 -> Wt [z][N][K] bf16 ----------
__global__ __launch_bounds__(256) void wtrans(const float* __restrict__ W, u16* __restrict__ Wt,
                                              int K, int N) {
    __shared__ u16 tile[32][36];
    const int k0 = blockIdx.x * 32, n0 = blockIdx.y * 32, z = blockIdx.z;
    const float* Wz = W + (long)z * K * N;
    u16* Wtz = Wt + (long)z * K * N;
    const int t = threadIdx.x;
    const int r = t >> 3, c = (t & 7) * 4;
    float4 v = *(const float4*)(Wz + (long)(k0 + r) * N + n0 + c);
    tile[r][c+0] = f2b(v.x); tile[r][c+1] = f2b(v.y);
    tile[r][c+2] = f2b(v.z); tile[r][c+3] = f2b(v.w);
    __syncthreads();
    u16 o0 = tile[c+0][r], o1 = tile[c+1][r], o2 = tile[c+2][r], o3 = tile[c+3][r];
    uint2 pk;
    pk.x = (u32)o0 | ((u32)o1 << 16);
    pk.y = (u32)o2 | ((u32)o3 << 16);
    *(uint2*)(Wtz + (long)(n0 + r) * K + k0 + c) = pk;
}

// ---------- V transpose (bf16): QKVG V-segment (B,S,6144)+2048 -> Vt (B,H,256,S) ----------
__global__ __launch_bounds__(256) void vtrans(const u16* __restrict__ Vseg, u16* __restrict__ Vt) {
    __shared__ u16 tile[32][36];
    const int s0 = blockIdx.x * 32, v0 = blockIdx.y * 32, z = blockIdx.z; // z = b*8+h
    const int b = z >> 3, h = z & 7;
    const u16* Vz = Vseg + (long)b * 2048 * 6144 + h * 256;
    u16* Vtz = Vt + (long)z * 256 * 2048;
    const int t = threadIdx.x;
    const int r = t >> 3, c = (t & 7) * 4;
    uint2 ld = *(const uint2*)(Vz + (long)(s0 + r) * 6144 + v0 + c);
    tile[r][c+0] = (u16)(ld.x & 0xFFFF); tile[r][c+1] = (u16)(ld.x >> 16);
    tile[r][c+2] = (u16)(ld.y & 0xFFFF); tile[r][c+3] = (u16)(ld.y >> 16);
    __syncthreads();
    uint2 pk;
    pk.x = (u32)tile[c+0][r] | ((u32)tile[c+1][r] << 16);
    pk.y = (u32)tile[c+2][r] | ((u32)tile[c+3][r] << 16);
    *(uint2*)(Vtz + (long)(v0 + r) * 2048 + s0 + c) = pk;
}

// ---------- MFMA GEMM (m97 structure): C = A[M][K] @ Bt[N][K]^T, bf16->fp32 ----------
// Block order: mb innermost (mb = pid & 31) -> XCD x pins mb%8==x (A L2-resident),
// B streamed once per XCD. M hardcoded 4096 (32 mb tiles).
enum { EPI_NONE = 0, EPI_RESID = 1, EPI_GELU_BIAS = 2, EPI_BIAS_RESID = 3, EPI_QKVG = 4 };

template<int EPI, bool OUT_BF16>
__global__ __launch_bounds__(256) void mgemm(
    const u16* __restrict__ A, const u16* __restrict__ Bt, void* __restrict__ Cv,
    int N, int K, int aStride, long cStride,
    const float* __restrict__ bias, const float* __restrict__ resid) {
    __shared__ __align__(16) u16 As[128 * 32];
    __shared__ __align__(16) u16 Bs[128 * 32];
    const int pid = blockIdx.x;
    const int mb = pid & 31;
    const int nb = pid >> 5;
    const int t = threadIdx.x;
    const int row0 = mb * 128, col0 = nb * 128;
    const int wave = t >> 6, lane = t & 63;
    const int wm = wave >> 1, wn = wave & 1;
    const int quad = lane >> 4, l16 = lane & 15;
    const u16* Ag = A + (long)(row0 + (t >> 2)) * aStride + ((t & 3) * 8);
    const u16* Bg = Bt + (long)(col0 + (t >> 2)) * K + ((t & 3) * 8);
    const long aj = (long)64 * aStride;
    const long bj = (long)64 * K;
    const u32 lo = __builtin_amdgcn_readfirstlane((u32)(wave * 1024));

    f32x4 acc[4][4];
#pragma unroll
    for (int i = 0; i < 4; i++)
#pragma unroll
        for (int j = 0; j < 4; j++) acc[i][j] = (f32x4){0.f, 0.f, 0.f, 0.f};

    for (int k0 = 0; k0 < K; k0 += 32) {
        async_ld16(Ag + k0,      (const char*)As + lo);
        async_ld16(Ag + k0 + aj, (const char*)As + 4096 + lo);
        async_ld16(Bg + k0,      (const char*)Bs + lo);
        async_ld16(Bg + k0 + bj, (const char*)Bs + 4096 + lo);
        __syncthreads();
        short8 af[4], bf[4];
#pragma unroll
        for (int mt = 0; mt < 4; mt++)
            af[mt] = *(const short8*)(As + (wm*64 + mt*16 + l16) * 32 + quad*8);
#pragma unroll
        for (int nt = 0; nt < 4; nt++)
            bf[nt] = *(const short8*)(Bs + (wn*64 + nt*16 + l16) * 32 + quad*8);
#pragma unroll
        for (int mt = 0; mt < 4; mt++)
#pragma unroll
            for (int nt = 0; nt < 4; nt++)
                acc[mt][nt] = __builtin_amdgcn_mfma_f32_16x16x32_bf16(af[mt], bf[nt], acc[mt][nt], 0, 0, 0);
        __syncthreads();
    }

#pragma unroll
    for (int mt = 0; mt < 4; mt++) {
#pragma unroll
        for (int reg = 0; reg < 4; reg++) {
            int r = row0 + wm*64 + mt*16 + quad*4 + reg;
#pragma unroll
            for (int nt = 0; nt < 4; nt++) {
                int c = col0 + wn*64 + nt*16 + l16;
                float v = acc[mt][nt][reg];
                if constexpr (EPI == EPI_RESID) {
                    v += resid[(long)r * N + c];
                } else if constexpr (EPI == EPI_GELU_BIAS) {
                    v += bias[c];
                    v = 0.5f * v * (1.f + erff(v * 0.70710678118654752f));
                } else if constexpr (EPI == EPI_BIAS_RESID) {
                    v += bias[c] + resid[(long)r * N + c];
                } else if constexpr (EPI == EPI_QKVG) {
                    if (c < 2048) {  // xPos rotary: Q (c<1024, up) / K (else, down) via table
                        int j = (c & 127) >> 1;
                        float4 tb = ((const float4*)bias)[((r & 2047) << 6) + j];
                        float cs = (c < 1024) ? tb.x : tb.z;
                        float sn = (c < 1024) ? tb.y : tb.w;
                        float partner = __shfl_xor(v, 1, 64);
                        v = v * cs + ((c & 1) ? partner : -partner) * sn;
                    }
                }
                long caddr = (long)r * cStride + c;
                if constexpr (OUT_BF16) ((u16*)Cv)[caddr] = f2b(v);
                else                    ((float*)Cv)[caddr] = v;
            }
        }
    }
}

// ---------- MFMA retention + fused groupnorm + fused silu-gate ----------
// grid 512 (1D). QKVG (B,S,6144): Q cols 0..1023, K 1024..2047, V 2048..4095, G 4096..6143.
// Writes gated = silu(G)*groupnorm(O) in-place over the G segment. Vt (B,H,256,S).
__global__ __launch_bounds__(256) void retention_mfma(
    u16* __restrict__ QKVG, const u16* __restrict__ Vt,
    const float* __restrict__ gnw, const float* __restrict__ gnb) {
    __shared__ __align__(16) u16 Qs[4][64][32];
    __shared__ __align__(16) u16 Ks[2][4][32][32];
    __shared__ __align__(16) u16 Vs[2][256][32];
    __shared__ u16 Ss[64][40];
    const int id = blockIdx.x;
    const int halfg = id >> 8, r5 = id & 255;
    const int bh = r5 >> 4, i16 = r5 & 15;
    const int tile = halfg ? i16 : 31 - i16;   // pair (i, i+256) work = 68 steps const
    const int b = bh >> 3, h = bh & 7;
    const int t = threadIdx.x;
    const int wave = t >> 6, lane = t & 63, quad = lane >> 4, l16 = lane & 15;
    const u32 lo = __builtin_amdgcn_readfirstlane((u32)(wave * 1024));
    const u16* Qbase = QKVG + (long)b * 2048 * 6144 + h * 128;
    const u16* Kbase = Qbase + 1024;
    const u16* Vbase = Vt + (long)(b * 8 + h) * 256 * 2048;
    u16* Gseg = QKVG + (long)b * 2048 * 6144 + 4096 + h * 256;

    float g = 1.f - expf(-3.4657359027997265f + (-0.3960841031771116f) * (float)h);
    float log2g = log2f(g);

    auto issueKV = [&](int jt, int buf) {
#pragma unroll
        for (int i = 0; i < 2; i++) {
            int c = t + i * 256;
            int ks = c >> 7, row = (c >> 2) & 31, cb = c & 3;
            async_ld16(Kbase + (long)(jt*32 + row) * 6144 + ks*32 + cb*8,
                       (const char*)Ks + buf*8192 + i*4096 + lo);
        }
#pragma unroll
        for (int i = 0; i < 4; i++) {
            int c = t + i * 256;
            int row = c >> 2, cb = c & 3;
            async_ld16(Vbase + (long)row * 2048 + jt*32 + cb*8,
                       (const char*)Vs + buf*16384 + i*4096 + lo);
        }
    };

    // prologue: Q tile + (K,V) for jt=0 into buf 0
#pragma unroll
    for (int i = 0; i < 4; i++) {
        int c = t + i * 256;
        int ks = c >> 8, row = (c >> 2) & 63, cb = c & 3;
        async_ld16(Qbase + (long)(tile*64 + row) * 6144 + ks*32 + cb*8,
                   (const char*)Qs + i*4096 + lo);
    }
    issueKV(0, 0);

    float gw[16], gbv[16];
#pragma unroll
    for (int nt = 0; nt < 16; nt++) {
        gw[nt]  = gnw[h*256 + nt*16 + l16];
        gbv[nt] = gnb[h*256 + nt*16 + l16];
    }
    f32x4 oacc[16];
#pragma unroll
    for (int nt = 0; nt < 16; nt++) oacc[nt] = (f32x4){0.f, 0.f, 0.f, 0.f};
    __syncthreads();

    const int njt = 2 * tile + 2;
    for (int jt = 0; jt < njt; jt++) {
        const int cur = jt & 1;
        if (jt + 1 < njt) issueKV(jt + 1, cur ^ 1);   // prefetch overlaps compute
        // QK^T
        f32x4 s0 = (f32x4){0.f,0.f,0.f,0.f}, s1 = (f32x4){0.f,0.f,0.f,0.f};
#pragma unroll
        for (int ks = 0; ks < 4; ks++) {
            short8 aq = *(const short8*)&Qs[ks][wave*16 + l16][quad*8];
            short8 b0 = *(const short8*)&Ks[cur][ks][l16][quad*8];
            short8 b1 = *(const short8*)&Ks[cur][ks][16 + l16][quad*8];
            s0 = __builtin_amdgcn_mfma_f32_16x16x32_bf16(aq, b0, s0, 0, 0, 0);
            s1 = __builtin_amdgcn_mfma_f32_16x16x32_bf16(aq, b1, s1, 0, 0, 0);
        }
        // decay + causal mask -> Ss (wave-private rows: no barrier needed)
#pragma unroll
        for (int reg = 0; reg < 4; reg++) {
            int srow = tile*64 + wave*16 + quad*4 + reg;
            int tc0 = jt*32 + l16, tc1 = tc0 + 16;
            float d0 = (srow >= tc0) ? exp2f(log2g * (float)(srow - tc0)) : 0.f;
            float d1 = (srow >= tc1) ? exp2f(log2g * (float)(srow - tc1)) : 0.f;
            Ss[wave*16 + quad*4 + reg][l16]      = f2b(s0[reg] * d0);
            Ss[wave*16 + quad*4 + reg][16 + l16] = f2b(s1[reg] * d1);
        }
        // PV: O[64x256] += S[64x32] @ V[32x256]
        short8 as = *(const short8*)&Ss[wave*16 + l16][quad*8];
#pragma unroll
        for (int nt = 0; nt < 16; nt++) {
            short8 bv = *(const short8*)&Vs[cur][nt*16 + l16][quad*8];
            oacc[nt] = __builtin_amdgcn_mfma_f32_16x16x32_bf16(as, bv, oacc[nt], 0, 0, 0);
        }
        __syncthreads();   // drains prefetch + guards buf reuse
    }

    // fused groupnorm + silu(G) gate, written in-place over G segment
#pragma unroll
    for (int reg = 0; reg < 4; reg++) {
        float s = 0.f, q = 0.f;
#pragma unroll
        for (int nt = 0; nt < 16; nt++) { float v = oacc[nt][reg]; s += v; q += v*v; }
#pragma unroll
        for (int m = 1; m < 16; m <<= 1) { s += __shfl_xor(s, m, 16); q += __shfl_xor(q, m, 16); }
        float mean = s * (1.f/256.f);
        float var  = q * (1.f/256.f) - mean*mean;
        float rstd = rsqrtf(var + 1e-5f);
        int srow = tile*64 + wave*16 + quad*4 + reg;
        u16* grow = Gseg + (long)srow * 6144;
#pragma unroll
        for (int nt = 0; nt < 16; nt++) {
            float gval = b2f(grow[nt*16 + l16]);
            float y = (oacc[nt][reg] - mean) * rstd * gw[nt] + gbv[nt];
            float sg = gval / (1.f + expf(-gval));
            grow[nt*16 + l16] = f2b(sg * y);
        }
    }
}

extern "C" void kernel_launch(void* const* d_in, const int* in_sizes, int n_in,
                              void* d_out, int out_size, void* d_ws, size_t ws_size,
                              hipStream_t stream) {
    (void)in_sizes; (void)n_in; (void)out_size; (void)ws_size;
    const float* X    = (const float*)d_in[0];
    const float* Wq   = (const float*)d_in[1];
    const float* Wk   = (const float*)d_in[2];
    const float* Wv   = (const float*)d_in[3];
    const float* WG   = (const float*)d_in[4];
    const float* WO   = (const float*)d_in[5];
    const float* gnw  = (const float*)d_in[6];
    const float* gnb  = (const float*)d_in[7];
    const float* ln1w = (const float*)d_in[8];
    const float* ln1b = (const float*)d_in[9];
    const float* ln2w = (const float*)d_in[10];
    const float* ln2b = (const float*)d_in[11];
    const float* fw1  = (const float*)d_in[12];
    const float* fb1  = (const float*)d_in[13];
    const float* fw2  = (const float*)d_in[14];
    const float* fb2  = (const float*)d_in[15];

    constexpr int D = 1024, FFN = 4096;
    constexpr int M = 4096; // B*S rows
    constexpr long MB = 1048576;

    char* ws = (char*)d_ws;
    // [0,32) MB: combined transposed weights (persistent)
    //   rows 0..1023 Wq^T (8 heads x128), 1024..2047 Wk^T, 2048..4095 Wv^T, 4096..6143 WG^T
    u16* WT   = (u16*)(ws + 0*MB);
    u16* WOT  = (u16*)(ws + 12*MB);   // (1024, 2048)
    u16* fw1T = (u16*)(ws + 16*MB);   // (4096, 1024)
    u16* fw2T = (u16*)(ws + 24*MB);   // (1024, 4096)
    // activations:
    u16*   QKVG = (u16*)(ws + 32*MB); // bf16 (B,S,6144) 48 MB  [QKVG gemm .. WO]
    u16*   Xn   = (u16*)(ws + 80*MB); // bf16 (B,S,D)     8 MB  [LN1 .. QKVG gemm]
    float4* xtab= (float4*)(ws + 88*MB);// fp32 table     2 MB  [setup .. QKVG gemm]
    u16*   Vt   = (u16*)(ws + 80*MB); // bf16 (B,H,256,S)16 MB  [vtrans .. retention] (reuses Xn+xtab)
    float* X2   = (float*)(ws + 80*MB);//fp32 (B,S,D)    16 MB  [WO .. final]         (reuses Vt)
    u16*   hb   = (u16*)(ws + 32*MB); // bf16 (B,S,D)     8 MB  [LN2 .. FFN1]         (reuses QKVG)
    u16*   mid  = (u16*)(ws + 40*MB); // bf16 (B,S,FFN)  32 MB  [FFN1 .. FFN2]

    // 0. weight transpose + bf16 convert (into combined WT + separates), xPos table
    wtrans<<<dim3(32, 4, 8),   256, 0, stream>>>(Wq,  WT,            D, 128);
    wtrans<<<dim3(32, 4, 8),   256, 0, stream>>>(Wk,  WT + 1048576,  D, 128);
    wtrans<<<dim3(32, 8, 8),   256, 0, stream>>>(Wv,  WT + 2097152,  D, 256);
    wtrans<<<dim3(32, 64, 1),  256, 0, stream>>>(WG,  WT + 4194304,  D, 2048);
    wtrans<<<dim3(64, 32, 1),  256, 0, stream>>>(WO,  WOT,  2048, D);
    wtrans<<<dim3(32, 128, 1), 256, 0, stream>>>(fw1, fw1T, D, FFN);
    wtrans<<<dim3(128, 32, 1), 256, 0, stream>>>(fw2, fw2T, FFN, D);
    xtab_k<<<512, 256, 0, stream>>>(xtab);
    // 1. LN1 -> Xn bf16
    ln_k<<<M, 256, 0, stream>>>(X, ln1w, ln1b, Xn);
    // 2. fused QKVG projection + xPos table epilogue -> QKVG (B,S,6144)
    mgemm<EPI_QKVG, true><<<1536, 256, 0, stream>>>(
        Xn, WT, QKVG, 6144, D, D, 6144, (const float*)xtab, nullptr);
    // 3. V^T (B,H,256,S)
    vtrans<<<dim3(64, 8, 16), 256, 0, stream>>>(QKVG + 2048, Vt);
    // 4. retention + groupnorm + silu-gate -> in-place on G segment
    retention_mfma<<<512, 256, 0, stream>>>(QKVG, Vt, gnw, gnb);
    // 5. X2 = gated @ W_O + X  (fp32)
    mgemm<EPI_RESID, false><<<256, 256, 0, stream>>>(
        QKVG + 4096, WOT, X2, D, 2048, 6144, D, nullptr, X);
    // 6. LN2 (fp32 in, bf16 out)
    ln_k<<<M, 256, 0, stream>>>(X2, ln2w, ln2b, hb);
    // 7. mid = gelu(h @ W1 + b1)  bf16
    mgemm<EPI_GELU_BIAS, true><<<1024, 256, 0, stream>>>(
        hb, fw1T, mid, FFN, D, D, FFN, fb1, nullptr);
    // 8. out = mid @ W2 + b2 + X2  (fp32 -> d_out)
    mgemm<EPI_BIAS_RESID, false><<<256, 256, 0, stream>>>(
        mid, fw2T, (float*)d_out, D, FFN, FFN, D, fb2, X2);
}

// Round 8
// 512.775 us; speedup vs baseline: 7.0383x; 1.0738x over previous
//
#include <hip/hip_runtime.h>
#include <hip/hip_bf16.h>

typedef unsigned short u16;
typedef unsigned int   u32;
typedef short short8 __attribute__((ext_vector_type(8)));
typedef float f32x4  __attribute__((ext_vector_type(4)));

// ---------- bf16 helpers ----------
__device__ __forceinline__ float b2f(u16 u) { return __uint_as_float(((u32)u) << 16); }
__device__ __forceinline__ u16 f2b(float f) {
    u32 u = __float_as_uint(f);
    u += 0x7FFF + ((u >> 16) & 1);   // RTNE
    return (u16)(u >> 16);
}

// ---------- async global->LDS 16B (wave-uniform LDS base + lane*16) ----------
typedef const unsigned int __attribute__((address_space(1)))* gas1;
typedef unsigned int __attribute__((address_space(3)))* las3;
__device__ __forceinline__ void async_ld16(const void* g, const void* l) {
    __builtin_amdgcn_global_load_lds((gas1)(unsigned long long)g,
                                     (las3)(unsigned int)(unsigned long long)l,
                                     16, 0, 0);
}

// ---------- xPos table: (2048 s) x (64 j) x {cs*sc, sn*sc, cs/sc, sn/sc} ----------
__global__ __launch_bounds__(256) void xtab_k(float4* __restrict__ tab) {
    int idx = blockIdx.x * 256 + threadIdx.x;   // 0..131071
    int j = idx & 63, s = idx >> 6;
    float sv = (2.f * j + 51.2f) / 179.2f;
    float scale = exp2f(log2f(sv) * ((float)s * (1.f / 512.f)));
    float inv_freq = exp2f((float)j * (-13.287712379549449f / 64.f));
    float ang = (float)s * inv_freq;
    float sn = sinf(ang), cs = cosf(ang);
    tab[idx] = make_float4(cs * scale, sn * scale, cs / scale, sn / scale);
}

// ---------- LayerNorm (row = 1024 fp32 elems, 256 threads) ----------
__global__ __launch_bounds__(256) void ln_k(const float* __restrict__ X,
                                            const float* __restrict__ w,
                                            const float* __restrict__ bb,
                                            u16* __restrict__ out) {
    const long row = blockIdx.x;
    const int t = threadIdx.x;
    float4 p = ((const float4*)(X + row * 1024))[t];
    float x[4] = { p.x, p.y, p.z, p.w };
    float s = x[0]+x[1]+x[2]+x[3];
    float q = x[0]*x[0]+x[1]*x[1]+x[2]*x[2]+x[3]*x[3];
#pragma unroll
    for (int o = 32; o > 0; o >>= 1) { s += __shfl_down(s, o, 64); q += __shfl_down(q, o, 64); }
    __shared__ float aS[4], aQ[4];
    if ((t & 63) == 0) { aS[t >> 6] = s; aQ[t >> 6] = q; }
    __syncthreads();
    s = aS[0]+aS[1]+aS[2]+aS[3];
    q = aQ[0]+aQ[1]+aQ[2]+aQ[3];
    float mean = s * (1.f/1024.f);
    float var  = q * (1.f/1024.f) - mean*mean;
    float rstd = rsqrtf(var + 1e-5f);
    float4 wv = ((const float4*)w)[t];
    float4 bv = ((const float4*)bb)[t];
    float y[4];
    y[0] = (x[0]-mean)*rstd*wv.x + bv.x;
    y[1] = (x[1]-mean)*rstd*wv.y + bv.y;
    y[2] = (x[2]-mean)*rstd*wv.z + bv.z;
    y[3] = (x[3]-mean)*rstd*wv.w + bv.w;
    uint2 r;
    r.x = (u32)f2b(y[0]) | ((u32)f2b(y[1]) << 16);
    r.y = (u32)f2b(y[2]) | ((u32)f2b(y[3]) << 16);
    ((uint2*)(out + row * 1024))[t] = r;
}

// ---------- combine WO partials + residual X, then LN2 -> X2 (fp32) and hb (bf16) ----------
// P = QKVG viewed as float rows of 3072: slice0 at +0, slice1 at +1024.
__global__ __launch_bounds__(256) void ln2_combine(const float* __restrict__ P,
                                                   const float* __restrict__ X,
                                                   const float* __restrict__ w,
                                                   const float* __restrict__ bb,
                                                   float* __restrict__ X2,
                                                   u16* __restrict__ hb) {
    const long row = blockIdx.x;
    const int t = threadIdx.x;
    const float* p = P + row * 3072;
    float4 a = ((const float4*)p)[t];
    float4 c = ((const float4*)(p + 1024))[t];
    float4 xr = ((const float4*)(X + row * 1024))[t];
    float x[4] = { a.x+c.x+xr.x, a.y+c.y+xr.y, a.z+c.z+xr.z, a.w+c.w+xr.w };
    ((float4*)(X2 + row * 1024))[t] = make_float4(x[0], x[1], x[2], x[3]);
    float s = x[0]+x[1]+x[2]+x[3];
    float q = x[0]*x[0]+x[1]*x[1]+x[2]*x[2]+x[3]*x[3];
#pragma unroll
    for (int o = 32; o > 0; o >>= 1) { s += __shfl_down(s, o, 64); q += __shfl_down(q, o, 64); }
    __shared__ float aS[4], aQ[4];
    if ((t & 63) == 0) { aS[t >> 6] = s; aQ[t >> 6] = q; }
    __syncthreads();
    s = aS[0]+aS[1]+aS[2]+aS[3];
    q = aQ[0]+aQ[1]+aQ[2]+aQ[3];
    float mean = s * (1.f/1024.f);
    float var  = q * (1.f/1024.f) - mean*mean;
    float rstd = rsqrtf(var + 1e-5f);
    float4 wv = ((const float4*)w)[t];
    float4 bv = ((const float4*)bb)[t];
    float y[4];
    y[0] = (x[0]-mean)*rstd*wv.x + bv.x;
    y[1] = (x[1]-mean)*rstd*wv.y + bv.y;
    y[2] = (x[2]-mean)*rstd*wv.z + bv.z;
    y[3] = (x[3]-mean)*rstd*wv.w + bv.w;
    uint2 r;
    r.x = (u32)f2b(y[0]) | ((u32)f2b(y[1]) << 16);
    r.y = (u32)f2b(y[2]) | ((u32)f2b(y[3]) << 16);
    ((uint2*)(hb + row * 1024))[t] = r;
}

// ---------- combine FFN2 partials + bias + X2 -> d_out (fp32) ----------
__global__ __launch_bounds__(256) void ffn2_combine(const float* __restrict__ P,
                                                    const float* __restrict__ b2,
                                                    const float* __restrict__ X2,
                                                    float* __restrict__ out) {
    const long row = blockIdx.x;
    const int t = threadIdx.x;
    float4 p0 = ((const float4*)(P + row * 1024))[t];
    float4 p1 = ((const float4*)(P + 16777216 + row * 1024))[t];
    float4 x2 = ((const float4*)(X2 + row * 1024))[t];
    float4 bv = ((const float4*)b2)[t];
    ((float4*)(out + row * 1024))[t] = make_float4(
        p0.x + p1.x + x2.x + bv.x, p0.y + p1.y + x2.y + bv.y,
        p0.z + p1.z + x2.z + bv.z, p0.w + p1.w + x2.w + bv.w);
}

// ---------- weight transpose+convert: W [z][K][N] fp32 -> Wt [z][N][K] bf16 ----------
__global__ __launch_bounds__(256) void wtrans(const float* __restrict__ W, u16* __restrict__ Wt,
                                              int K, int N) {
    __shared__ u16 tile[32][36];
    const int k0 = blockIdx.x * 32, n0 = blockIdx.y * 32, z = blockIdx.z;
    const float* Wz = W + (long)z * K * N;
    u16* Wtz = Wt + (long)z * K * N;
    const int t = threadIdx.x;
    const int r = t >> 3, c = (t & 7) * 4;
    float4 v = *(const float4*)(Wz + (long)(k0 + r) * N + n0 + c);
    tile[r][c+0] = f2b(v.x); tile[r][c+1] = f2b(v.y);
    tile[r][c+2] = f2b(v.z); tile[r][c+3] = f2b(v.w);
    __syncthreads();
    u16 o0 = tile[c+0][r], o1 = tile[c+1][r], o2 = tile[c+2][r], o3 = tile[c+3][r];
    uint2 pk;
    pk.x = (u32)o0 | ((u32)o1 << 16);
    pk.y = (u32)o2 | ((u32)o3 << 16);
    *(uint2*)(Wtz + (long)(n0 + r) * K + k0 + c) = pk;
}

// ---------- V transpose (bf16): QKVG V-segment (B,S,6144)+2048 -> Vt (B,H,256,S) ----------
__global__ __launch_bounds__(256) void vtrans(const u16* __restrict__ Vseg, u16* __restrict__ Vt) {
    __shared__ u16 tile[32][36];
    const int s0 = blockIdx.x * 32, v0 = blockIdx.y * 32, z = blockIdx.z; // z = b*8+h
    const int b = z >> 3, h = z & 7;
    const u16* Vz = Vseg + (long)b * 2048 * 6144 + h * 256;
    u16* Vtz = Vt + (long)z * 256 * 2048;
    const int t = threadIdx.x;
    const int r = t >> 3, c = (t & 7) * 4;
    uint2 ld = *(const uint2*)(Vz + (long)(s0 + r) * 6144 + v0 + c);
    tile[r][c+0] = (u16)(ld.x & 0xFFFF); tile[r][c+1] = (u16)(ld.x >> 16);
    tile[r][c+2] = (u16)(ld.y & 0xFFFF); tile[r][c+3] = (u16)(ld.y >> 16);
    __syncthreads();
    uint2 pk;
    pk.x = (u32)tile[c+0][r] | ((u32)tile[c+1][r] << 16);
    pk.y = (u32)tile[c+2][r] | ((u32)tile[c+3][r] << 16);
    *(uint2*)(Vtz + (long)(v0 + r) * 2048 + s0 + c) = pk;
}

// ---------- MFMA GEMM (m97 structure): C = A[M][K] @ Bt[N][K]^T, bf16->fp32 ----------
// Block order: mb innermost (mb = pid & 31). M hardcoded 4096 (32 mb tiles).
enum { EPI_GELU_BIAS = 2, EPI_QKVG = 4 };

template<int EPI>
__global__ __launch_bounds__(256) void mgemm(
    const u16* __restrict__ A, const u16* __restrict__ Bt, u16* __restrict__ Cv,
    int K, int aStride, long cStride,
    const float* __restrict__ bias) {
    __shared__ __align__(16) u16 As[128 * 32];
    __shared__ __align__(16) u16 Bs[128 * 32];
    const int pid = blockIdx.x;
    const int mb = pid & 31;
    const int nb = pid >> 5;
    const int t = threadIdx.x;
    const int row0 = mb * 128, col0 = nb * 128;
    const int wave = t >> 6, lane = t & 63;
    const int wm = wave >> 1, wn = wave & 1;
    const int quad = lane >> 4, l16 = lane & 15;
    const u16* Ag = A + (long)(row0 + (t >> 2)) * aStride + ((t & 3) * 8);
    const u16* Bg = Bt + (long)(col0 + (t >> 2)) * K + ((t & 3) * 8);
    const long aj = (long)64 * aStride;
    const long bj = (long)64 * K;
    const u32 lo = __builtin_amdgcn_readfirstlane((u32)(wave * 1024));

    f32x4 acc[4][4];
#pragma unroll
    for (int i = 0; i < 4; i++)
#pragma unroll
        for (int j = 0; j < 4; j++) acc[i][j] = (f32x4){0.f, 0.f, 0.f, 0.f};

    for (int k0 = 0; k0 < K; k0 += 32) {
        async_ld16(Ag + k0,      (const char*)As + lo);
        async_ld16(Ag + k0 + aj, (const char*)As + 4096 + lo);
        async_ld16(Bg + k0,      (const char*)Bs + lo);
        async_ld16(Bg + k0 + bj, (const char*)Bs + 4096 + lo);
        __syncthreads();
        short8 af[4], bf[4];
#pragma unroll
        for (int mt = 0; mt < 4; mt++)
            af[mt] = *(const short8*)(As + (wm*64 + mt*16 + l16) * 32 + quad*8);
#pragma unroll
        for (int nt = 0; nt < 4; nt++)
            bf[nt] = *(const short8*)(Bs + (wn*64 + nt*16 + l16) * 32 + quad*8);
#pragma unroll
        for (int mt = 0; mt < 4; mt++)
#pragma unroll
            for (int nt = 0; nt < 4; nt++)
                acc[mt][nt] = __builtin_amdgcn_mfma_f32_16x16x32_bf16(af[mt], bf[nt], acc[mt][nt], 0, 0, 0);
        __syncthreads();
    }

#pragma unroll
    for (int mt = 0; mt < 4; mt++) {
#pragma unroll
        for (int reg = 0; reg < 4; reg++) {
            int r = row0 + wm*64 + mt*16 + quad*4 + reg;
#pragma unroll
            for (int nt = 0; nt < 4; nt++) {
                int c = col0 + wn*64 + nt*16 + l16;
                float v = acc[mt][nt][reg];
                if constexpr (EPI == EPI_GELU_BIAS) {
                    v += bias[c];
                    v = 0.5f * v * (1.f + erff(v * 0.70710678118654752f));
                } else if constexpr (EPI == EPI_QKVG) {
                    if (c < 2048) {  // xPos rotary: Q (c<1024, up) / K (else, down) via table
                        int j = (c & 127) >> 1;
                        float4 tb = ((const float4*)bias)[((r & 2047) << 6) + j];
                        float cs = (c < 1024) ? tb.x : tb.z;
                        float sn = (c < 1024) ? tb.y : tb.w;
                        float partner = __shfl_xor(v, 1, 64);
                        v = v * cs + ((c & 1) ? partner : -partner) * sn;
                    }
                }
                Cv[(long)r * cStride + c] = f2b(v);
            }
        }
    }
}

// ---------- split-K (x2) MFMA GEMM, N=1024 (8 nb x 32 mb), fp32 partial out ----------
// grid 512: pid&255 -> tile (mb = pid&31, nb = (pid&255)>>5), slice = pid>>8.
// P addr (floats) = slice*sliceOff + r*pRowStride + c
__global__ __launch_bounds__(256) void mgemm_sk(
    const u16* __restrict__ A, const u16* __restrict__ Bt, float* __restrict__ P,
    int K, int kHalf, int aStride, long pRowStride, long sliceOff) {
    __shared__ __align__(16) u16 As[128 * 32];
    __shared__ __align__(16) u16 Bs[128 * 32];
    const int pid = blockIdx.x;
    const int mb = pid & 31;
    const int nb = (pid & 255) >> 5;
    const int slice = pid >> 8;
    const int t = threadIdx.x;
    const int row0 = mb * 128, col0 = nb * 128;
    const int wave = t >> 6, lane = t & 63;
    const int wm = wave >> 1, wn = wave & 1;
    const int quad = lane >> 4, l16 = lane & 15;
    const u16* Ag = A + (long)(row0 + (t >> 2)) * aStride + ((t & 3) * 8);
    const u16* Bg = Bt + (long)(col0 + (t >> 2)) * K + ((t & 3) * 8);
    const long aj = (long)64 * aStride;
    const long bj = (long)64 * K;
    const u32 lo = __builtin_amdgcn_readfirstlane((u32)(wave * 1024));

    f32x4 acc[4][4];
#pragma unroll
    for (int i = 0; i < 4; i++)
#pragma unroll
        for (int j = 0; j < 4; j++) acc[i][j] = (f32x4){0.f, 0.f, 0.f, 0.f};

    const int kBeg = slice * kHalf, kEnd = kBeg + kHalf;
    for (int k0 = kBeg; k0 < kEnd; k0 += 32) {
        async_ld16(Ag + k0,      (const char*)As + lo);
        async_ld16(Ag + k0 + aj, (const char*)As + 4096 + lo);
        async_ld16(Bg + k0,      (const char*)Bs + lo);
        async_ld16(Bg + k0 + bj, (const char*)Bs + 4096 + lo);
        __syncthreads();
        short8 af[4], bf[4];
#pragma unroll
        for (int mt = 0; mt < 4; mt++)
            af[mt] = *(const short8*)(As + (wm*64 + mt*16 + l16) * 32 + quad*8);
#pragma unroll
        for (int nt = 0; nt < 4; nt++)
            bf[nt] = *(const short8*)(Bs + (wn*64 + nt*16 + l16) * 32 + quad*8);
#pragma unroll
        for (int mt = 0; mt < 4; mt++)
#pragma unroll
            for (int nt = 0; nt < 4; nt++)
                acc[mt][nt] = __builtin_amdgcn_mfma_f32_16x16x32_bf16(af[mt], bf[nt], acc[mt][nt], 0, 0, 0);
        __syncthreads();
    }

    float* Pb = P + slice * sliceOff;
#pragma unroll
    for (int mt = 0; mt < 4; mt++) {
#pragma unroll
        for (int reg = 0; reg < 4; reg++) {
            int r = row0 + wm*64 + mt*16 + quad*4 + reg;
#pragma unroll
            for (int nt = 0; nt < 4; nt++) {
                int c = col0 + wn*64 + nt*16 + l16;
                Pb[(long)r * pRowStride + c] = acc[mt][nt][reg];
            }
        }
    }
}

// ---------- MFMA retention + fused groupnorm + fused silu-gate ----------
// grid 512 (1D). QKVG (B,S,6144): Q cols 0..1023, K 1024..2047, V 2048..4095, G 4096..6143.
// Writes gated = silu(G)*groupnorm(O) in-place over the G segment. Vt (B,H,256,S).
__global__ __launch_bounds__(256) void retention_mfma(
    u16* __restrict__ QKVG, const u16* __restrict__ Vt,
    const float* __restrict__ gnw, const float* __restrict__ gnb) {
    __shared__ __align__(16) u16 Qs[4][64][32];
    __shared__ __align__(16) u16 Ks[2][4][32][32];
    __shared__ __align__(16) u16 Vs[2][256][32];
    __shared__ u16 Ss[64][40];
    const int id = blockIdx.x;
    const int halfg = id >> 8, r5 = id & 255;
    const int bh = r5 >> 4, i16 = r5 & 15;
    const int tile = halfg ? i16 : 31 - i16;   // pair (i, i+256) work = 68 steps const
    const int b = bh >> 3, h = bh & 7;
    const int t = threadIdx.x;
    const int wave = t >> 6, lane = t & 63, quad = lane >> 4, l16 = lane & 15;
    const u32 lo = __builtin_amdgcn_readfirstlane((u32)(wave * 1024));
    const u16* Qbase = QKVG + (long)b * 2048 * 6144 + h * 128;
    const u16* Kbase = Qbase + 1024;
    const u16* Vbase = Vt + (long)(b * 8 + h) * 256 * 2048;
    u16* Gseg = QKVG + (long)b * 2048 * 6144 + 4096 + h * 256;

    float g = 1.f - expf(-3.4657359027997265f + (-0.3960841031771116f) * (float)h);
    float log2g = log2f(g);

    auto issueKV = [&](int jt, int buf) {
#pragma unroll
        for (int i = 0; i < 2; i++) {
            int c = t + i * 256;
            int ks = c >> 7, row = (c >> 2) & 31, cb = c & 3;
            async_ld16(Kbase + (long)(jt*32 + row) * 6144 + ks*32 + cb*8,
                       (const char*)Ks + buf*8192 + i*4096 + lo);
        }
#pragma unroll
        for (int i = 0; i < 4; i++) {
            int c = t + i * 256;
            int row = c >> 2, cb = c & 3;
            async_ld16(Vbase + (long)row * 2048 + jt*32 + cb*8,
                       (const char*)Vs + buf*16384 + i*4096 + lo);
        }
    };

    // prologue: Q tile + (K,V) for jt=0 into buf 0
#pragma unroll
    for (int i = 0; i < 4; i++) {
        int c = t + i * 256;
        int ks = c >> 8, row = (c >> 2) & 63, cb = c & 3;
        async_ld16(Qbase + (long)(tile*64 + row) * 6144 + ks*32 + cb*8,
                   (const char*)Qs + i*4096 + lo);
    }
    issueKV(0, 0);

    float gw[16], gbv[16];
#pragma unroll
    for (int nt = 0; nt < 16; nt++) {
        gw[nt]  = gnw[h*256 + nt*16 + l16];
        gbv[nt] = gnb[h*256 + nt*16 + l16];
    }
    f32x4 oacc[16];
#pragma unroll
    for (int nt = 0; nt < 16; nt++) oacc[nt] = (f32x4){0.f, 0.f, 0.f, 0.f};
    __syncthreads();

    const int njt = 2 * tile + 2;
    for (int jt = 0; jt < njt; jt++) {
        const int cur = jt & 1;
        if (jt + 1 < njt) issueKV(jt + 1, cur ^ 1);   // prefetch overlaps compute
        // QK^T
        f32x4 s0 = (f32x4){0.f,0.f,0.f,0.f}, s1 = (f32x4){0.f,0.f,0.f,0.f};
#pragma unroll
        for (int ks = 0; ks < 4; ks++) {
            short8 aq = *(const short8*)&Qs[ks][wave*16 + l16][quad*8];
            short8 b0 = *(const short8*)&Ks[cur][ks][l16][quad*8];
            short8 b1 = *(const short8*)&Ks[cur][ks][16 + l16][quad*8];
            s0 = __builtin_amdgcn_mfma_f32_16x16x32_bf16(aq, b0, s0, 0, 0, 0);
            s1 = __builtin_amdgcn_mfma_f32_16x16x32_bf16(aq, b1, s1, 0, 0, 0);
        }
        // decay + causal mask -> Ss (wave-private rows: no barrier needed)
#pragma unroll
        for (int reg = 0; reg < 4; reg++) {
            int srow = tile*64 + wave*16 + quad*4 + reg;
            int tc0 = jt*32 + l16, tc1 = tc0 + 16;
            float d0 = (srow >= tc0) ? exp2f(log2g * (float)(srow - tc0)) : 0.f;
            float d1 = (srow >= tc1) ? exp2f(log2g * (float)(srow - tc1)) : 0.f;
            Ss[wave*16 + quad*4 + reg][l16]      = f2b(s0[reg] * d0);
            Ss[wave*16 + quad*4 + reg][16 + l16] = f2b(s1[reg] * d1);
        }
        // PV: O[64x256] += S[64x32] @ V[32x256]
        short8 as = *(const short8*)&Ss[wave*16 + l16][quad*8];
#pragma unroll
        for (int nt = 0; nt < 16; nt++) {
            short8 bv = *(const short8*)&Vs[cur][nt*16 + l16][quad*8];
            oacc[nt] = __builtin_amdgcn_mfma_f32_16x16x32_bf16(as, bv, oacc[nt], 0, 0, 0);
        }
        __syncthreads();   // drains prefetch + guards buf reuse
    }

    // fused groupnorm + silu(G) gate, written in-place over G segment
#pragma unroll
    for (int reg = 0; reg < 4; reg++) {
        float s = 0.f, q = 0.f;
#pragma unroll
        for (int nt = 0; nt < 16; nt++) { float v = oacc[nt][reg]; s += v; q += v*v; }
#pragma unroll
        for (int m = 1; m < 16; m <<= 1) { s += __shfl_xor(s, m, 16); q += __shfl_xor(q, m, 16); }
        float mean = s * (1.f/256.f);
        float var  = q * (1.f/256.f) - mean*mean;
        float rstd = rsqrtf(var + 1e-5f);
        int srow = tile*64 + wave*16 + quad*4 + reg;
        u16* grow = Gseg + (long)srow * 6144;
#pragma unroll
        for (int nt = 0; nt < 16; nt++) {
            float gval = b2f(grow[nt*16 + l16]);
            float y = (oacc[nt][reg] - mean) * rstd * gw[nt] + gbv[nt];
            float sg = gval / (1.f + expf(-gval));
            grow[nt*16 + l16] = f2b(sg * y);
        }
    }
}

extern "C" void kernel_launch(void* const* d_in, const int* in_sizes, int n_in,
                              void* d_out, int out_size, void* d_ws, size_t ws_size,
                              hipStream_t stream) {
    (void)in_sizes; (void)n_in; (void)out_size; (void)ws_size;
    const float* X    = (const float*)d_in[0];
    const float* Wq   = (const float*)d_in[1];
    const float* Wk   = (const float*)d_in[2];
    const float* Wv   = (const float*)d_in[3];
    const float* WG   = (const float*)d_in[4];
    const float* WO   = (const float*)d_in[5];
    const float* gnw  = (const float*)d_in[6];
    const float* gnb  = (const float*)d_in[7];
    const float* ln1w = (const float*)d_in[8];
    const float* ln1b = (const float*)d_in[9];
    const float* ln2w = (const float*)d_in[10];
    const float* ln2b = (const float*)d_in[11];
    const float* fw1  = (const float*)d_in[12];
    const float* fb1  = (const float*)d_in[13];
    const float* fw2  = (const float*)d_in[14];
    const float* fb2  = (const float*)d_in[15];

    constexpr int D = 1024, FFN = 4096;
    constexpr int M = 4096; // B*S rows
    constexpr long MB = 1048576;

    char* ws = (char*)d_ws;
    // weights (persistent until consumed):
    u16* WT   = (u16*)(ws + 0*MB);    // QKVG combined (6144,1024)  12 MB [..QKVG gemm]
    u16* WOT  = (u16*)(ws + 12*MB);   // (1024, 2048)                4 MB [..WO]
    u16* fw1T = (u16*)(ws + 16*MB);   // (4096, 1024)                8 MB [..FFN1]
    u16* fw2T = (u16*)(ws + 24*MB);   // (1024, 4096)                8 MB [..FFN2]
    // activations:
    u16*   QKVG = (u16*)(ws + 32*MB); // bf16 (B,S,6144) 48 MB [QKVG gemm .. WO]
                                      //   WO parks fp32 partials in Q/K/V seg bytes 0..8191/row
    u16*   Xn   = (u16*)(ws + 80*MB); // bf16 (B,S,D)     8 MB [LN1 .. QKVG gemm]
    float4* xtab= (float4*)(ws + 88*MB);// fp32 table     2 MB [setup .. QKVG gemm]
    u16*   Vt   = (u16*)(ws + 80*MB); // bf16 (B,H,256,S)16 MB [vtrans .. retention] (reuses Xn+xtab)
    float* X2   = (float*)(ws + 80*MB);//fp32 (B,S,D)    16 MB [ln2_combine .. ffn2_combine]
    u16*   hb   = (u16*)(ws + 0*MB);  // bf16 (B,S,D)     8 MB [ln2_combine .. FFN1] (reuses WT)
    u16*   mid  = (u16*)(ws + 32*MB); // bf16 (B,S,FFN)  32 MB [FFN1 .. FFN2]        (reuses QKVG)
    float* PF   = (float*)(ws + 0*MB);// FFN2 partials: P0 [0,16), P1 [64,80) MB

    // 0. weight transpose + bf16 convert, xPos table
    wtrans<<<dim3(32, 4, 8),   256, 0, stream>>>(Wq,  WT,            D, 128);
    wtrans<<<dim3(32, 4, 8),   256, 0, stream>>>(Wk,  WT + 1048576,  D, 128);
    wtrans<<<dim3(32, 8, 8),   256, 0, stream>>>(Wv,  WT + 2097152,  D, 256);
    wtrans<<<dim3(32, 64, 1),  256, 0, stream>>>(WG,  WT + 4194304,  D, 2048);
    wtrans<<<dim3(64, 32, 1),  256, 0, stream>>>(WO,  WOT,  2048, D);
    wtrans<<<dim3(32, 128, 1), 256, 0, stream>>>(fw1, fw1T, D, FFN);
    wtrans<<<dim3(128, 32, 1), 256, 0, stream>>>(fw2, fw2T, FFN, D);
    xtab_k<<<512, 256, 0, stream>>>(xtab);
    // 1. LN1 -> Xn bf16
    ln_k<<<M, 256, 0, stream>>>(X, ln1w, ln1b, Xn);
    // 2. fused QKVG projection + xPos table epilogue -> QKVG (B,S,6144)
    mgemm<EPI_QKVG><<<1536, 256, 0, stream>>>(
        Xn, WT, QKVG, D, D, 6144, (const float*)xtab);
    // 3. V^T (B,H,256,S)
    vtrans<<<dim3(64, 8, 16), 256, 0, stream>>>(QKVG + 2048, Vt);
    // 4. retention + groupnorm + silu-gate -> in-place on G segment
    retention_mfma<<<512, 256, 0, stream>>>(QKVG, Vt, gnw, gnb);
    // 5. WO split-K x2: partials into dead Q/K/V segment bytes of QKVG rows
    mgemm_sk<<<512, 256, 0, stream>>>(
        QKVG + 4096, WOT, (float*)QKVG, 2048, 1024, 6144, 3072, 1024);
    // 6. combine + residual + LN2 -> X2 (fp32) and hb (bf16)
    ln2_combine<<<M, 256, 0, stream>>>((const float*)QKVG, X, ln2w, ln2b, X2, hb);
    // 7. mid = gelu(hb @ W1 + b1)  bf16
    mgemm<EPI_GELU_BIAS><<<1024, 256, 0, stream>>>(
        hb, fw1T, mid, D, D, FFN, fb1);
    // 8. FFN2 split-K x2: partials P0 [0,16) MB, P1 [64,80) MB
    mgemm_sk<<<512, 256, 0, stream>>>(
        mid, fw2T, PF, 4096, 2048, 4096, 1024, 16777216);
    // 9. combine + bias + X2 residual -> d_out (fp32)
    ffn2_combine<<<M, 256, 0, stream>>>(PF, fb2, X2, (float*)d_out);
}

// Round 9
// 508.878 us; speedup vs baseline: 7.0922x; 1.0077x over previous
//
#include <hip/hip_runtime.h>
#include <hip/hip_bf16.h>

typedef unsigned short u16;
typedef unsigned int   u32;
typedef short short8 __attribute__((ext_vector_type(8)));
typedef float f32x4  __attribute__((ext_vector_type(4)));

// ---------- bf16 helpers ----------
__device__ __forceinline__ float b2f(u16 u) { return __uint_as_float(((u32)u) << 16); }
__device__ __forceinline__ u16 f2b(float f) {
    u32 u = __float_as_uint(f);
    u += 0x7FFF + ((u >> 16) & 1);   // RTNE
    return (u16)(u >> 16);
}

// ---------- async global->LDS 16B (wave-uniform LDS base + lane*16) ----------
typedef const unsigned int __attribute__((address_space(1)))* gas1;
typedef unsigned int __attribute__((address_space(3)))* las3;
__device__ __forceinline__ void async_ld16(const void* g, const void* l) {
    __builtin_amdgcn_global_load_lds((gas1)(unsigned long long)g,
                                     (las3)(unsigned int)(unsigned long long)l,
                                     16, 0, 0);
}

// ================= fused prep: 7x wtrans + xPos table + LN1 =================
__device__ __forceinline__ void wtrans_body(const float* __restrict__ W, u16* __restrict__ Wt,
                                            int K, int N, int bx, int by, int bz) {
    __shared__ u16 tile[32][36];
    const int k0 = bx * 32, n0 = by * 32;
    const float* Wz = W + (long)bz * K * N;
    u16* Wtz = Wt + (long)bz * K * N;
    const int t = threadIdx.x;
    const int r = t >> 3, c = (t & 7) * 4;
    float4 v = *(const float4*)(Wz + (long)(k0 + r) * N + n0 + c);
    tile[r][c+0] = f2b(v.x); tile[r][c+1] = f2b(v.y);
    tile[r][c+2] = f2b(v.z); tile[r][c+3] = f2b(v.w);
    __syncthreads();
    uint2 pk;
    pk.x = (u32)tile[c+0][r] | ((u32)tile[c+1][r] << 16);
    pk.y = (u32)tile[c+2][r] | ((u32)tile[c+3][r] << 16);
    *(uint2*)(Wtz + (long)(n0 + r) * K + k0 + c) = pk;
}

__device__ __forceinline__ void xtab_body(float4* __restrict__ tab, int blk) {
    int idx = blk * 256 + threadIdx.x;   // 0..131071
    int j = idx & 63, s = idx >> 6;
    float sv = (2.f * j + 51.2f) / 179.2f;
    float scale = exp2f(log2f(sv) * ((float)s * (1.f / 512.f)));
    float inv_freq = exp2f((float)j * (-13.287712379549449f / 64.f));
    float ang = (float)s * inv_freq;
    float sn = sinf(ang), cs = cosf(ang);
    tab[idx] = make_float4(cs * scale, sn * scale, cs / scale, sn / scale);
}

__device__ __forceinline__ void ln_body(const float* __restrict__ X,
                                        const float* __restrict__ w,
                                        const float* __restrict__ bb,
                                        u16* __restrict__ out, long row) {
    const int t = threadIdx.x;
    float4 p = ((const float4*)(X + row * 1024))[t];
    float x[4] = { p.x, p.y, p.z, p.w };
    float s = x[0]+x[1]+x[2]+x[3];
    float q = x[0]*x[0]+x[1]*x[1]+x[2]*x[2]+x[3]*x[3];
#pragma unroll
    for (int o = 32; o > 0; o >>= 1) { s += __shfl_down(s, o, 64); q += __shfl_down(q, o, 64); }
    __shared__ float aS[4], aQ[4];
    if ((t & 63) == 0) { aS[t >> 6] = s; aQ[t >> 6] = q; }
    __syncthreads();
    s = aS[0]+aS[1]+aS[2]+aS[3];
    q = aQ[0]+aQ[1]+aQ[2]+aQ[3];
    float mean = s * (1.f/1024.f);
    float var  = q * (1.f/1024.f) - mean*mean;
    float rstd = rsqrtf(var + 1e-5f);
    float4 wv = ((const float4*)w)[t];
    float4 bv = ((const float4*)bb)[t];
    uint2 r;
    r.x = (u32)f2b((x[0]-mean)*rstd*wv.x + bv.x) | ((u32)f2b((x[1]-mean)*rstd*wv.y + bv.y) << 16);
    r.y = (u32)f2b((x[2]-mean)*rstd*wv.z + bv.z) | ((u32)f2b((x[3]-mean)*rstd*wv.w + bv.w) << 16);
    ((uint2*)(out + row * 1024))[t] = r;
}

__global__ __launch_bounds__(256) void prep_k(
    const float* __restrict__ Wq, const float* __restrict__ Wk,
    const float* __restrict__ Wv, const float* __restrict__ WG,
    const float* __restrict__ WO, const float* __restrict__ fw1,
    const float* __restrict__ fw2, const float* __restrict__ X,
    const float* __restrict__ ln1w, const float* __restrict__ ln1b,
    u16* __restrict__ WT, u16* __restrict__ WOT,
    u16* __restrict__ fw1T, u16* __restrict__ fw2T,
    float4* __restrict__ xtab, u16* __restrict__ Xn) {
    const int id = blockIdx.x;
    if (id < 16384) {
        const float* W; u16* Wt; int K, N, bx, by, bz = 0;
        if (id < 1024)       { W=Wq;  Wt=WT;           K=1024; N=128;  int l=id;       bx=l&31;  by=(l>>5)&3; bz=l>>7; }
        else if (id < 2048)  { W=Wk;  Wt=WT+1048576;   K=1024; N=128;  int l=id-1024;  bx=l&31;  by=(l>>5)&3; bz=l>>7; }
        else if (id < 4096)  { W=Wv;  Wt=WT+2097152;   K=1024; N=256;  int l=id-2048;  bx=l&31;  by=(l>>5)&7; bz=l>>8; }
        else if (id < 6144)  { W=WG;  Wt=WT+4194304;   K=1024; N=2048; int l=id-4096;  bx=l&31;  by=l>>5; }
        else if (id < 8192)  { W=WO;  Wt=WOT;          K=2048; N=1024; int l=id-6144;  bx=l&63;  by=l>>6; }
        else if (id < 12288) { W=fw1; Wt=fw1T;         K=1024; N=4096; int l=id-8192;  bx=l&31;  by=l>>5; }
        else                 { W=fw2; Wt=fw2T;         K=4096; N=1024; int l=id-12288; bx=l&127; by=l>>7; }
        wtrans_body(W, Wt, K, N, bx, by, bz);
    } else if (id < 16896) {
        xtab_body(xtab, id - 16384);
    } else {
        ln_body(X, ln1w, ln1b, Xn, id - 16896);
    }
}

// ---------- combine WO partials + residual X, then LN2 -> X2 (fp32) and hb (bf16) ----------
__global__ __launch_bounds__(256) void ln2_combine(const float* __restrict__ P,
                                                   const float* __restrict__ X,
                                                   const float* __restrict__ w,
                                                   const float* __restrict__ bb,
                                                   float* __restrict__ X2,
                                                   u16* __restrict__ hb) {
    const long row = blockIdx.x;
    const int t = threadIdx.x;
    const float* p = P + row * 3072;
    float4 a = ((const float4*)p)[t];
    float4 c = ((const float4*)(p + 1024))[t];
    float4 xr = ((const float4*)(X + row * 1024))[t];
    float x[4] = { a.x+c.x+xr.x, a.y+c.y+xr.y, a.z+c.z+xr.z, a.w+c.w+xr.w };
    ((float4*)(X2 + row * 1024))[t] = make_float4(x[0], x[1], x[2], x[3]);
    float s = x[0]+x[1]+x[2]+x[3];
    float q = x[0]*x[0]+x[1]*x[1]+x[2]*x[2]+x[3]*x[3];
#pragma unroll
    for (int o = 32; o > 0; o >>= 1) { s += __shfl_down(s, o, 64); q += __shfl_down(q, o, 64); }
    __shared__ float aS[4], aQ[4];
    if ((t & 63) == 0) { aS[t >> 6] = s; aQ[t >> 6] = q; }
    __syncthreads();
    s = aS[0]+aS[1]+aS[2]+aS[3];
    q = aQ[0]+aQ[1]+aQ[2]+aQ[3];
    float mean = s * (1.f/1024.f);
    float var  = q * (1.f/1024.f) - mean*mean;
    float rstd = rsqrtf(var + 1e-5f);
    float4 wv = ((const float4*)w)[t];
    float4 bv = ((const float4*)bb)[t];
    uint2 r;
    r.x = (u32)f2b((x[0]-mean)*rstd*wv.x + bv.x) | ((u32)f2b((x[1]-mean)*rstd*wv.y + bv.y) << 16);
    r.y = (u32)f2b((x[2]-mean)*rstd*wv.z + bv.z) | ((u32)f2b((x[3]-mean)*rstd*wv.w + bv.w) << 16);
    ((uint2*)(hb + row * 1024))[t] = r;
}

// ---------- combine FFN2 partials + bias + X2 -> d_out (fp32) ----------
__global__ __launch_bounds__(256) void ffn2_combine(const float* __restrict__ P,
                                                    const float* __restrict__ b2,
                                                    const float* __restrict__ X2,
                                                    float* __restrict__ out) {
    const long row = blockIdx.x;
    const int t = threadIdx.x;
    float4 p0 = ((const float4*)(P + row * 1024))[t];
    float4 p1 = ((const float4*)(P + 16777216 + row * 1024))[t];
    float4 x2 = ((const float4*)(X2 + row * 1024))[t];
    float4 bv = ((const float4*)b2)[t];
    ((float4*)(out + row * 1024))[t] = make_float4(
        p0.x + p1.x + x2.x + bv.x, p0.y + p1.y + x2.y + bv.y,
        p0.z + p1.z + x2.z + bv.z, p0.w + p1.w + x2.w + bv.w);
}

// ---------- V transpose (bf16): QKVG V-segment (B,S,6144)+2048 -> Vt (B,H,256,S) ----------
__global__ __launch_bounds__(256) void vtrans(const u16* __restrict__ Vseg, u16* __restrict__ Vt) {
    __shared__ u16 tile[32][36];
    const int s0 = blockIdx.x * 32, v0 = blockIdx.y * 32, z = blockIdx.z; // z = b*8+h
    const int b = z >> 3, h = z & 7;
    const u16* Vz = Vseg + (long)b * 2048 * 6144 + h * 256;
    u16* Vtz = Vt + (long)z * 256 * 2048;
    const int t = threadIdx.x;
    const int r = t >> 3, c = (t & 7) * 4;
    uint2 ld = *(const uint2*)(Vz + (long)(s0 + r) * 6144 + v0 + c);
    tile[r][c+0] = (u16)(ld.x & 0xFFFF); tile[r][c+1] = (u16)(ld.x >> 16);
    tile[r][c+2] = (u16)(ld.y & 0xFFFF); tile[r][c+3] = (u16)(ld.y >> 16);
    __syncthreads();
    uint2 pk;
    pk.x = (u32)tile[c+0][r] | ((u32)tile[c+1][r] << 16);
    pk.y = (u32)tile[c+2][r] | ((u32)tile[c+3][r] << 16);
    *(uint2*)(Vtz + (long)(v0 + r) * 2048 + s0 + c) = pk;
}

// ---------- MFMA GEMM (m97 structure): C = A[M][K] @ Bt[N][K]^T, bf16->fp32 ----------
// Block order: mb innermost (mb = pid & 31). M hardcoded 4096 (32 mb tiles).
// Packed u32 stores: even lanes write 2 bf16.
enum { EPI_GELU_BIAS = 2, EPI_QKVG = 4 };

template<int EPI>
__global__ __launch_bounds__(256) void mgemm(
    const u16* __restrict__ A, const u16* __restrict__ Bt, u16* __restrict__ Cv,
    int K, int aStride, long cStride,
    const float* __restrict__ bias) {
    __shared__ __align__(16) u16 As[128 * 32];
    __shared__ __align__(16) u16 Bs[128 * 32];
    const int pid = blockIdx.x;
    const int mb = pid & 31;
    const int nb = pid >> 5;
    const int t = threadIdx.x;
    const int row0 = mb * 128, col0 = nb * 128;
    const int wave = t >> 6, lane = t & 63;
    const int wm = wave >> 1, wn = wave & 1;
    const int quad = lane >> 4, l16 = lane & 15;
    const u16* Ag = A + (long)(row0 + (t >> 2)) * aStride + ((t & 3) * 8);
    const u16* Bg = Bt + (long)(col0 + (t >> 2)) * K + ((t & 3) * 8);
    const long aj = (long)64 * aStride;
    const long bj = (long)64 * K;
    const u32 lo = __builtin_amdgcn_readfirstlane((u32)(wave * 1024));

    f32x4 acc[4][4];
#pragma unroll
    for (int i = 0; i < 4; i++)
#pragma unroll
        for (int j = 0; j < 4; j++) acc[i][j] = (f32x4){0.f, 0.f, 0.f, 0.f};

    for (int k0 = 0; k0 < K; k0 += 32) {
        async_ld16(Ag + k0,      (const char*)As + lo);
        async_ld16(Ag + k0 + aj, (const char*)As + 4096 + lo);
        async_ld16(Bg + k0,      (const char*)Bs + lo);
        async_ld16(Bg + k0 + bj, (const char*)Bs + 4096 + lo);
        __syncthreads();
        short8 af[4], bf[4];
#pragma unroll
        for (int mt = 0; mt < 4; mt++)
            af[mt] = *(const short8*)(As + (wm*64 + mt*16 + l16) * 32 + quad*8);
#pragma unroll
        for (int nt = 0; nt < 4; nt++)
            bf[nt] = *(const short8*)(Bs + (wn*64 + nt*16 + l16) * 32 + quad*8);
#pragma unroll
        for (int mt = 0; mt < 4; mt++)
#pragma unroll
            for (int nt = 0; nt < 4; nt++)
                acc[mt][nt] = __builtin_amdgcn_mfma_f32_16x16x32_bf16(af[mt], bf[nt], acc[mt][nt], 0, 0, 0);
        __syncthreads();
    }

#pragma unroll
    for (int mt = 0; mt < 4; mt++) {
#pragma unroll
        for (int reg = 0; reg < 4; reg++) {
            int r = row0 + wm*64 + mt*16 + quad*4 + reg;
#pragma unroll
            for (int nt = 0; nt < 4; nt++) {
                int c = col0 + wn*64 + nt*16 + l16;
                float v = acc[mt][nt][reg];
                if constexpr (EPI == EPI_GELU_BIAS) {
                    v += bias[c];
                    v = 0.5f * v * (1.f + erff(v * 0.70710678118654752f));
                } else if constexpr (EPI == EPI_QKVG) {
                    if (c < 2048) {  // xPos rotary: Q (c<1024, up) / K (else, down) via table
                        int j = (c & 127) >> 1;
                        float4 tb = ((const float4*)bias)[((r & 2047) << 6) + j];
                        float cs = (c < 1024) ? tb.x : tb.z;
                        float sn = (c < 1024) ? tb.y : tb.w;
                        float partner = __shfl_xor(v, 1, 64);
                        v = v * cs + ((c & 1) ? partner : -partner) * sn;
                    }
                }
                // pack pair of cols -> u32 store by even lanes
                float pv = __shfl_xor(v, 1, 64);
                if (!(lane & 1)) {
                    u32 pk = (u32)f2b(v) | ((u32)f2b(pv) << 16);
                    *(u32*)(Cv + (long)r * cStride + c) = pk;
                }
            }
        }
    }
}

// ---------- split-K (x2) MFMA GEMM, N=1024 (8 nb x 32 mb), fp32 partial out ----------
// grid 512: pid&255 -> tile (mb = pid&31, nb = (pid&255)>>5), slice = pid>>8.
__global__ __launch_bounds__(256) void mgemm_sk(
    const u16* __restrict__ A, const u16* __restrict__ Bt, float* __restrict__ P,
    int K, int kHalf, int aStride, long pRowStride, long sliceOff) {
    __shared__ __align__(16) u16 As[128 * 32];
    __shared__ __align__(16) u16 Bs[128 * 32];
    const int pid = blockIdx.x;
    const int mb = pid & 31;
    const int nb = (pid & 255) >> 5;
    const int slice = pid >> 8;
    const int t = threadIdx.x;
    const int row0 = mb * 128, col0 = nb * 128;
    const int wave = t >> 6, lane = t & 63;
    const int wm = wave >> 1, wn = wave & 1;
    const int quad = lane >> 4, l16 = lane & 15;
    const u16* Ag = A + (long)(row0 + (t >> 2)) * aStride + ((t & 3) * 8);
    const u16* Bg = Bt + (long)(col0 + (t >> 2)) * K + ((t & 3) * 8);
    const long aj = (long)64 * aStride;
    const long bj = (long)64 * K;
    const u32 lo = __builtin_amdgcn_readfirstlane((u32)(wave * 1024));

    f32x4 acc[4][4];
#pragma unroll
    for (int i = 0; i < 4; i++)
#pragma unroll
        for (int j = 0; j < 4; j++) acc[i][j] = (f32x4){0.f, 0.f, 0.f, 0.f};

    const int kBeg = slice * kHalf, kEnd = kBeg + kHalf;
    for (int k0 = kBeg; k0 < kEnd; k0 += 32) {
        async_ld16(Ag + k0,      (const char*)As + lo);
        async_ld16(Ag + k0 + aj, (const char*)As + 4096 + lo);
        async_ld16(Bg + k0,      (const char*)Bs + lo);
        async_ld16(Bg + k0 + bj, (const char*)Bs + 4096 + lo);
        __syncthreads();
        short8 af[4], bf[4];
#pragma unroll
        for (int mt = 0; mt < 4; mt++)
            af[mt] = *(const short8*)(As + (wm*64 + mt*16 + l16) * 32 + quad*8);
#pragma unroll
        for (int nt = 0; nt < 4; nt++)
            bf[nt] = *(const short8*)(Bs + (wn*64 + nt*16 + l16) * 32 + quad*8);
#pragma unroll
        for (int mt = 0; mt < 4; mt++)
#pragma unroll
            for (int nt = 0; nt < 4; nt++)
                acc[mt][nt] = __builtin_amdgcn_mfma_f32_16x16x32_bf16(af[mt], bf[nt], acc[mt][nt], 0, 0, 0);
        __syncthreads();
    }

    float* Pb = P + slice * sliceOff;
#pragma unroll
    for (int mt = 0; mt < 4; mt++) {
#pragma unroll
        for (int reg = 0; reg < 4; reg++) {
            int r = row0 + wm*64 + mt*16 + quad*4 + reg;
#pragma unroll
            for (int nt = 0; nt < 4; nt++) {
                int c = col0 + wn*64 + nt*16 + l16;
                float v = acc[mt][nt][reg];
                float pv = __shfl_xor(v, 1, 64);
                if (!(lane & 1))
                    *(float2*)(Pb + (long)r * pRowStride + c) = make_float2(v, pv);
            }
        }
    }
}

// ---------- MFMA retention + fused groupnorm + fused silu-gate ----------
// grid 512 (1D). QKVG (B,S,6144): Q cols 0..1023, K 1024..2047, V 2048..4095, G 4096..6143.
// Writes gated = silu(G)*groupnorm(O) in-place over the G segment. Vt (B,H,256,S).
__global__ __launch_bounds__(256) void retention_mfma(
    u16* __restrict__ QKVG, const u16* __restrict__ Vt,
    const float* __restrict__ gnw, const float* __restrict__ gnb) {
    __shared__ __align__(16) u16 Qs[4][64][32];
    __shared__ __align__(16) u16 Ks[2][4][32][32];
    __shared__ __align__(16) u16 Vs[2][256][32];
    __shared__ u16 Ss[64][40];
    const int id = blockIdx.x;
    const int halfg = id >> 8, r5 = id & 255;
    const int bh = r5 >> 4, i16 = r5 & 15;
    const int tile = halfg ? i16 : 31 - i16;   // pair (i, i+256) work = 68 steps const
    const int b = bh >> 3, h = bh & 7;
    const int t = threadIdx.x;
    const int wave = t >> 6, lane = t & 63, quad = lane >> 4, l16 = lane & 15;
    const u32 lo = __builtin_amdgcn_readfirstlane((u32)(wave * 1024));
    const u16* Qbase = QKVG + (long)b * 2048 * 6144 + h * 128;
    const u16* Kbase = Qbase + 1024;
    const u16* Vbase = Vt + (long)(b * 8 + h) * 256 * 2048;
    u16* Gseg = QKVG + (long)b * 2048 * 6144 + 4096 + h * 256;

    float g = 1.f - expf(-3.4657359027997265f + (-0.3960841031771116f) * (float)h);
    float log2g = log2f(g);

    auto issueKV = [&](int jt, int buf) {
#pragma unroll
        for (int i = 0; i < 2; i++) {
            int c = t + i * 256;
            int ks = c >> 7, row = (c >> 2) & 31, cb = c & 3;
            async_ld16(Kbase + (long)(jt*32 + row) * 6144 + ks*32 + cb*8,
                       (const char*)Ks + buf*8192 + i*4096 + lo);
        }
#pragma unroll
        for (int i = 0; i < 4; i++) {
            int c = t + i * 256;
            int row = c >> 2, cb = c & 3;
            async_ld16(Vbase + (long)row * 2048 + jt*32 + cb*8,
                       (const char*)Vs + buf*16384 + i*4096 + lo);
        }
    };

    // prologue: Q tile + (K,V) for jt=0 into buf 0
#pragma unroll
    for (int i = 0; i < 4; i++) {
        int c = t + i * 256;
        int ks = c >> 8, row = (c >> 2) & 63, cb = c & 3;
        async_ld16(Qbase + (long)(tile*64 + row) * 6144 + ks*32 + cb*8,
                   (const char*)Qs + i*4096 + lo);
    }
    issueKV(0, 0);

    float gw[16], gbv[16];
#pragma unroll
    for (int nt = 0; nt < 16; nt++) {
        gw[nt]  = gnw[h*256 + nt*16 + l16];
        gbv[nt] = gnb[h*256 + nt*16 + l16];
    }
    f32x4 oacc[16];
#pragma unroll
    for (int nt = 0; nt < 16; nt++) oacc[nt] = (f32x4){0.f, 0.f, 0.f, 0.f};
    __syncthreads();

    const int njt = 2 * tile + 2;
    for (int jt = 0; jt < njt; jt++) {
        const int cur = jt & 1;
        if (jt + 1 < njt) issueKV(jt + 1, cur ^ 1);   // prefetch overlaps compute
        // QK^T
        f32x4 s0 = (f32x4){0.f,0.f,0.f,0.f}, s1 = (f32x4){0.f,0.f,0.f,0.f};
#pragma unroll
        for (int ks = 0; ks < 4; ks++) {
            short8 aq = *(const short8*)&Qs[ks][wave*16 + l16][quad*8];
            short8 b0 = *(const short8*)&Ks[cur][ks][l16][quad*8];
            short8 b1 = *(const short8*)&Ks[cur][ks][16 + l16][quad*8];
            s0 = __builtin_amdgcn_mfma_f32_16x16x32_bf16(aq, b0, s0, 0, 0, 0);
            s1 = __builtin_amdgcn_mfma_f32_16x16x32_bf16(aq, b1, s1, 0, 0, 0);
        }
        // decay + causal mask -> Ss (wave-private rows: no barrier needed)
#pragma unroll
        for (int reg = 0; reg < 4; reg++) {
            int srow = tile*64 + wave*16 + quad*4 + reg;
            int tc0 = jt*32 + l16, tc1 = tc0 + 16;
            float d0 = (srow >= tc0) ? exp2f(log2g * (float)(srow - tc0)) : 0.f;
            float d1 = (srow >= tc1) ? exp2f(log2g * (float)(srow - tc1)) : 0.f;
            Ss[wave*16 + quad*4 + reg][l16]      = f2b(s0[reg] * d0);
            Ss[wave*16 + quad*4 + reg][16 + l16] = f2b(s1[reg] * d1);
        }
        // PV: O[64x256] += S[64x32] @ V[32x256]
        short8 as = *(const short8*)&Ss[wave*16 + l16][quad*8];
#pragma unroll
        for (int nt = 0; nt < 16; nt++) {
            short8 bv = *(const short8*)&Vs[cur][nt*16 + l16][quad*8];
            oacc[nt] = __builtin_amdgcn_mfma_f32_16x16x32_bf16(as, bv, oacc[nt], 0, 0, 0);
        }
        __syncthreads();   // drains prefetch + guards buf reuse
    }

    // fused groupnorm + silu(G) gate, written in-place over G segment
#pragma unroll
    for (int reg = 0; reg < 4; reg++) {
        float s = 0.f, q = 0.f;
#pragma unroll
        for (int nt = 0; nt < 16; nt++) { float v = oacc[nt][reg]; s += v; q += v*v; }
#pragma unroll
        for (int m = 1; m < 16; m <<= 1) { s += __shfl_xor(s, m, 16); q += __shfl_xor(q, m, 16); }
        float mean = s * (1.f/256.f);
        float var  = q * (1.f/256.f) - mean*mean;
        float rstd = rsqrtf(var + 1e-5f);
        int srow = tile*64 + wave*16 + quad*4 + reg;
        u16* grow = Gseg + (long)srow * 6144;
#pragma unroll
        for (int nt = 0; nt < 16; nt++) {
            float gval = b2f(grow[nt*16 + l16]);
            float y = (oacc[nt][reg] - mean) * rstd * gw[nt] + gbv[nt];
            float sg = gval / (1.f + expf(-gval));
            grow[nt*16 + l16] = f2b(sg * y);
        }
    }
}

extern "C" void kernel_launch(void* const* d_in, const int* in_sizes, int n_in,
                              void* d_out, int out_size, void* d_ws, size_t ws_size,
                              hipStream_t stream) {
    (void)in_sizes; (void)n_in; (void)out_size; (void)ws_size;
    const float* X    = (const float*)d_in[0];
    const float* Wq   = (const float*)d_in[1];
    const float* Wk   = (const float*)d_in[2];
    const float* Wv   = (const float*)d_in[3];
    const float* WG   = (const float*)d_in[4];
    const float* WO   = (const float*)d_in[5];
    const float* gnw  = (const float*)d_in[6];
    const float* gnb  = (const float*)d_in[7];
    const float* ln1w = (const float*)d_in[8];
    const float* ln1b = (const float*)d_in[9];
    const float* ln2w = (const float*)d_in[10];
    const float* ln2b = (const float*)d_in[11];
    const float* fw1  = (const float*)d_in[12];
    const float* fb1  = (const float*)d_in[13];
    const float* fw2  = (const float*)d_in[14];
    const float* fb2  = (const float*)d_in[15];

    constexpr int D = 1024, FFN = 4096;
    constexpr int M = 4096; // B*S rows
    constexpr long MB = 1048576;

    char* ws = (char*)d_ws;
    // weights (persistent until consumed):
    u16* WT   = (u16*)(ws + 0*MB);    // QKVG combined (6144,1024)  12 MB [..QKVG gemm]
    u16* WOT  = (u16*)(ws + 12*MB);   // (1024, 2048)                4 MB [..WO]
    u16* fw1T = (u16*)(ws + 16*MB);   // (4096, 1024)                8 MB [..FFN1]
    u16* fw2T = (u16*)(ws + 24*MB);   // (1024, 4096)                8 MB [..FFN2]
    // activations:
    u16*   QKVG = (u16*)(ws + 32*MB); // bf16 (B,S,6144) 48 MB [QKVG gemm .. WO]
                                      //   WO parks fp32 partials in Q/K seg bytes of each row
    u16*   Xn   = (u16*)(ws + 80*MB); // bf16 (B,S,D)     8 MB [prep .. QKVG gemm]
    float4* xtab= (float4*)(ws + 88*MB);// fp32 table     2 MB [prep .. QKVG gemm]
    u16*   Vt   = (u16*)(ws + 80*MB); // bf16 (B,H,256,S)16 MB [vtrans .. retention] (reuses Xn+xtab)
    float* X2   = (float*)(ws + 80*MB);//fp32 (B,S,D)    16 MB [ln2_combine .. ffn2_combine]
    u16*   hb   = (u16*)(ws + 0*MB);  // bf16 (B,S,D)     8 MB [ln2_combine .. FFN1] (reuses WT)
    u16*   mid  = (u16*)(ws + 32*MB); // bf16 (B,S,FFN)  32 MB [FFN1 .. FFN2]        (reuses QKVG)
    float* PF   = (float*)(ws + 0*MB);// FFN2 partials: P0 [0,16), P1 [64,80) MB

    // 1. fused prep: 7x weight transpose + xPos table + LN1
    prep_k<<<20992, 256, 0, stream>>>(Wq, Wk, Wv, WG, WO, fw1, fw2, X, ln1w, ln1b,
                                      WT, WOT, fw1T, fw2T, xtab, Xn);
    // 2. fused QKVG projection + xPos table epilogue -> QKVG (B,S,6144)
    mgemm<EPI_QKVG><<<1536, 256, 0, stream>>>(
        Xn, WT, QKVG, D, D, 6144, (const float*)xtab);
    // 3. V^T (B,H,256,S)
    vtrans<<<dim3(64, 8, 16), 256, 0, stream>>>(QKVG + 2048, Vt);
    // 4. retention + groupnorm + silu-gate -> in-place on G segment
    retention_mfma<<<512, 256, 0, stream>>>(QKVG, Vt, gnw, gnb);
    // 5. WO split-K x2: partials into dead Q/K segment bytes of QKVG rows
    mgemm_sk<<<512, 256, 0, stream>>>(
        QKVG + 4096, WOT, (float*)QKVG, 2048, 1024, 6144, 3072, 1024);
    // 6. combine + residual + LN2 -> X2 (fp32) and hb (bf16)
    ln2_combine<<<M, 256, 0, stream>>>((const float*)QKVG, X, ln2w, ln2b, X2, hb);
    // 7. mid = gelu(hb @ W1 + b1)  bf16
    mgemm<EPI_GELU_BIAS><<<1024, 256, 0, stream>>>(
        hb, fw1T, mid, D, D, FFN, fb1);
    // 8. FFN2 split-K x2: partials P0 [0,16) MB, P1 [64,80) MB
    mgemm_sk<<<512, 256, 0, stream>>>(
        mid, fw2T, PF, 4096, 2048, 4096, 1024, 16777216);
    // 9. combine + bias + X2 residual -> d_out (fp32)
    ffn2_combine<<<M, 256, 0, stream>>>(PF, fb2, X2, (float*)d_out);
}

// Round 10
// 493.018 us; speedup vs baseline: 7.3204x; 1.0322x over previous
//
#include <hip/hip_runtime.h>
#include <hip/hip_bf16.h>

typedef unsigned short u16;
typedef unsigned int   u32;
typedef short short8 __attribute__((ext_vector_type(8)));
typedef float f32x4  __attribute__((ext_vector_type(4)));

// ---------- bf16 helpers ----------
__device__ __forceinline__ float b2f(u16 u) { return __uint_as_float(((u32)u) << 16); }
__device__ __forceinline__ u16 f2b(float f) {
    u32 u = __float_as_uint(f);
    u += 0x7FFF + ((u >> 16) & 1);   // RTNE
    return (u16)(u >> 16);
}

// ---------- async global->LDS 16B (wave-uniform LDS base + lane*16) ----------
typedef const unsigned int __attribute__((address_space(1)))* gas1;
typedef unsigned int __attribute__((address_space(3)))* las3;
__device__ __forceinline__ void async_ld16(const void* g, const void* l) {
    __builtin_amdgcn_global_load_lds((gas1)(unsigned long long)g,
                                     (las3)(unsigned int)(unsigned long long)l,
                                     16, 0, 0);
}

// ================= fused prep: 7x wtrans + xPos table + LN1 =================
__device__ __forceinline__ void wtrans_body(const float* __restrict__ W, u16* __restrict__ Wt,
                                            int K, int N, int bx, int by, int bz) {
    __shared__ u16 tile[32][36];
    const int k0 = bx * 32, n0 = by * 32;
    const float* Wz = W + (long)bz * K * N;
    u16* Wtz = Wt + (long)bz * K * N;
    const int t = threadIdx.x;
    const int r = t >> 3, c = (t & 7) * 4;
    float4 v = *(const float4*)(Wz + (long)(k0 + r) * N + n0 + c);
    tile[r][c+0] = f2b(v.x); tile[r][c+1] = f2b(v.y);
    tile[r][c+2] = f2b(v.z); tile[r][c+3] = f2b(v.w);
    __syncthreads();
    uint2 pk;
    pk.x = (u32)tile[c+0][r] | ((u32)tile[c+1][r] << 16);
    pk.y = (u32)tile[c+2][r] | ((u32)tile[c+3][r] << 16);
    *(uint2*)(Wtz + (long)(n0 + r) * K + k0 + c) = pk;
}

__device__ __forceinline__ void xtab_body(float4* __restrict__ tab, int blk) {
    int idx = blk * 256 + threadIdx.x;   // 0..131071
    int j = idx & 63, s = idx >> 6;
    float sv = (2.f * j + 51.2f) / 179.2f;
    float scale = exp2f(log2f(sv) * ((float)s * (1.f / 512.f)));
    float inv_freq = exp2f((float)j * (-13.287712379549449f / 64.f));
    float ang = (float)s * inv_freq;
    float sn = sinf(ang), cs = cosf(ang);
    tab[idx] = make_float4(cs * scale, sn * scale, cs / scale, sn / scale);
}

__device__ __forceinline__ void ln_body(const float* __restrict__ X,
                                        const float* __restrict__ w,
                                        const float* __restrict__ bb,
                                        u16* __restrict__ out, long row) {
    const int t = threadIdx.x;
    float4 p = ((const float4*)(X + row * 1024))[t];
    float x[4] = { p.x, p.y, p.z, p.w };
    float s = x[0]+x[1]+x[2]+x[3];
    float q = x[0]*x[0]+x[1]*x[1]+x[2]*x[2]+x[3]*x[3];
#pragma unroll
    for (int o = 32; o > 0; o >>= 1) { s += __shfl_down(s, o, 64); q += __shfl_down(q, o, 64); }
    __shared__ float aS[4], aQ[4];
    if ((t & 63) == 0) { aS[t >> 6] = s; aQ[t >> 6] = q; }
    __syncthreads();
    s = aS[0]+aS[1]+aS[2]+aS[3];
    q = aQ[0]+aQ[1]+aQ[2]+aQ[3];
    float mean = s * (1.f/1024.f);
    float var  = q * (1.f/1024.f) - mean*mean;
    float rstd = rsqrtf(var + 1e-5f);
    float4 wv = ((const float4*)w)[t];
    float4 bv = ((const float4*)bb)[t];
    uint2 r;
    r.x = (u32)f2b((x[0]-mean)*rstd*wv.x + bv.x) | ((u32)f2b((x[1]-mean)*rstd*wv.y + bv.y) << 16);
    r.y = (u32)f2b((x[2]-mean)*rstd*wv.z + bv.z) | ((u32)f2b((x[3]-mean)*rstd*wv.w + bv.w) << 16);
    ((uint2*)(out + row * 1024))[t] = r;
}

__global__ __launch_bounds__(256) void prep_k(
    const float* __restrict__ Wq, const float* __restrict__ Wk,
    const float* __restrict__ Wv, const float* __restrict__ WG,
    const float* __restrict__ WO, const float* __restrict__ fw1,
    const float* __restrict__ fw2, const float* __restrict__ X,
    const float* __restrict__ ln1w, const float* __restrict__ ln1b,
    u16* __restrict__ WT, u16* __restrict__ WOT,
    u16* __restrict__ fw1T, u16* __restrict__ fw2T,
    float4* __restrict__ xtab, u16* __restrict__ Xn) {
    const int id = blockIdx.x;
    if (id < 16384) {
        const float* W; u16* Wt; int K, N, bx, by, bz = 0;
        if (id < 1024)       { W=Wq;  Wt=WT;           K=1024; N=128;  int l=id;       bx=l&31;  by=(l>>5)&3; bz=l>>7; }
        else if (id < 2048)  { W=Wk;  Wt=WT+1048576;   K=1024; N=128;  int l=id-1024;  bx=l&31;  by=(l>>5)&3; bz=l>>7; }
        else if (id < 4096)  { W=Wv;  Wt=WT+2097152;   K=1024; N=256;  int l=id-2048;  bx=l&31;  by=(l>>5)&7; bz=l>>8; }
        else if (id < 6144)  { W=WG;  Wt=WT+4194304;   K=1024; N=2048; int l=id-4096;  bx=l&31;  by=l>>5; }
        else if (id < 8192)  { W=WO;  Wt=WOT;          K=2048; N=1024; int l=id-6144;  bx=l&63;  by=l>>6; }
        else if (id < 12288) { W=fw1; Wt=fw1T;         K=1024; N=4096; int l=id-8192;  bx=l&31;  by=l>>5; }
        else                 { W=fw2; Wt=fw2T;         K=4096; N=1024; int l=id-12288; bx=l&127; by=l>>7; }
        wtrans_body(W, Wt, K, N, bx, by, bz);
    } else if (id < 16896) {
        xtab_body(xtab, id - 16384);
    } else {
        ln_body(X, ln1w, ln1b, Xn, id - 16896);
    }
}

// ---------- combine WO partials + residual X, then LN2 -> X2 (fp32) and hb (bf16) ----------
__global__ __launch_bounds__(256) void ln2_combine(const float* __restrict__ P,
                                                   const float* __restrict__ X,
                                                   const float* __restrict__ w,
                                                   const float* __restrict__ bb,
                                                   float* __restrict__ X2,
                                                   u16* __restrict__ hb) {
    const long row = blockIdx.x;
    const int t = threadIdx.x;
    const float* p = P + row * 3072;
    float4 a = ((const float4*)p)[t];
    float4 c = ((const float4*)(p + 1024))[t];
    float4 xr = ((const float4*)(X + row * 1024))[t];
    float x[4] = { a.x+c.x+xr.x, a.y+c.y+xr.y, a.z+c.z+xr.z, a.w+c.w+xr.w };
    ((float4*)(X2 + row * 1024))[t] = make_float4(x[0], x[1], x[2], x[3]);
    float s = x[0]+x[1]+x[2]+x[3];
    float q = x[0]*x[0]+x[1]*x[1]+x[2]*x[2]+x[3]*x[3];
#pragma unroll
    for (int o = 32; o > 0; o >>= 1) { s += __shfl_down(s, o, 64); q += __shfl_down(q, o, 64); }
    __shared__ float aS[4], aQ[4];
    if ((t & 63) == 0) { aS[t >> 6] = s; aQ[t >> 6] = q; }
    __syncthreads();
    s = aS[0]+aS[1]+aS[2]+aS[3];
    q = aQ[0]+aQ[1]+aQ[2]+aQ[3];
    float mean = s * (1.f/1024.f);
    float var  = q * (1.f/1024.f) - mean*mean;
    float rstd = rsqrtf(var + 1e-5f);
    float4 wv = ((const float4*)w)[t];
    float4 bv = ((const float4*)bb)[t];
    uint2 r;
    r.x = (u32)f2b((x[0]-mean)*rstd*wv.x + bv.x) | ((u32)f2b((x[1]-mean)*rstd*wv.y + bv.y) << 16);
    r.y = (u32)f2b((x[2]-mean)*rstd*wv.z + bv.z) | ((u32)f2b((x[3]-mean)*rstd*wv.w + bv.w) << 16);
    ((uint2*)(hb + row * 1024))[t] = r;
}

// ---------- combine FFN2 partials + bias + X2 -> d_out (fp32) ----------
__global__ __launch_bounds__(256) void ffn2_combine(const float* __restrict__ P,
                                                    const float* __restrict__ b2,
                                                    const float* __restrict__ X2,
                                                    float* __restrict__ out) {
    const long row = blockIdx.x;
    const int t = threadIdx.x;
    float4 p0 = ((const float4*)(P + row * 1024))[t];
    float4 p1 = ((const float4*)(P + 16777216 + row * 1024))[t];
    float4 x2 = ((const float4*)(X2 + row * 1024))[t];
    float4 bv = ((const float4*)b2)[t];
    ((float4*)(out + row * 1024))[t] = make_float4(
        p0.x + p1.x + x2.x + bv.x, p0.y + p1.y + x2.y + bv.y,
        p0.z + p1.z + x2.z + bv.z, p0.w + p1.w + x2.w + bv.w);
}

// ---------- V transpose (bf16): QKVG V-segment (B,S,6144)+2048 -> Vt (B,H,256,S) ----------
__global__ __launch_bounds__(256) void vtrans(const u16* __restrict__ Vseg, u16* __restrict__ Vt) {
    __shared__ u16 tile[32][36];
    const int s0 = blockIdx.x * 32, v0 = blockIdx.y * 32, z = blockIdx.z; // z = b*8+h
    const int b = z >> 3, h = z & 7;
    const u16* Vz = Vseg + (long)b * 2048 * 6144 + h * 256;
    u16* Vtz = Vt + (long)z * 256 * 2048;
    const int t = threadIdx.x;
    const int r = t >> 3, c = (t & 7) * 4;
    uint2 ld = *(const uint2*)(Vz + (long)(s0 + r) * 6144 + v0 + c);
    tile[r][c+0] = (u16)(ld.x & 0xFFFF); tile[r][c+1] = (u16)(ld.x >> 16);
    tile[r][c+2] = (u16)(ld.y & 0xFFFF); tile[r][c+3] = (u16)(ld.y >> 16);
    __syncthreads();
    uint2 pk;
    pk.x = (u32)tile[c+0][r] | ((u32)tile[c+1][r] << 16);
    pk.y = (u32)tile[c+2][r] | ((u32)tile[c+3][r] << 16);
    *(uint2*)(Vtz + (long)(v0 + r) * 2048 + s0 + c) = pk;
}

// ---------- MFMA GEMM, BK=64 paneled (2x [128][32] sub-tiles per operand) ----------
// C = A[M][K] @ Bt[N][K]^T, bf16->fp32->bf16. mb innermost (mb = pid & 31), M=4096.
enum { EPI_GELU_BIAS = 2, EPI_QKVG = 4 };

template<int EPI>
__global__ __launch_bounds__(256) void mgemm(
    const u16* __restrict__ A, const u16* __restrict__ Bt, u16* __restrict__ Cv,
    int K, int aStride, long cStride,
    const float* __restrict__ bias) {
    __shared__ __align__(16) u16 As[2 * 128 * 32];
    __shared__ __align__(16) u16 Bs[2 * 128 * 32];
    const int pid = blockIdx.x;
    const int mb = pid & 31;
    const int nb = pid >> 5;
    const int t = threadIdx.x;
    const int row0 = mb * 128, col0 = nb * 128;
    const int wave = t >> 6, lane = t & 63;
    const int wm = wave >> 1, wn = wave & 1;
    const int quad = lane >> 4, l16 = lane & 15;
    const u16* Ag = A + (long)(row0 + (t >> 2)) * aStride + ((t & 3) * 8);
    const u16* Bg = Bt + (long)(col0 + (t >> 2)) * K + ((t & 3) * 8);
    const long aj = (long)64 * aStride;
    const long bj = (long)64 * K;
    const u32 lo = __builtin_amdgcn_readfirstlane((u32)(wave * 1024));

    f32x4 acc[4][4];
#pragma unroll
    for (int i = 0; i < 4; i++)
#pragma unroll
        for (int j = 0; j < 4; j++) acc[i][j] = (f32x4){0.f, 0.f, 0.f, 0.f};

    for (int k0 = 0; k0 < K; k0 += 64) {
#pragma unroll
        for (int h = 0; h < 2; h++) {
            const u16* Agh = Ag + k0 + h * 32;
            const u16* Bgh = Bg + k0 + h * 32;
            async_ld16(Agh,      (const char*)As + h*8192 + lo);
            async_ld16(Agh + aj, (const char*)As + h*8192 + 4096 + lo);
            async_ld16(Bgh,      (const char*)Bs + h*8192 + lo);
            async_ld16(Bgh + bj, (const char*)Bs + h*8192 + 4096 + lo);
        }
        __syncthreads();
#pragma unroll
        for (int h = 0; h < 2; h++) {
            short8 af[4], bf[4];
#pragma unroll
            for (int mt = 0; mt < 4; mt++)
                af[mt] = *(const short8*)(As + h*4096 + (wm*64 + mt*16 + l16) * 32 + quad*8);
#pragma unroll
            for (int nt = 0; nt < 4; nt++)
                bf[nt] = *(const short8*)(Bs + h*4096 + (wn*64 + nt*16 + l16) * 32 + quad*8);
#pragma unroll
            for (int mt = 0; mt < 4; mt++)
#pragma unroll
                for (int nt = 0; nt < 4; nt++)
                    acc[mt][nt] = __builtin_amdgcn_mfma_f32_16x16x32_bf16(af[mt], bf[nt], acc[mt][nt], 0, 0, 0);
        }
        __syncthreads();
    }

#pragma unroll
    for (int mt = 0; mt < 4; mt++) {
#pragma unroll
        for (int reg = 0; reg < 4; reg++) {
            int r = row0 + wm*64 + mt*16 + quad*4 + reg;
#pragma unroll
            for (int nt = 0; nt < 4; nt++) {
                int c = col0 + wn*64 + nt*16 + l16;
                float v = acc[mt][nt][reg];
                if constexpr (EPI == EPI_GELU_BIAS) {
                    v += bias[c];
                    v = 0.5f * v * (1.f + erff(v * 0.70710678118654752f));
                }
                float pv = __shfl_xor(v, 1, 64);  // partner column value
                float w0 = v, w1 = pv;            // even lanes: (c, c+1)
                if constexpr (EPI == EPI_QKVG) {
                    if (c < 2048) {  // xPos rotary: even lane computes both pair outputs
                        int j = (c & 127) >> 1;
                        float4 tb = ((const float4*)bias)[((r & 2047) << 6) + j];
                        float cs = (c < 1024) ? tb.x : tb.z;
                        float sn = (c < 1024) ? tb.y : tb.w;
                        w0 = v * cs - pv * sn;
                        w1 = pv * cs + v * sn;
                    }
                }
                if (!(lane & 1)) {
                    u32 pk = (u32)f2b(w0) | ((u32)f2b(w1) << 16);
                    *(u32*)(Cv + (long)r * cStride + c) = pk;
                }
            }
        }
    }
}

// ---------- split-K (x2) MFMA GEMM, BK=64 paneled, N=1024, fp32 partial out ----------
// grid 512: mb = pid&31, nb = (pid&255)>>5, slice = pid>>8.
__global__ __launch_bounds__(256) void mgemm_sk(
    const u16* __restrict__ A, const u16* __restrict__ Bt, float* __restrict__ P,
    int K, int kHalf, int aStride, long pRowStride, long sliceOff) {
    __shared__ __align__(16) u16 As[2 * 128 * 32];
    __shared__ __align__(16) u16 Bs[2 * 128 * 32];
    const int pid = blockIdx.x;
    const int mb = pid & 31;
    const int nb = (pid & 255) >> 5;
    const int slice = pid >> 8;
    const int t = threadIdx.x;
    const int row0 = mb * 128, col0 = nb * 128;
    const int wave = t >> 6, lane = t & 63;
    const int wm = wave >> 1, wn = wave & 1;
    const int quad = lane >> 4, l16 = lane & 15;
    const u16* Ag = A + (long)(row0 + (t >> 2)) * aStride + ((t & 3) * 8);
    const u16* Bg = Bt + (long)(col0 + (t >> 2)) * K + ((t & 3) * 8);
    const long aj = (long)64 * aStride;
    const long bj = (long)64 * K;
    const u32 lo = __builtin_amdgcn_readfirstlane((u32)(wave * 1024));

    f32x4 acc[4][4];
#pragma unroll
    for (int i = 0; i < 4; i++)
#pragma unroll
        for (int j = 0; j < 4; j++) acc[i][j] = (f32x4){0.f, 0.f, 0.f, 0.f};

    const int kBeg = slice * kHalf, kEnd = kBeg + kHalf;
    for (int k0 = kBeg; k0 < kEnd; k0 += 64) {
#pragma unroll
        for (int h = 0; h < 2; h++) {
            const u16* Agh = Ag + k0 + h * 32;
            const u16* Bgh = Bg + k0 + h * 32;
            async_ld16(Agh,      (const char*)As + h*8192 + lo);
            async_ld16(Agh + aj, (const char*)As + h*8192 + 4096 + lo);
            async_ld16(Bgh,      (const char*)Bs + h*8192 + lo);
            async_ld16(Bgh + bj, (const char*)Bs + h*8192 + 4096 + lo);
        }
        __syncthreads();
#pragma unroll
        for (int h = 0; h < 2; h++) {
            short8 af[4], bf[4];
#pragma unroll
            for (int mt = 0; mt < 4; mt++)
                af[mt] = *(const short8*)(As + h*4096 + (wm*64 + mt*16 + l16) * 32 + quad*8);
#pragma unroll
            for (int nt = 0; nt < 4; nt++)
                bf[nt] = *(const short8*)(Bs + h*4096 + (wn*64 + nt*16 + l16) * 32 + quad*8);
#pragma unroll
            for (int mt = 0; mt < 4; mt++)
#pragma unroll
                for (int nt = 0; nt < 4; nt++)
                    acc[mt][nt] = __builtin_amdgcn_mfma_f32_16x16x32_bf16(af[mt], bf[nt], acc[mt][nt], 0, 0, 0);
        }
        __syncthreads();
    }

    float* Pb = P + slice * sliceOff;
#pragma unroll
    for (int mt = 0; mt < 4; mt++) {
#pragma unroll
        for (int reg = 0; reg < 4; reg++) {
            int r = row0 + wm*64 + mt*16 + quad*4 + reg;
#pragma unroll
            for (int nt = 0; nt < 4; nt++) {
                int c = col0 + wn*64 + nt*16 + l16;
                float v = acc[mt][nt][reg];
                float pv = __shfl_xor(v, 1, 64);
                if (!(lane & 1))
                    *(float2*)(Pb + (long)r * pRowStride + c) = make_float2(v, pv);
            }
        }
    }
}

// ---------- MFMA retention + fused groupnorm + fused silu-gate ----------
// grid 512 (1D). QKVG (B,S,6144): Q cols 0..1023, K 1024..2047, V 2048..4095, G 4096..6143.
// Writes gated = silu(G)*groupnorm(O) in-place over the G segment. Vt (B,H,256,S).
__global__ __launch_bounds__(256) void retention_mfma(
    u16* __restrict__ QKVG, const u16* __restrict__ Vt,
    const float* __restrict__ gnw, const float* __restrict__ gnb) {
    __shared__ __align__(16) u16 Qs[4][64][32];
    __shared__ __align__(16) u16 Ks[2][4][32][32];
    __shared__ __align__(16) u16 Vs[2][256][32];
    __shared__ u16 Ss[64][40];
    const int id = blockIdx.x;
    const int halfg = id >> 8, r5 = id & 255;
    const int bh = r5 >> 4, i16 = r5 & 15;
    const int tile = halfg ? i16 : 31 - i16;   // pair (i, i+256) work = 68 steps const
    const int b = bh >> 3, h = bh & 7;
    const int t = threadIdx.x;
    const int wave = t >> 6, lane = t & 63, quad = lane >> 4, l16 = lane & 15;
    const u32 lo = __builtin_amdgcn_readfirstlane((u32)(wave * 1024));
    const u16* Qbase = QKVG + (long)b * 2048 * 6144 + h * 128;
    const u16* Kbase = Qbase + 1024;
    const u16* Vbase = Vt + (long)(b * 8 + h) * 256 * 2048;
    u16* Gseg = QKVG + (long)b * 2048 * 6144 + 4096 + h * 256;

    float g = 1.f - expf(-3.4657359027997265f + (-0.3960841031771116f) * (float)h);
    float log2g = log2f(g);

    auto issueKV = [&](int jt, int buf) {
#pragma unroll
        for (int i = 0; i < 2; i++) {
            int c = t + i * 256;
            int ks = c >> 7, row = (c >> 2) & 31, cb = c & 3;
            async_ld16(Kbase + (long)(jt*32 + row) * 6144 + ks*32 + cb*8,
                       (const char*)Ks + buf*8192 + i*4096 + lo);
        }
#pragma unroll
        for (int i = 0; i < 4; i++) {
            int c = t + i * 256;
            int row = c >> 2, cb = c & 3;
            async_ld16(Vbase + (long)row * 2048 + jt*32 + cb*8,
                       (const char*)Vs + buf*16384 + i*4096 + lo);
        }
    };

    // prologue: Q tile + (K,V) for jt=0 into buf 0
#pragma unroll
    for (int i = 0; i < 4; i++) {
        int c = t + i * 256;
        int ks = c >> 8, row = (c >> 2) & 63, cb = c & 3;
        async_ld16(Qbase + (long)(tile*64 + row) * 6144 + ks*32 + cb*8,
                   (const char*)Qs + i*4096 + lo);
    }
    issueKV(0, 0);

    float gw[16], gbv[16];
#pragma unroll
    for (int nt = 0; nt < 16; nt++) {
        gw[nt]  = gnw[h*256 + nt*16 + l16];
        gbv[nt] = gnb[h*256 + nt*16 + l16];
    }
    f32x4 oacc[16];
#pragma unroll
    for (int nt = 0; nt < 16; nt++) oacc[nt] = (f32x4){0.f, 0.f, 0.f, 0.f};
    __syncthreads();

    const int njt = 2 * tile + 2;
    for (int jt = 0; jt < njt; jt++) {
        const int cur = jt & 1;
        if (jt + 1 < njt) issueKV(jt + 1, cur ^ 1);   // prefetch overlaps compute
        // QK^T
        f32x4 s0 = (f32x4){0.f,0.f,0.f,0.f}, s1 = (f32x4){0.f,0.f,0.f,0.f};
#pragma unroll
        for (int ks = 0; ks < 4; ks++) {
            short8 aq = *(const short8*)&Qs[ks][wave*16 + l16][quad*8];
            short8 b0 = *(const short8*)&Ks[cur][ks][l16][quad*8];
            short8 b1 = *(const short8*)&Ks[cur][ks][16 + l16][quad*8];
            s0 = __builtin_amdgcn_mfma_f32_16x16x32_bf16(aq, b0, s0, 0, 0, 0);
            s1 = __builtin_amdgcn_mfma_f32_16x16x32_bf16(aq, b1, s1, 0, 0, 0);
        }
        // decay + causal mask -> Ss (wave-private rows: no barrier needed)
#pragma unroll
        for (int reg = 0; reg < 4; reg++) {
            int srow = tile*64 + wave*16 + quad*4 + reg;
            int tc0 = jt*32 + l16, tc1 = tc0 + 16;
            float d0 = (srow >= tc0) ? exp2f(log2g * (float)(srow - tc0)) : 0.f;
            float d1 = (srow >= tc1) ? exp2f(log2g * (float)(srow - tc1)) : 0.f;
            Ss[wave*16 + quad*4 + reg][l16]      = f2b(s0[reg] * d0);
            Ss[wave*16 + quad*4 + reg][16 + l16] = f2b(s1[reg] * d1);
        }
        // PV: O[64x256] += S[64x32] @ V[32x256]
        short8 as = *(const short8*)&Ss[wave*16 + l16][quad*8];
#pragma unroll
        for (int nt = 0; nt < 16; nt++) {
            short8 bv = *(const short8*)&Vs[cur][nt*16 + l16][quad*8];
            oacc[nt] = __builtin_amdgcn_mfma_f32_16x16x32_bf16(as, bv, oacc[nt], 0, 0, 0);
        }
        __syncthreads();   // drains prefetch + guards buf reuse
    }

    // fused groupnorm + silu(G) gate, written in-place over G segment
#pragma unroll
    for (int reg = 0; reg < 4; reg++) {
        float s = 0.f, q = 0.f;
#pragma unroll
        for (int nt = 0; nt < 16; nt++) { float v = oacc[nt][reg]; s += v; q += v*v; }
#pragma unroll
        for (int m = 1; m < 16; m <<= 1) { s += __shfl_xor(s, m, 16); q += __shfl_xor(q, m, 16); }
        float mean = s * (1.f/256.f);
        float var  = q * (1.f/256.f) - mean*mean;
        float rstd = rsqrtf(var + 1e-5f);
        int srow = tile*64 + wave*16 + quad*4 + reg;
        u16* grow = Gseg + (long)srow * 6144;
#pragma unroll
        for (int nt = 0; nt < 16; nt++) {
            float gval = b2f(grow[nt*16 + l16]);
            float y = (oacc[nt][reg] - mean) * rstd * gw[nt] + gbv[nt];
            float sg = gval / (1.f + expf(-gval));
            grow[nt*16 + l16] = f2b(sg * y);
        }
    }
}

extern "C" void kernel_launch(void* const* d_in, const int* in_sizes, int n_in,
                              void* d_out, int out_size, void* d_ws, size_t ws_size,
                              hipStream_t stream) {
    (void)in_sizes; (void)n_in; (void)out_size; (void)ws_size;
    const float* X    = (const float*)d_in[0];
    const float* Wq   = (const float*)d_in[1];
    const float* Wk   = (const float*)d_in[2];
    const float* Wv   = (const float*)d_in[3];
    const float* WG   = (const float*)d_in[4];
    const float* WO   = (const float*)d_in[5];
    const float* gnw  = (const float*)d_in[6];
    const float* gnb  = (const float*)d_in[7];
    const float* ln1w = (const float*)d_in[8];
    const float* ln1b = (const float*)d_in[9];
    const float* ln2w = (const float*)d_in[10];
    const float* ln2b = (const float*)d_in[11];
    const float* fw1  = (const float*)d_in[12];
    const float* fb1  = (const float*)d_in[13];
    const float* fw2  = (const float*)d_in[14];
    const float* fb2  = (const float*)d_in[15];

    constexpr int D = 1024, FFN = 4096;
    constexpr int M = 4096; // B*S rows
    constexpr long MB = 1048576;

    char* ws = (char*)d_ws;
    // weights (persistent until consumed):
    u16* WT   = (u16*)(ws + 0*MB);    // QKVG combined (6144,1024)  12 MB [..QKVG gemm]
    u16* WOT  = (u16*)(ws + 12*MB);   // (1024, 2048)                4 MB [..WO]
    u16* fw1T = (u16*)(ws + 16*MB);   // (4096, 1024)                8 MB [..FFN1]
    u16* fw2T = (u16*)(ws + 24*MB);   // (1024, 4096)                8 MB [..FFN2]
    // activations:
    u16*   QKVG = (u16*)(ws + 32*MB); // bf16 (B,S,6144) 48 MB [QKVG gemm .. WO]
                                      //   WO parks fp32 partials in Q/K/V seg bytes of each row
    u16*   Xn   = (u16*)(ws + 80*MB); // bf16 (B,S,D)     8 MB [prep .. QKVG gemm]
    float4* xtab= (float4*)(ws + 88*MB);// fp32 table     2 MB [prep .. QKVG gemm]
    u16*   Vt   = (u16*)(ws + 80*MB); // bf16 (B,H,256,S)16 MB [vtrans .. retention] (reuses Xn+xtab)
    float* X2   = (float*)(ws + 80*MB);//fp32 (B,S,D)    16 MB [ln2_combine .. ffn2_combine]
    u16*   hb   = (u16*)(ws + 0*MB);  // bf16 (B,S,D)     8 MB [ln2_combine .. FFN1] (reuses WT)
    u16*   mid  = (u16*)(ws + 32*MB); // bf16 (B,S,FFN)  32 MB [FFN1 .. FFN2]        (reuses QKVG)
    float* PF   = (float*)(ws + 0*MB);// FFN2 partials: P0 [0,16), P1 [64,80) MB

    // 1. fused prep: 7x weight transpose + xPos table + LN1
    prep_k<<<20992, 256, 0, stream>>>(Wq, Wk, Wv, WG, WO, fw1, fw2, X, ln1w, ln1b,
                                      WT, WOT, fw1T, fw2T, xtab, Xn);
    // 2. fused QKVG projection + xPos table epilogue -> QKVG (B,S,6144)
    mgemm<EPI_QKVG><<<1536, 256, 0, stream>>>(
        Xn, WT, QKVG, D, D, 6144, (const float*)xtab);
    // 3. V^T (B,H,256,S)
    vtrans<<<dim3(64, 8, 16), 256, 0, stream>>>(QKVG + 2048, Vt);
    // 4. retention + groupnorm + silu-gate -> in-place on G segment
    retention_mfma<<<512, 256, 0, stream>>>(QKVG, Vt, gnw, gnb);
    // 5. WO split-K x2: partials into dead Q/K segment bytes of QKVG rows
    mgemm_sk<<<512, 256, 0, stream>>>(
        QKVG + 4096, WOT, (float*)QKVG, 2048, 1024, 6144, 3072, 1024);
    // 6. combine + residual + LN2 -> X2 (fp32) and hb (bf16)
    ln2_combine<<<M, 256, 0, stream>>>((const float*)QKVG, X, ln2w, ln2b, X2, hb);
    // 7. mid = gelu(hb @ W1 + b1)  bf16
    mgemm<EPI_GELU_BIAS><<<1024, 256, 0, stream>>>(
        hb, fw1T, mid, D, D, FFN, fb1);
    // 8. FFN2 split-K x2: partials P0 [0,16), P1 [64,80) MB
    mgemm_sk<<<512, 256, 0, stream>>>(
        mid, fw2T, PF, 4096, 2048, 4096, 1024, 16777216);
    // 9. combine + bias + X2 residual -> d_out (fp32)
    ffn2_combine<<<M, 256, 0, stream>>>(PF, fb2, X2, (float*)d_out);
}

// Round 11
// 472.261 us; speedup vs baseline: 7.6421x; 1.0440x over previous
//
#include <hip/hip_runtime.h>
#include <hip/hip_bf16.h>

typedef unsigned short u16;
typedef unsigned int   u32;
typedef short short8 __attribute__((ext_vector_type(8)));
typedef float f32x4  __attribute__((ext_vector_type(4)));

// ---------- bf16 helpers ----------
__device__ __forceinline__ float b2f(u16 u) { return __uint_as_float(((u32)u) << 16); }
__device__ __forceinline__ u16 f2b(float f) {
    u32 u = __float_as_uint(f);
    u += 0x7FFF + ((u >> 16) & 1);   // RTNE
    return (u16)(u >> 16);
}

// ---------- async global->LDS 16B (wave-uniform LDS base + lane*16) ----------
typedef const unsigned int __attribute__((address_space(1)))* gas1;
typedef unsigned int __attribute__((address_space(3)))* las3;
__device__ __forceinline__ void async_ld16(const void* g, const void* l) {
    __builtin_amdgcn_global_load_lds((gas1)(unsigned long long)g,
                                     (las3)(unsigned int)(unsigned long long)l,
                                     16, 0, 0);
}

// ================= fused prep: 7x wtrans + xPos table + LN1 =================
__device__ __forceinline__ void wtrans_body(const float* __restrict__ W, u16* __restrict__ Wt,
                                            int K, int N, int bx, int by, int bz) {
    __shared__ u16 tile[32][36];
    const int k0 = bx * 32, n0 = by * 32;
    const float* Wz = W + (long)bz * K * N;
    u16* Wtz = Wt + (long)bz * K * N;
    const int t = threadIdx.x;
    const int r = t >> 3, c = (t & 7) * 4;
    float4 v = *(const float4*)(Wz + (long)(k0 + r) * N + n0 + c);
    tile[r][c+0] = f2b(v.x); tile[r][c+1] = f2b(v.y);
    tile[r][c+2] = f2b(v.z); tile[r][c+3] = f2b(v.w);
    __syncthreads();
    uint2 pk;
    pk.x = (u32)tile[c+0][r] | ((u32)tile[c+1][r] << 16);
    pk.y = (u32)tile[c+2][r] | ((u32)tile[c+3][r] << 16);
    *(uint2*)(Wtz + (long)(n0 + r) * K + k0 + c) = pk;
}

__device__ __forceinline__ void xtab_body(float4* __restrict__ tab, int blk) {
    int idx = blk * 256 + threadIdx.x;   // 0..131071
    int j = idx & 63, s = idx >> 6;
    float sv = (2.f * j + 51.2f) / 179.2f;
    float scale = exp2f(log2f(sv) * ((float)s * (1.f / 512.f)));
    float inv_freq = exp2f((float)j * (-13.287712379549449f / 64.f));
    float ang = (float)s * inv_freq;
    float sn = sinf(ang), cs = cosf(ang);
    tab[idx] = make_float4(cs * scale, sn * scale, cs / scale, sn / scale);
}

__device__ __forceinline__ void ln_body(const float* __restrict__ X,
                                        const float* __restrict__ w,
                                        const float* __restrict__ bb,
                                        u16* __restrict__ out, long row) {
    const int t = threadIdx.x;
    float4 p = ((const float4*)(X + row * 1024))[t];
    float x[4] = { p.x, p.y, p.z, p.w };
    float s = x[0]+x[1]+x[2]+x[3];
    float q = x[0]*x[0]+x[1]*x[1]+x[2]*x[2]+x[3]*x[3];
#pragma unroll
    for (int o = 32; o > 0; o >>= 1) { s += __shfl_down(s, o, 64); q += __shfl_down(q, o, 64); }
    __shared__ float aS[4], aQ[4];
    if ((t & 63) == 0) { aS[t >> 6] = s; aQ[t >> 6] = q; }
    __syncthreads();
    s = aS[0]+aS[1]+aS[2]+aS[3];
    q = aQ[0]+aQ[1]+aQ[2]+aQ[3];
    float mean = s * (1.f/1024.f);
    float var  = q * (1.f/1024.f) - mean*mean;
    float rstd = rsqrtf(var + 1e-5f);
    float4 wv = ((const float4*)w)[t];
    float4 bv = ((const float4*)bb)[t];
    uint2 r;
    r.x = (u32)f2b((x[0]-mean)*rstd*wv.x + bv.x) | ((u32)f2b((x[1]-mean)*rstd*wv.y + bv.y) << 16);
    r.y = (u32)f2b((x[2]-mean)*rstd*wv.z + bv.z) | ((u32)f2b((x[3]-mean)*rstd*wv.w + bv.w) << 16);
    ((uint2*)(out + row * 1024))[t] = r;
}

__global__ __launch_bounds__(256) void prep_k(
    const float* __restrict__ Wq, const float* __restrict__ Wk,
    const float* __restrict__ Wv, const float* __restrict__ WG,
    const float* __restrict__ WO, const float* __restrict__ fw1,
    const float* __restrict__ fw2, const float* __restrict__ X,
    const float* __restrict__ ln1w, const float* __restrict__ ln1b,
    u16* __restrict__ WT, u16* __restrict__ WOT,
    u16* __restrict__ fw1T, u16* __restrict__ fw2T,
    float4* __restrict__ xtab, u16* __restrict__ Xn) {
    const int id = blockIdx.x;
    if (id < 16384) {
        const float* W; u16* Wt; int K, N, bx, by, bz = 0;
        if (id < 1024)       { W=Wq;  Wt=WT;           K=1024; N=128;  int l=id;       bx=l&31;  by=(l>>5)&3; bz=l>>7; }
        else if (id < 2048)  { W=Wk;  Wt=WT+1048576;   K=1024; N=128;  int l=id-1024;  bx=l&31;  by=(l>>5)&3; bz=l>>7; }
        else if (id < 4096)  { W=Wv;  Wt=WT+2097152;   K=1024; N=256;  int l=id-2048;  bx=l&31;  by=(l>>5)&7; bz=l>>8; }
        else if (id < 6144)  { W=WG;  Wt=WT+4194304;   K=1024; N=2048; int l=id-4096;  bx=l&31;  by=l>>5; }
        else if (id < 8192)  { W=WO;  Wt=WOT;          K=2048; N=1024; int l=id-6144;  bx=l&63;  by=l>>6; }
        else if (id < 12288) { W=fw1; Wt=fw1T;         K=1024; N=4096; int l=id-8192;  bx=l&31;  by=l>>5; }
        else                 { W=fw2; Wt=fw2T;         K=4096; N=1024; int l=id-12288; bx=l&127; by=l>>7; }
        wtrans_body(W, Wt, K, N, bx, by, bz);
    } else if (id < 16896) {
        xtab_body(xtab, id - 16384);
    } else {
        ln_body(X, ln1w, ln1b, Xn, id - 16896);
    }
}

// ---------- combine WO partials + residual X, then LN2 -> X2 (fp32) and hb (bf16) ----------
__global__ __launch_bounds__(256) void ln2_combine(const float* __restrict__ P,
                                                   const float* __restrict__ X,
                                                   const float* __restrict__ w,
                                                   const float* __restrict__ bb,
                                                   float* __restrict__ X2,
                                                   u16* __restrict__ hb) {
    const long row = blockIdx.x;
    const int t = threadIdx.x;
    const float* p = P + row * 3072;
    float4 a = ((const float4*)p)[t];
    float4 c = ((const float4*)(p + 1024))[t];
    float4 xr = ((const float4*)(X + row * 1024))[t];
    float x[4] = { a.x+c.x+xr.x, a.y+c.y+xr.y, a.z+c.z+xr.z, a.w+c.w+xr.w };
    ((float4*)(X2 + row * 1024))[t] = make_float4(x[0], x[1], x[2], x[3]);
    float s = x[0]+x[1]+x[2]+x[3];
    float q = x[0]*x[0]+x[1]*x[1]+x[2]*x[2]+x[3]*x[3];
#pragma unroll
    for (int o = 32; o > 0; o >>= 1) { s += __shfl_down(s, o, 64); q += __shfl_down(q, o, 64); }
    __shared__ float aS[4], aQ[4];
    if ((t & 63) == 0) { aS[t >> 6] = s; aQ[t >> 6] = q; }
    __syncthreads();
    s = aS[0]+aS[1]+aS[2]+aS[3];
    q = aQ[0]+aQ[1]+aQ[2]+aQ[3];
    float mean = s * (1.f/1024.f);
    float var  = q * (1.f/1024.f) - mean*mean;
    float rstd = rsqrtf(var + 1e-5f);
    float4 wv = ((const float4*)w)[t];
    float4 bv = ((const float4*)bb)[t];
    uint2 r;
    r.x = (u32)f2b((x[0]-mean)*rstd*wv.x + bv.x) | ((u32)f2b((x[1]-mean)*rstd*wv.y + bv.y) << 16);
    r.y = (u32)f2b((x[2]-mean)*rstd*wv.z + bv.z) | ((u32)f2b((x[3]-mean)*rstd*wv.w + bv.w) << 16);
    ((uint2*)(hb + row * 1024))[t] = r;
}

// ---------- combine FFN2 partials + bias + X2 -> d_out (fp32) ----------
__global__ __launch_bounds__(256) void ffn2_combine(const float* __restrict__ P,
                                                    const float* __restrict__ b2,
                                                    const float* __restrict__ X2,
                                                    float* __restrict__ out) {
    const long row = blockIdx.x;
    const int t = threadIdx.x;
    float4 p0 = ((const float4*)(P + row * 1024))[t];
    float4 p1 = ((const float4*)(P + 16777216 + row * 1024))[t];
    float4 x2 = ((const float4*)(X2 + row * 1024))[t];
    float4 bv = ((const float4*)b2)[t];
    ((float4*)(out + row * 1024))[t] = make_float4(
        p0.x + p1.x + x2.x + bv.x, p0.y + p1.y + x2.y + bv.y,
        p0.z + p1.z + x2.z + bv.z, p0.w + p1.w + x2.w + bv.w);
}

// ---------- V transpose (bf16): QKVG V-segment (B,S,6144)+2048 -> Vt (B,H,256,S) ----------
__global__ __launch_bounds__(256) void vtrans(const u16* __restrict__ Vseg, u16* __restrict__ Vt) {
    __shared__ u16 tile[32][36];
    const int s0 = blockIdx.x * 32, v0 = blockIdx.y * 32, z = blockIdx.z; // z = b*8+h
    const int b = z >> 3, h = z & 7;
    const u16* Vz = Vseg + (long)b * 2048 * 6144 + h * 256;
    u16* Vtz = Vt + (long)z * 256 * 2048;
    const int t = threadIdx.x;
    const int r = t >> 3, c = (t & 7) * 4;
    uint2 ld = *(const uint2*)(Vz + (long)(s0 + r) * 6144 + v0 + c);
    tile[r][c+0] = (u16)(ld.x & 0xFFFF); tile[r][c+1] = (u16)(ld.x >> 16);
    tile[r][c+2] = (u16)(ld.y & 0xFFFF); tile[r][c+3] = (u16)(ld.y >> 16);
    __syncthreads();
    uint2 pk;
    pk.x = (u32)tile[c+0][r] | ((u32)tile[c+1][r] << 16);
    pk.y = (u32)tile[c+2][r] | ((u32)tile[c+3][r] << 16);
    *(uint2*)(Vtz + (long)(v0 + r) * 2048 + s0 + c) = pk;
}

// ---------- MFMA GEMM, templated panel count (BK = PANELS*32) ----------
// C = A[M][K] @ Bt[N][K]^T, bf16->fp32->bf16. mb innermost (mb = pid & 31), M=4096.
// Epilogue: ungated scalar u16 stores (measured best, R8).
enum { EPI_GELU_BIAS = 2, EPI_QKVG = 4 };

template<int EPI, int PANELS>
__global__ __launch_bounds__(256) void mgemm(
    const u16* __restrict__ A, const u16* __restrict__ Bt, u16* __restrict__ Cv,
    int K, int aStride, long cStride,
    const float* __restrict__ bias) {
    __shared__ __align__(16) u16 As[PANELS * 4096];
    __shared__ __align__(16) u16 Bs[PANELS * 4096];
    const int pid = blockIdx.x;
    const int mb = pid & 31;
    const int nb = pid >> 5;
    const int t = threadIdx.x;
    const int row0 = mb * 128, col0 = nb * 128;
    const int wave = t >> 6, lane = t & 63;
    const int wm = wave >> 1, wn = wave & 1;
    const int quad = lane >> 4, l16 = lane & 15;
    const u16* Ag = A + (long)(row0 + (t >> 2)) * aStride + ((t & 3) * 8);
    const u16* Bg = Bt + (long)(col0 + (t >> 2)) * K + ((t & 3) * 8);
    const long aj = (long)64 * aStride;
    const long bj = (long)64 * K;
    const u32 lo = __builtin_amdgcn_readfirstlane((u32)(wave * 1024));

    f32x4 acc[4][4];
#pragma unroll
    for (int i = 0; i < 4; i++)
#pragma unroll
        for (int j = 0; j < 4; j++) acc[i][j] = (f32x4){0.f, 0.f, 0.f, 0.f};

    for (int k0 = 0; k0 < K; k0 += PANELS * 32) {
#pragma unroll
        for (int h = 0; h < PANELS; h++) {
            const u16* Agh = Ag + k0 + h * 32;
            const u16* Bgh = Bg + k0 + h * 32;
            async_ld16(Agh,      (const char*)As + h*8192 + lo);
            async_ld16(Agh + aj, (const char*)As + h*8192 + 4096 + lo);
            async_ld16(Bgh,      (const char*)Bs + h*8192 + lo);
            async_ld16(Bgh + bj, (const char*)Bs + h*8192 + 4096 + lo);
        }
        __syncthreads();
#pragma unroll
        for (int h = 0; h < PANELS; h++) {
            short8 af[4], bf[4];
#pragma unroll
            for (int mt = 0; mt < 4; mt++)
                af[mt] = *(const short8*)(As + h*4096 + (wm*64 + mt*16 + l16) * 32 + quad*8);
#pragma unroll
            for (int nt = 0; nt < 4; nt++)
                bf[nt] = *(const short8*)(Bs + h*4096 + (wn*64 + nt*16 + l16) * 32 + quad*8);
#pragma unroll
            for (int mt = 0; mt < 4; mt++)
#pragma unroll
                for (int nt = 0; nt < 4; nt++)
                    acc[mt][nt] = __builtin_amdgcn_mfma_f32_16x16x32_bf16(af[mt], bf[nt], acc[mt][nt], 0, 0, 0);
        }
        __syncthreads();
    }

#pragma unroll
    for (int mt = 0; mt < 4; mt++) {
#pragma unroll
        for (int reg = 0; reg < 4; reg++) {
            int r = row0 + wm*64 + mt*16 + quad*4 + reg;
#pragma unroll
            for (int nt = 0; nt < 4; nt++) {
                int c = col0 + wn*64 + nt*16 + l16;
                float v = acc[mt][nt][reg];
                if constexpr (EPI == EPI_GELU_BIAS) {
                    v += bias[c];
                    v = 0.5f * v * (1.f + erff(v * 0.70710678118654752f));
                } else if constexpr (EPI == EPI_QKVG) {
                    if (c < 2048) {  // xPos rotary: Q (c<1024, up) / K (else, down) via table
                        int j = (c & 127) >> 1;
                        float4 tb = ((const float4*)bias)[((r & 2047) << 6) + j];
                        float cs = (c < 1024) ? tb.x : tb.z;
                        float sn = (c < 1024) ? tb.y : tb.w;
                        float partner = __shfl_xor(v, 1, 64);
                        v = v * cs + ((c & 1) ? partner : -partner) * sn;
                    }
                }
                Cv[(long)r * cStride + c] = f2b(v);
            }
        }
    }
}

// ---------- split-K (x2) MFMA GEMM, BK=64 paneled, N=1024, fp32 partial out ----------
// grid 512: mb = pid&31, nb = (pid&255)>>5, slice = pid>>8. Scalar float stores.
__global__ __launch_bounds__(256) void mgemm_sk(
    const u16* __restrict__ A, const u16* __restrict__ Bt, float* __restrict__ P,
    int K, int kHalf, int aStride, long pRowStride, long sliceOff) {
    __shared__ __align__(16) u16 As[2 * 4096];
    __shared__ __align__(16) u16 Bs[2 * 4096];
    const int pid = blockIdx.x;
    const int mb = pid & 31;
    const int nb = (pid & 255) >> 5;
    const int slice = pid >> 8;
    const int t = threadIdx.x;
    const int row0 = mb * 128, col0 = nb * 128;
    const int wave = t >> 6, lane = t & 63;
    const int wm = wave >> 1, wn = wave & 1;
    const int quad = lane >> 4, l16 = lane & 15;
    const u16* Ag = A + (long)(row0 + (t >> 2)) * aStride + ((t & 3) * 8);
    const u16* Bg = Bt + (long)(col0 + (t >> 2)) * K + ((t & 3) * 8);
    const long aj = (long)64 * aStride;
    const long bj = (long)64 * K;
    const u32 lo = __builtin_amdgcn_readfirstlane((u32)(wave * 1024));

    f32x4 acc[4][4];
#pragma unroll
    for (int i = 0; i < 4; i++)
#pragma unroll
        for (int j = 0; j < 4; j++) acc[i][j] = (f32x4){0.f, 0.f, 0.f, 0.f};

    const int kBeg = slice * kHalf, kEnd = kBeg + kHalf;
    for (int k0 = kBeg; k0 < kEnd; k0 += 64) {
#pragma unroll
        for (int h = 0; h < 2; h++) {
            const u16* Agh = Ag + k0 + h * 32;
            const u16* Bgh = Bg + k0 + h * 32;
            async_ld16(Agh,      (const char*)As + h*8192 + lo);
            async_ld16(Agh + aj, (const char*)As + h*8192 + 4096 + lo);
            async_ld16(Bgh,      (const char*)Bs + h*8192 + lo);
            async_ld16(Bgh + bj, (const char*)Bs + h*8192 + 4096 + lo);
        }
        __syncthreads();
#pragma unroll
        for (int h = 0; h < 2; h++) {
            short8 af[4], bf[4];
#pragma unroll
            for (int mt = 0; mt < 4; mt++)
                af[mt] = *(const short8*)(As + h*4096 + (wm*64 + mt*16 + l16) * 32 + quad*8);
#pragma unroll
            for (int nt = 0; nt < 4; nt++)
                bf[nt] = *(const short8*)(Bs + h*4096 + (wn*64 + nt*16 + l16) * 32 + quad*8);
#pragma unroll
            for (int mt = 0; mt < 4; mt++)
#pragma unroll
                for (int nt = 0; nt < 4; nt++)
                    acc[mt][nt] = __builtin_amdgcn_mfma_f32_16x16x32_bf16(af[mt], bf[nt], acc[mt][nt], 0, 0, 0);
        }
        __syncthreads();
    }

    float* Pb = P + slice * sliceOff;
#pragma unroll
    for (int mt = 0; mt < 4; mt++) {
#pragma unroll
        for (int reg = 0; reg < 4; reg++) {
            int r = row0 + wm*64 + mt*16 + quad*4 + reg;
#pragma unroll
            for (int nt = 0; nt < 4; nt++) {
                int c = col0 + wn*64 + nt*16 + l16;
                Pb[(long)r * pRowStride + c] = acc[mt][nt][reg];
            }
        }
    }
}

// ---------- MFMA retention + fused groupnorm + fused silu-gate ----------
// grid 512 (1D). QKVG (B,S,6144): Q cols 0..1023, K 1024..2047, V 2048..4095, G 4096..6143.
// Writes gated = silu(G)*groupnorm(O) in-place over the G segment. Vt (B,H,256,S).
// Decay via incremental running factor (2 exp2f init, 1 mul/step).
__global__ __launch_bounds__(256) void retention_mfma(
    u16* __restrict__ QKVG, const u16* __restrict__ Vt,
    const float* __restrict__ gnw, const float* __restrict__ gnb) {
    __shared__ __align__(16) u16 Qs[4][64][32];
    __shared__ __align__(16) u16 Ks[2][4][32][32];
    __shared__ __align__(16) u16 Vs[2][256][32];
    __shared__ u16 Ss[64][40];
    const int id = blockIdx.x;
    const int halfg = id >> 8, r5 = id & 255;
    const int bh = r5 >> 4, i16 = r5 & 15;
    const int tile = halfg ? i16 : 31 - i16;   // pair (i, i+256) work = 68 steps const
    const int b = bh >> 3, h = bh & 7;
    const int t = threadIdx.x;
    const int wave = t >> 6, lane = t & 63, quad = lane >> 4, l16 = lane & 15;
    const u32 lo = __builtin_amdgcn_readfirstlane((u32)(wave * 1024));
    const u16* Qbase = QKVG + (long)b * 2048 * 6144 + h * 128;
    const u16* Kbase = Qbase + 1024;
    const u16* Vbase = Vt + (long)(b * 8 + h) * 256 * 2048;
    u16* Gseg = QKVG + (long)b * 2048 * 6144 + 4096 + h * 256;

    float g = 1.f - expf(-3.4657359027997265f + (-0.3960841031771116f) * (float)h);
    float log2g = log2f(g);
    const float gi16 = exp2f(log2g * -16.f);   // γ^-16
    const float gi32 = gi16 * gi16;            // γ^-32 (per-step update)
    const float gf[4] = {1.f, g, g*g, g*g*g};
    const int srow0 = tile*64 + wave*16 + quad*4;
    float drun = exp2f(log2g * (float)(srow0 - l16));   // γ^(srow0 - l16) at jt=0

    auto issueKV = [&](int jt, int buf) {
#pragma unroll
        for (int i = 0; i < 2; i++) {
            int c = t + i * 256;
            int ks = c >> 7, row = (c >> 2) & 31, cb = c & 3;
            async_ld16(Kbase + (long)(jt*32 + row) * 6144 + ks*32 + cb*8,
                       (const char*)Ks + buf*8192 + i*4096 + lo);
        }
#pragma unroll
        for (int i = 0; i < 4; i++) {
            int c = t + i * 256;
            int row = c >> 2, cb = c & 3;
            async_ld16(Vbase + (long)row * 2048 + jt*32 + cb*8,
                       (const char*)Vs + buf*16384 + i*4096 + lo);
        }
    };

    // prologue: Q tile + (K,V) for jt=0 into buf 0
#pragma unroll
    for (int i = 0; i < 4; i++) {
        int c = t + i * 256;
        int ks = c >> 8, row = (c >> 2) & 63, cb = c & 3;
        async_ld16(Qbase + (long)(tile*64 + row) * 6144 + ks*32 + cb*8,
                   (const char*)Qs + i*4096 + lo);
    }
    issueKV(0, 0);

    float gw[16], gbv[16];
#pragma unroll
    for (int nt = 0; nt < 16; nt++) {
        gw[nt]  = gnw[h*256 + nt*16 + l16];
        gbv[nt] = gnb[h*256 + nt*16 + l16];
    }
    f32x4 oacc[16];
#pragma unroll
    for (int nt = 0; nt < 16; nt++) oacc[nt] = (f32x4){0.f, 0.f, 0.f, 0.f};
    __syncthreads();

    const int njt = 2 * tile + 2;
    for (int jt = 0; jt < njt; jt++) {
        const int cur = jt & 1;
        if (jt + 1 < njt) issueKV(jt + 1, cur ^ 1);   // prefetch overlaps compute
        // QK^T
        f32x4 s0 = (f32x4){0.f,0.f,0.f,0.f}, s1 = (f32x4){0.f,0.f,0.f,0.f};
#pragma unroll
        for (int ks = 0; ks < 4; ks++) {
            short8 aq = *(const short8*)&Qs[ks][wave*16 + l16][quad*8];
            short8 b0 = *(const short8*)&Ks[cur][ks][l16][quad*8];
            short8 b1 = *(const short8*)&Ks[cur][ks][16 + l16][quad*8];
            s0 = __builtin_amdgcn_mfma_f32_16x16x32_bf16(aq, b0, s0, 0, 0, 0);
            s1 = __builtin_amdgcn_mfma_f32_16x16x32_bf16(aq, b1, s1, 0, 0, 0);
        }
        // decay + causal mask -> Ss (wave-private rows: no barrier needed)
#pragma unroll
        for (int reg = 0; reg < 4; reg++) {
            int srow = srow0 + reg;
            int tc0 = jt*32 + l16, tc1 = tc0 + 16;
            float dbase = drun * gf[reg];               // γ^(srow - tc0)
            float d0 = (srow >= tc0) ? dbase : 0.f;
            float d1 = (srow >= tc1) ? dbase * gi16 : 0.f;
            Ss[wave*16 + quad*4 + reg][l16]      = f2b(s0[reg] * d0);
            Ss[wave*16 + quad*4 + reg][16 + l16] = f2b(s1[reg] * d1);
        }
        drun *= gi32;
        // PV: O[64x256] += S[64x32] @ V[32x256]
        short8 as = *(const short8*)&Ss[wave*16 + l16][quad*8];
#pragma unroll
        for (int nt = 0; nt < 16; nt++) {
            short8 bv = *(const short8*)&Vs[cur][nt*16 + l16][quad*8];
            oacc[nt] = __builtin_amdgcn_mfma_f32_16x16x32_bf16(as, bv, oacc[nt], 0, 0, 0);
        }
        __syncthreads();   // drains prefetch + guards buf reuse
    }

    // fused groupnorm + silu(G) gate, written in-place over G segment
#pragma unroll
    for (int reg = 0; reg < 4; reg++) {
        float s = 0.f, q = 0.f;
#pragma unroll
        for (int nt = 0; nt < 16; nt++) { float v = oacc[nt][reg]; s += v; q += v*v; }
#pragma unroll
        for (int m = 1; m < 16; m <<= 1) { s += __shfl_xor(s, m, 16); q += __shfl_xor(q, m, 16); }
        float mean = s * (1.f/256.f);
        float var  = q * (1.f/256.f) - mean*mean;
        float rstd = rsqrtf(var + 1e-5f);
        int srow = srow0 + reg;
        u16* grow = Gseg + (long)srow * 6144;
#pragma unroll
        for (int nt = 0; nt < 16; nt++) {
            float gval = b2f(grow[nt*16 + l16]);
            float y = (oacc[nt][reg] - mean) * rstd * gw[nt] + gbv[nt];
            float sg = gval / (1.f + expf(-gval));
            grow[nt*16 + l16] = f2b(sg * y);
        }
    }
}

extern "C" void kernel_launch(void* const* d_in, const int* in_sizes, int n_in,
                              void* d_out, int out_size, void* d_ws, size_t ws_size,
                              hipStream_t stream) {
    (void)in_sizes; (void)n_in; (void)out_size; (void)ws_size;
    const float* X    = (const float*)d_in[0];
    const float* Wq   = (const float*)d_in[1];
    const float* Wk   = (const float*)d_in[2];
    const float* Wv   = (const float*)d_in[3];
    const float* WG   = (const float*)d_in[4];
    const float* WO   = (const float*)d_in[5];
    const float* gnw  = (const float*)d_in[6];
    const float* gnb  = (const float*)d_in[7];
    const float* ln1w = (const float*)d_in[8];
    const float* ln1b = (const float*)d_in[9];
    const float* ln2w = (const float*)d_in[10];
    const float* ln2b = (const float*)d_in[11];
    const float* fw1  = (const float*)d_in[12];
    const float* fb1  = (const float*)d_in[13];
    const float* fw2  = (const float*)d_in[14];
    const float* fb2  = (const float*)d_in[15];

    constexpr int D = 1024, FFN = 4096;
    constexpr int M = 4096; // B*S rows
    constexpr long MB = 1048576;

    char* ws = (char*)d_ws;
    // weights (persistent until consumed):
    u16* WT   = (u16*)(ws + 0*MB);    // QKVG combined (6144,1024)  12 MB [..QKVG gemm]
    u16* WOT  = (u16*)(ws + 12*MB);   // (1024, 2048)                4 MB [..WO]
    u16* fw1T = (u16*)(ws + 16*MB);   // (4096, 1024)                8 MB [..FFN1]
    u16* fw2T = (u16*)(ws + 24*MB);   // (1024, 4096)                8 MB [..FFN2]
    // activations:
    u16*   QKVG = (u16*)(ws + 32*MB); // bf16 (B,S,6144) 48 MB [QKVG gemm .. WO]
                                      //   WO parks fp32 partials in Q/K/V seg bytes of each row
    u16*   Xn   = (u16*)(ws + 80*MB); // bf16 (B,S,D)     8 MB [prep .. QKVG gemm]
    float4* xtab= (float4*)(ws + 88*MB);// fp32 table     2 MB [prep .. QKVG gemm]
    u16*   Vt   = (u16*)(ws + 80*MB); // bf16 (B,H,256,S)16 MB [vtrans .. retention] (reuses Xn+xtab)
    float* X2   = (float*)(ws + 80*MB);//fp32 (B,S,D)    16 MB [ln2_combine .. ffn2_combine]
    u16*   hb   = (u16*)(ws + 0*MB);  // bf16 (B,S,D)     8 MB [ln2_combine .. FFN1] (reuses WT)
    u16*   mid  = (u16*)(ws + 32*MB); // bf16 (B,S,FFN)  32 MB [FFN1 .. FFN2]        (reuses QKVG)
    float* PF   = (float*)(ws + 0*MB);// FFN2 partials: P0 [0,16), P1 [64,80) MB

    // 1. fused prep: 7x weight transpose + xPos table + LN1
    prep_k<<<20992, 256, 0, stream>>>(Wq, Wk, Wv, WG, WO, fw1, fw2, X, ln1w, ln1b,
                                      WT, WOT, fw1T, fw2T, xtab, Xn);
    // 2. fused QKVG projection + xPos table epilogue -> QKVG (B,S,6144)  [BK=32]
    mgemm<EPI_QKVG, 1><<<1536, 256, 0, stream>>>(
        Xn, WT, QKVG, D, D, 6144, (const float*)xtab);
    // 3. V^T (B,H,256,S)
    vtrans<<<dim3(64, 8, 16), 256, 0, stream>>>(QKVG + 2048, Vt);
    // 4. retention + groupnorm + silu-gate -> in-place on G segment
    retention_mfma<<<512, 256, 0, stream>>>(QKVG, Vt, gnw, gnb);
    // 5. WO split-K x2: partials into dead Q/K segment bytes of QKVG rows  [BK=64]
    mgemm_sk<<<512, 256, 0, stream>>>(
        QKVG + 4096, WOT, (float*)QKVG, 2048, 1024, 6144, 3072, 1024);
    // 6. combine + residual + LN2 -> X2 (fp32) and hb (bf16)
    ln2_combine<<<M, 256, 0, stream>>>((const float*)QKVG, X, ln2w, ln2b, X2, hb);
    // 7. mid = gelu(hb @ W1 + b1)  bf16  [BK=64]
    mgemm<EPI_GELU_BIAS, 2><<<1024, 256, 0, stream>>>(
        hb, fw1T, mid, D, D, FFN, fb1);
    // 8. FFN2 split-K x2: partials P0 [0,16), P1 [64,80) MB  [BK=64]
    mgemm_sk<<<512, 256, 0, stream>>>(
        mid, fw2T, PF, 4096, 2048, 4096, 1024, 16777216);
    // 9. combine + bias + X2 residual -> d_out (fp32)
    ffn2_combine<<<M, 256, 0, stream>>>(PF, fb2, X2, (float*)d_out);
}

// Round 12
// 446.084 us; speedup vs baseline: 8.0906x; 1.0587x over previous
//
#include <hip/hip_runtime.h>
#include <hip/hip_bf16.h>

typedef unsigned short u16;
typedef unsigned int   u32;
typedef short short8 __attribute__((ext_vector_type(8)));
typedef float f32x4  __attribute__((ext_vector_type(4)));

// ---------- bf16 helpers ----------
__device__ __forceinline__ float b2f(u16 u) { return __uint_as_float(((u32)u) << 16); }
__device__ __forceinline__ u16 f2b(float f) {
    u32 u = __float_as_uint(f);
    u += 0x7FFF + ((u >> 16) & 1);   // RTNE
    return (u16)(u >> 16);
}
// fast gelu (tanh form), |err| < 4e-4 (far below bf16 storage rounding)
__device__ __forceinline__ float gelu_fast(float v) {
    float a = v * (2.302118f + 0.102953f * v * v);   // 2*log2e*0.79788456*(1+0.044715 v^2)
    a = fminf(a, 120.f);                              // avoid inf/inf for v > ~10.8
    float e = exp2f(a);
    return v * e / (1.f + e);
}

// ---------- async global->LDS 16B (wave-uniform LDS base + lane*16) ----------
typedef const unsigned int __attribute__((address_space(1)))* gas1;
typedef unsigned int __attribute__((address_space(3)))* las3;
__device__ __forceinline__ void async_ld16(const void* g, const void* l) {
    __builtin_amdgcn_global_load_lds((gas1)(unsigned long long)g,
                                     (las3)(unsigned int)(unsigned long long)l,
                                     16, 0, 0);
}

// ================= fused prep: 7x wtrans + xPos table + LN1 =================
__device__ __forceinline__ void wtrans_body(const float* __restrict__ W, u16* __restrict__ Wt,
                                            int K, int N, int bx, int by, int bz) {
    __shared__ u16 tile[32][36];
    const int k0 = bx * 32, n0 = by * 32;
    const float* Wz = W + (long)bz * K * N;
    u16* Wtz = Wt + (long)bz * K * N;
    const int t = threadIdx.x;
    const int r = t >> 3, c = (t & 7) * 4;
    float4 v = *(const float4*)(Wz + (long)(k0 + r) * N + n0 + c);
    tile[r][c+0] = f2b(v.x); tile[r][c+1] = f2b(v.y);
    tile[r][c+2] = f2b(v.z); tile[r][c+3] = f2b(v.w);
    __syncthreads();
    uint2 pk;
    pk.x = (u32)tile[c+0][r] | ((u32)tile[c+1][r] << 16);
    pk.y = (u32)tile[c+2][r] | ((u32)tile[c+3][r] << 16);
    *(uint2*)(Wtz + (long)(n0 + r) * K + k0 + c) = pk;
}

__device__ __forceinline__ void xtab_body(float4* __restrict__ tab, int blk) {
    int idx = blk * 256 + threadIdx.x;   // 0..131071
    int j = idx & 63, s = idx >> 6;
    float sv = (2.f * j + 51.2f) / 179.2f;
    float scale = exp2f(log2f(sv) * ((float)s * (1.f / 512.f)));
    float inv_freq = exp2f((float)j * (-13.287712379549449f / 64.f));
    float ang = (float)s * inv_freq;
    float sn = sinf(ang), cs = cosf(ang);
    tab[idx] = make_float4(cs * scale, sn * scale, cs / scale, sn / scale);
}

__device__ __forceinline__ void ln_body(const float* __restrict__ X,
                                        const float* __restrict__ w,
                                        const float* __restrict__ bb,
                                        u16* __restrict__ out, long row) {
    const int t = threadIdx.x;
    float4 p = ((const float4*)(X + row * 1024))[t];
    float x[4] = { p.x, p.y, p.z, p.w };
    float s = x[0]+x[1]+x[2]+x[3];
    float q = x[0]*x[0]+x[1]*x[1]+x[2]*x[2]+x[3]*x[3];
#pragma unroll
    for (int o = 32; o > 0; o >>= 1) { s += __shfl_down(s, o, 64); q += __shfl_down(q, o, 64); }
    __shared__ float aS[4], aQ[4];
    if ((t & 63) == 0) { aS[t >> 6] = s; aQ[t >> 6] = q; }
    __syncthreads();
    s = aS[0]+aS[1]+aS[2]+aS[3];
    q = aQ[0]+aQ[1]+aQ[2]+aQ[3];
    float mean = s * (1.f/1024.f);
    float var  = q * (1.f/1024.f) - mean*mean;
    float rstd = rsqrtf(var + 1e-5f);
    float4 wv = ((const float4*)w)[t];
    float4 bv = ((const float4*)bb)[t];
    uint2 r;
    r.x = (u32)f2b((x[0]-mean)*rstd*wv.x + bv.x) | ((u32)f2b((x[1]-mean)*rstd*wv.y + bv.y) << 16);
    r.y = (u32)f2b((x[2]-mean)*rstd*wv.z + bv.z) | ((u32)f2b((x[3]-mean)*rstd*wv.w + bv.w) << 16);
    ((uint2*)(out + row * 1024))[t] = r;
}

__global__ __launch_bounds__(256) void prep_k(
    const float* __restrict__ Wq, const float* __restrict__ Wk,
    const float* __restrict__ Wv, const float* __restrict__ WG,
    const float* __restrict__ WO, const float* __restrict__ fw1,
    const float* __restrict__ fw2, const float* __restrict__ X,
    const float* __restrict__ ln1w, const float* __restrict__ ln1b,
    u16* __restrict__ WT, u16* __restrict__ WOT,
    u16* __restrict__ fw1T, u16* __restrict__ fw2T,
    float4* __restrict__ xtab, u16* __restrict__ Xn) {
    const int id = blockIdx.x;
    if (id < 16384) {
        const float* W; u16* Wt; int K, N, bx, by, bz = 0;
        if (id < 1024)       { W=Wq;  Wt=WT;           K=1024; N=128;  int l=id;       bx=l&31;  by=(l>>5)&3; bz=l>>7; }
        else if (id < 2048)  { W=Wk;  Wt=WT+1048576;   K=1024; N=128;  int l=id-1024;  bx=l&31;  by=(l>>5)&3; bz=l>>7; }
        else if (id < 4096)  { W=Wv;  Wt=WT+2097152;   K=1024; N=256;  int l=id-2048;  bx=l&31;  by=(l>>5)&7; bz=l>>8; }
        else if (id < 6144)  { W=WG;  Wt=WT+4194304;   K=1024; N=2048; int l=id-4096;  bx=l&31;  by=l>>5; }
        else if (id < 8192)  { W=WO;  Wt=WOT;          K=2048; N=1024; int l=id-6144;  bx=l&63;  by=l>>6; }
        else if (id < 12288) { W=fw1; Wt=fw1T;         K=1024; N=4096; int l=id-8192;  bx=l&31;  by=l>>5; }
        else                 { W=fw2; Wt=fw2T;         K=4096; N=1024; int l=id-12288; bx=l&127; by=l>>7; }
        wtrans_body(W, Wt, K, N, bx, by, bz);
    } else if (id < 16896) {
        xtab_body(xtab, id - 16384);
    } else {
        ln_body(X, ln1w, ln1b, Xn, id - 16896);
    }
}

// ---------- combine WO partials + residual X, then LN2 -> X2 (fp32) and hb (bf16) ----------
__global__ __launch_bounds__(256) void ln2_combine(const float* __restrict__ P,
                                                   const float* __restrict__ X,
                                                   const float* __restrict__ w,
                                                   const float* __restrict__ bb,
                                                   float* __restrict__ X2,
                                                   u16* __restrict__ hb) {
    const long row = blockIdx.x;
    const int t = threadIdx.x;
    const float* p = P + row * 3072;
    float4 a = ((const float4*)p)[t];
    float4 c = ((const float4*)(p + 1024))[t];
    float4 xr = ((const float4*)(X + row * 1024))[t];
    float x[4] = { a.x+c.x+xr.x, a.y+c.y+xr.y, a.z+c.z+xr.z, a.w+c.w+xr.w };
    ((float4*)(X2 + row * 1024))[t] = make_float4(x[0], x[1], x[2], x[3]);
    float s = x[0]+x[1]+x[2]+x[3];
    float q = x[0]*x[0]+x[1]*x[1]+x[2]*x[2]+x[3]*x[3];
#pragma unroll
    for (int o = 32; o > 0; o >>= 1) { s += __shfl_down(s, o, 64); q += __shfl_down(q, o, 64); }
    __shared__ float aS[4], aQ[4];
    if ((t & 63) == 0) { aS[t >> 6] = s; aQ[t >> 6] = q; }
    __syncthreads();
    s = aS[0]+aS[1]+aS[2]+aS[3];
    q = aQ[0]+aQ[1]+aQ[2]+aQ[3];
    float mean = s * (1.f/1024.f);
    float var  = q * (1.f/1024.f) - mean*mean;
    float rstd = rsqrtf(var + 1e-5f);
    float4 wv = ((const float4*)w)[t];
    float4 bv = ((const float4*)bb)[t];
    uint2 r;
    r.x = (u32)f2b((x[0]-mean)*rstd*wv.x + bv.x) | ((u32)f2b((x[1]-mean)*rstd*wv.y + bv.y) << 16);
    r.y = (u32)f2b((x[2]-mean)*rstd*wv.z + bv.z) | ((u32)f2b((x[3]-mean)*rstd*wv.w + bv.w) << 16);
    ((uint2*)(hb + row * 1024))[t] = r;
}

// ---------- combine FFN2 partials + bias + X2 -> d_out (fp32) ----------
__global__ __launch_bounds__(256) void ffn2_combine(const float* __restrict__ P,
                                                    const float* __restrict__ b2,
                                                    const float* __restrict__ X2,
                                                    float* __restrict__ out) {
    const long row = blockIdx.x;
    const int t = threadIdx.x;
    float4 p0 = ((const float4*)(P + row * 1024))[t];
    float4 p1 = ((const float4*)(P + 16777216 + row * 1024))[t];
    float4 x2 = ((const float4*)(X2 + row * 1024))[t];
    float4 bv = ((const float4*)b2)[t];
    ((float4*)(out + row * 1024))[t] = make_float4(
        p0.x + p1.x + x2.x + bv.x, p0.y + p1.y + x2.y + bv.y,
        p0.z + p1.z + x2.z + bv.z, p0.w + p1.w + x2.w + bv.w);
}

// ---------- MFMA GEMM, templated panel count (BK = PANELS*32) ----------
// C = A[M][K] @ Bt[N][K]^T, bf16->fp32->bf16. mb innermost (mb = pid & 31), M=4096.
// EPI_QKVG: rotary for c<2048 (via xtab in `bias`); V-range blocks (2048<=col0<4096)
// store DIRECTLY TRANSPOSED into Vt (B,H,256,S) and skip the row-major write.
enum { EPI_GELU_BIAS = 2, EPI_QKVG = 4 };

template<int EPI, int PANELS>
__global__ __launch_bounds__(256) void mgemm(
    const u16* __restrict__ A, const u16* __restrict__ Bt, u16* __restrict__ Cv,
    int K, int aStride, long cStride,
    const float* __restrict__ bias, u16* __restrict__ Vt) {
    __shared__ __align__(16) u16 As[PANELS * 4096];
    __shared__ __align__(16) u16 Bs[PANELS * 4096];
    const int pid = blockIdx.x;
    const int mb = pid & 31;
    const int nb = pid >> 5;
    const int t = threadIdx.x;
    const int row0 = mb * 128, col0 = nb * 128;
    const int wave = t >> 6, lane = t & 63;
    const int wm = wave >> 1, wn = wave & 1;
    const int quad = lane >> 4, l16 = lane & 15;
    const u16* Ag = A + (long)(row0 + (t >> 2)) * aStride + ((t & 3) * 8);
    const u16* Bg = Bt + (long)(col0 + (t >> 2)) * K + ((t & 3) * 8);
    const long aj = (long)64 * aStride;
    const long bj = (long)64 * K;
    const u32 lo = __builtin_amdgcn_readfirstlane((u32)(wave * 1024));

    f32x4 acc[4][4];
#pragma unroll
    for (int i = 0; i < 4; i++)
#pragma unroll
        for (int j = 0; j < 4; j++) acc[i][j] = (f32x4){0.f, 0.f, 0.f, 0.f};

    for (int k0 = 0; k0 < K; k0 += PANELS * 32) {
#pragma unroll
        for (int h = 0; h < PANELS; h++) {
            const u16* Agh = Ag + k0 + h * 32;
            const u16* Bgh = Bg + k0 + h * 32;
            async_ld16(Agh,      (const char*)As + h*8192 + lo);
            async_ld16(Agh + aj, (const char*)As + h*8192 + 4096 + lo);
            async_ld16(Bgh,      (const char*)Bs + h*8192 + lo);
            async_ld16(Bgh + bj, (const char*)Bs + h*8192 + 4096 + lo);
        }
        __syncthreads();
#pragma unroll
        for (int h = 0; h < PANELS; h++) {
            short8 af[4], bf[4];
#pragma unroll
            for (int mt = 0; mt < 4; mt++)
                af[mt] = *(const short8*)(As + h*4096 + (wm*64 + mt*16 + l16) * 32 + quad*8);
#pragma unroll
            for (int nt = 0; nt < 4; nt++)
                bf[nt] = *(const short8*)(Bs + h*4096 + (wn*64 + nt*16 + l16) * 32 + quad*8);
#pragma unroll
            for (int mt = 0; mt < 4; mt++)
#pragma unroll
                for (int nt = 0; nt < 4; nt++)
                    acc[mt][nt] = __builtin_amdgcn_mfma_f32_16x16x32_bf16(af[mt], bf[nt], acc[mt][nt], 0, 0, 0);
        }
        __syncthreads();
    }

    if constexpr (EPI == EPI_QKVG) {
        if (col0 >= 2048 && col0 < 4096) {
            // V blocks: store transposed into Vt (B,H,256,S). reg 0..3 = 4 consecutive s.
            const int bq = row0 >> 11;
            const int sb = (row0 & 2047) + wm*64 + quad*4;
#pragma unroll
            for (int mt = 0; mt < 4; mt++) {
#pragma unroll
                for (int nt = 0; nt < 4; nt++) {
                    int vc = (col0 - 2048) + wn*64 + nt*16 + l16;
                    u16* dst = Vt + ((long)((bq << 3) + (vc >> 8)) * 256 + (vc & 255)) * 2048
                                  + sb + mt*16;
                    uint2 pk;
                    pk.x = (u32)f2b(acc[mt][nt][0]) | ((u32)f2b(acc[mt][nt][1]) << 16);
                    pk.y = (u32)f2b(acc[mt][nt][2]) | ((u32)f2b(acc[mt][nt][3]) << 16);
                    *(uint2*)dst = pk;
                }
            }
            return;
        }
    }

#pragma unroll
    for (int mt = 0; mt < 4; mt++) {
#pragma unroll
        for (int reg = 0; reg < 4; reg++) {
            int r = row0 + wm*64 + mt*16 + quad*4 + reg;
#pragma unroll
            for (int nt = 0; nt < 4; nt++) {
                int c = col0 + wn*64 + nt*16 + l16;
                float v = acc[mt][nt][reg];
                if constexpr (EPI == EPI_GELU_BIAS) {
                    v = gelu_fast(v + bias[c]);
                } else if constexpr (EPI == EPI_QKVG) {
                    if (c < 2048) {  // xPos rotary: Q (c<1024, up) / K (else, down) via table
                        int j = (c & 127) >> 1;
                        float4 tb = ((const float4*)bias)[((r & 2047) << 6) + j];
                        float cs = (c < 1024) ? tb.x : tb.z;
                        float sn = (c < 1024) ? tb.y : tb.w;
                        float partner = __shfl_xor(v, 1, 64);
                        v = v * cs + ((c & 1) ? partner : -partner) * sn;
                    }
                }
                Cv[(long)r * cStride + c] = f2b(v);
            }
        }
    }
}

// ---------- split-K (x2) MFMA GEMM, BK=64 paneled, N=1024, fp32 partial out ----------
__global__ __launch_bounds__(256) void mgemm_sk(
    const u16* __restrict__ A, const u16* __restrict__ Bt, float* __restrict__ P,
    int K, int kHalf, int aStride, long pRowStride, long sliceOff) {
    __shared__ __align__(16) u16 As[2 * 4096];
    __shared__ __align__(16) u16 Bs[2 * 4096];
    const int pid = blockIdx.x;
    const int mb = pid & 31;
    const int nb = (pid & 255) >> 5;
    const int slice = pid >> 8;
    const int t = threadIdx.x;
    const int row0 = mb * 128, col0 = nb * 128;
    const int wave = t >> 6, lane = t & 63;
    const int wm = wave >> 1, wn = wave & 1;
    const int quad = lane >> 4, l16 = lane & 15;
    const u16* Ag = A + (long)(row0 + (t >> 2)) * aStride + ((t & 3) * 8);
    const u16* Bg = Bt + (long)(col0 + (t >> 2)) * K + ((t & 3) * 8);
    const long aj = (long)64 * aStride;
    const long bj = (long)64 * K;
    const u32 lo = __builtin_amdgcn_readfirstlane((u32)(wave * 1024));

    f32x4 acc[4][4];
#pragma unroll
    for (int i = 0; i < 4; i++)
#pragma unroll
        for (int j = 0; j < 4; j++) acc[i][j] = (f32x4){0.f, 0.f, 0.f, 0.f};

    const int kBeg = slice * kHalf, kEnd = kBeg + kHalf;
    for (int k0 = kBeg; k0 < kEnd; k0 += 64) {
#pragma unroll
        for (int h = 0; h < 2; h++) {
            const u16* Agh = Ag + k0 + h * 32;
            const u16* Bgh = Bg + k0 + h * 32;
            async_ld16(Agh,      (const char*)As + h*8192 + lo);
            async_ld16(Agh + aj, (const char*)As + h*8192 + 4096 + lo);
            async_ld16(Bgh,      (const char*)Bs + h*8192 + lo);
            async_ld16(Bgh + bj, (const char*)Bs + h*8192 + 4096 + lo);
        }
        __syncthreads();
#pragma unroll
        for (int h = 0; h < 2; h++) {
            short8 af[4], bf[4];
#pragma unroll
            for (int mt = 0; mt < 4; mt++)
                af[mt] = *(const short8*)(As + h*4096 + (wm*64 + mt*16 + l16) * 32 + quad*8);
#pragma unroll
            for (int nt = 0; nt < 4; nt++)
                bf[nt] = *(const short8*)(Bs + h*4096 + (wn*64 + nt*16 + l16) * 32 + quad*8);
#pragma unroll
            for (int mt = 0; mt < 4; mt++)
#pragma unroll
                for (int nt = 0; nt < 4; nt++)
                    acc[mt][nt] = __builtin_amdgcn_mfma_f32_16x16x32_bf16(af[mt], bf[nt], acc[mt][nt], 0, 0, 0);
        }
        __syncthreads();
    }

    float* Pb = P + slice * sliceOff;
#pragma unroll
    for (int mt = 0; mt < 4; mt++) {
#pragma unroll
        for (int reg = 0; reg < 4; reg++) {
            int r = row0 + wm*64 + mt*16 + quad*4 + reg;
#pragma unroll
            for (int nt = 0; nt < 4; nt++) {
                int c = col0 + wn*64 + nt*16 + l16;
                Pb[(long)r * pRowStride + c] = acc[mt][nt][reg];
            }
        }
    }
}

// ---------- MFMA retention + fused groupnorm + fused silu-gate ----------
// grid 512 (1D). QKVG (B,S,6144): Q cols 0..1023, K 1024..2047, G 4096..6143.
// Writes gated = silu(G)*groupnorm(O) in-place over the G segment. Vt (B,H,256,S).
__global__ __launch_bounds__(256) void retention_mfma(
    u16* __restrict__ QKVG, const u16* __restrict__ Vt,
    const float* __restrict__ gnw, const float* __restrict__ gnb) {
    __shared__ __align__(16) u16 Qs[4][64][32];
    __shared__ __align__(16) u16 Ks[2][4][32][32];
    __shared__ __align__(16) u16 Vs[2][256][32];
    __shared__ u16 Ss[64][40];
    const int id = blockIdx.x;
    const int halfg = id >> 8, r5 = id & 255;
    const int bh = r5 >> 4, i16 = r5 & 15;
    const int tile = halfg ? i16 : 31 - i16;   // pair (i, i+256) work = 68 steps const
    const int b = bh >> 3, h = bh & 7;
    const int t = threadIdx.x;
    const int wave = t >> 6, lane = t & 63, quad = lane >> 4, l16 = lane & 15;
    const u32 lo = __builtin_amdgcn_readfirstlane((u32)(wave * 1024));
    const u16* Qbase = QKVG + (long)b * 2048 * 6144 + h * 128;
    const u16* Kbase = Qbase + 1024;
    const u16* Vbase = Vt + (long)(b * 8 + h) * 256 * 2048;
    u16* Gseg = QKVG + (long)b * 2048 * 6144 + 4096 + h * 256;

    float g = 1.f - expf(-3.4657359027997265f + (-0.3960841031771116f) * (float)h);
    float log2g = log2f(g);
    const float gi16 = exp2f(log2g * -16.f);   // γ^-16
    const float gi32 = gi16 * gi16;            // γ^-32 (per-step update)
    const float gf[4] = {1.f, g, g*g, g*g*g};
    const int srow0 = tile*64 + wave*16 + quad*4;
    float drun = exp2f(log2g * (float)(srow0 - l16));   // γ^(srow0 - l16) at jt=0

    auto issueKV = [&](int jt, int buf) {
#pragma unroll
        for (int i = 0; i < 2; i++) {
            int c = t + i * 256;
            int ks = c >> 7, row = (c >> 2) & 31, cb = c & 3;
            async_ld16(Kbase + (long)(jt*32 + row) * 6144 + ks*32 + cb*8,
                       (const char*)Ks + buf*8192 + i*4096 + lo);
        }
#pragma unroll
        for (int i = 0; i < 4; i++) {
            int c = t + i * 256;
            int row = c >> 2, cb = c & 3;
            async_ld16(Vbase + (long)row * 2048 + jt*32 + cb*8,
                       (const char*)Vs + buf*16384 + i*4096 + lo);
        }
    };

    // prologue: Q tile + (K,V) for jt=0 into buf 0
#pragma unroll
    for (int i = 0; i < 4; i++) {
        int c = t + i * 256;
        int ks = c >> 8, row = (c >> 2) & 63, cb = c & 3;
        async_ld16(Qbase + (long)(tile*64 + row) * 6144 + ks*32 + cb*8,
                   (const char*)Qs + i*4096 + lo);
    }
    issueKV(0, 0);

    float gw[16], gbv[16];
#pragma unroll
    for (int nt = 0; nt < 16; nt++) {
        gw[nt]  = gnw[h*256 + nt*16 + l16];
        gbv[nt] = gnb[h*256 + nt*16 + l16];
    }
    f32x4 oacc[16];
#pragma unroll
    for (int nt = 0; nt < 16; nt++) oacc[nt] = (f32x4){0.f, 0.f, 0.f, 0.f};
    __syncthreads();

    const int njt = 2 * tile + 2;
    for (int jt = 0; jt < njt; jt++) {
        const int cur = jt & 1;
        if (jt + 1 < njt) issueKV(jt + 1, cur ^ 1);   // prefetch overlaps compute
        // QK^T
        f32x4 s0 = (f32x4){0.f,0.f,0.f,0.f}, s1 = (f32x4){0.f,0.f,0.f,0.f};
#pragma unroll
        for (int ks = 0; ks < 4; ks++) {
            short8 aq = *(const short8*)&Qs[ks][wave*16 + l16][quad*8];
            short8 b0 = *(const short8*)&Ks[cur][ks][l16][quad*8];
            short8 b1 = *(const short8*)&Ks[cur][ks][16 + l16][quad*8];
            s0 = __builtin_amdgcn_mfma_f32_16x16x32_bf16(aq, b0, s0, 0, 0, 0);
            s1 = __builtin_amdgcn_mfma_f32_16x16x32_bf16(aq, b1, s1, 0, 0, 0);
        }
        // decay + causal mask -> Ss (wave-private rows: no barrier needed)
#pragma unroll
        for (int reg = 0; reg < 4; reg++) {
            int srow = srow0 + reg;
            int tc0 = jt*32 + l16, tc1 = tc0 + 16;
            float dbase = drun * gf[reg];               // γ^(srow - tc0)
            float d0 = (srow >= tc0) ? dbase : 0.f;
            float d1 = (srow >= tc1) ? dbase * gi16 : 0.f;
            Ss[wave*16 + quad*4 + reg][l16]      = f2b(s0[reg] * d0);
            Ss[wave*16 + quad*4 + reg][16 + l16] = f2b(s1[reg] * d1);
        }
        drun *= gi32;
        // PV: O[64x256] += S[64x32] @ V[32x256]
        short8 as = *(const short8*)&Ss[wave*16 + l16][quad*8];
#pragma unroll
        for (int nt = 0; nt < 16; nt++) {
            short8 bv = *(const short8*)&Vs[cur][nt*16 + l16][quad*8];
            oacc[nt] = __builtin_amdgcn_mfma_f32_16x16x32_bf16(as, bv, oacc[nt], 0, 0, 0);
        }
        __syncthreads();   // drains prefetch + guards buf reuse
    }

    // fused groupnorm + silu(G) gate, written in-place over G segment
#pragma unroll
    for (int reg = 0; reg < 4; reg++) {
        float s = 0.f, q = 0.f;
#pragma unroll
        for (int nt = 0; nt < 16; nt++) { float v = oacc[nt][reg]; s += v; q += v*v; }
#pragma unroll
        for (int m = 1; m < 16; m <<= 1) { s += __shfl_xor(s, m, 16); q += __shfl_xor(q, m, 16); }
        float mean = s * (1.f/256.f);
        float var  = q * (1.f/256.f) - mean*mean;
        float rstd = rsqrtf(var + 1e-5f);
        int srow = srow0 + reg;
        u16* grow = Gseg + (long)srow * 6144;
#pragma unroll
        for (int nt = 0; nt < 16; nt++) {
            float gval = b2f(grow[nt*16 + l16]);
            float y = (oacc[nt][reg] - mean) * rstd * gw[nt] + gbv[nt];
            float sg = gval / (1.f + exp2f(-1.4426950408889634f * gval));
            grow[nt*16 + l16] = f2b(sg * y);
        }
    }
}

extern "C" void kernel_launch(void* const* d_in, const int* in_sizes, int n_in,
                              void* d_out, int out_size, void* d_ws, size_t ws_size,
                              hipStream_t stream) {
    (void)in_sizes; (void)n_in; (void)out_size; (void)ws_size;
    const float* X    = (const float*)d_in[0];
    const float* Wq   = (const float*)d_in[1];
    const float* Wk   = (const float*)d_in[2];
    const float* Wv   = (const float*)d_in[3];
    const float* WG   = (const float*)d_in[4];
    const float* WO   = (const float*)d_in[5];
    const float* gnw  = (const float*)d_in[6];
    const float* gnb  = (const float*)d_in[7];
    const float* ln1w = (const float*)d_in[8];
    const float* ln1b = (const float*)d_in[9];
    const float* ln2w = (const float*)d_in[10];
    const float* ln2b = (const float*)d_in[11];
    const float* fw1  = (const float*)d_in[12];
    const float* fb1  = (const float*)d_in[13];
    const float* fw2  = (const float*)d_in[14];
    const float* fb2  = (const float*)d_in[15];

    constexpr int D = 1024, FFN = 4096;
    constexpr int M = 4096; // B*S rows
    constexpr long MB = 1048576;

    char* ws = (char*)d_ws;
    // weights (persistent until consumed):
    u16* WT   = (u16*)(ws + 0*MB);    // QKVG combined (6144,1024)  12 MB [..QKVG gemm]
    u16* WOT  = (u16*)(ws + 12*MB);   // (1024, 2048)                4 MB [..WO]
    u16* fw1T = (u16*)(ws + 16*MB);   // (4096, 1024)                8 MB [..FFN1]
    u16* fw2T = (u16*)(ws + 24*MB);   // (1024, 4096)                8 MB [..FFN2]
    // activations:
    u16*   QKVG = (u16*)(ws + 32*MB); // bf16 (B,S,6144) 48 MB [QKVG gemm .. WO]
                                      //   V segment row-major unused (V goes straight to Vt);
                                      //   WO parks fp32 partials in Q/K/V seg bytes of each row
    u16*   Xn   = (u16*)(ws + 80*MB); // bf16 (B,S,D)     8 MB [prep .. QKVG gemm]
    float4* xtab= (float4*)(ws + 88*MB);// fp32 table     2 MB [prep .. QKVG gemm]
    u16*   Vt   = (u16*)(ws + 90*MB); // bf16 (B,H,256,S)16 MB [QKVG gemm .. retention]
    float* X2   = (float*)(ws + 80*MB);//fp32 (B,S,D)    16 MB [ln2_combine .. ffn2_combine] (reuses Xn+xtab+Vt head)
    u16*   hb   = (u16*)(ws + 0*MB);  // bf16 (B,S,D)     8 MB [ln2_combine .. FFN1] (reuses WT)
    u16*   mid  = (u16*)(ws + 32*MB); // bf16 (B,S,FFN)  32 MB [FFN1 .. FFN2]        (reuses QKVG)
    float* PF   = (float*)(ws + 0*MB);// FFN2 partials: P0 [0,16), P1 [64,80) MB

    // 1. fused prep: 7x weight transpose + xPos table + LN1
    prep_k<<<20992, 256, 0, stream>>>(Wq, Wk, Wv, WG, WO, fw1, fw2, X, ln1w, ln1b,
                                      WT, WOT, fw1T, fw2T, xtab, Xn);
    // 2. fused QKVG projection + xPos epilogue; V blocks stored transposed into Vt [BK=32]
    mgemm<EPI_QKVG, 1><<<1536, 256, 0, stream>>>(
        Xn, WT, QKVG, D, D, 6144, (const float*)xtab, Vt);
    // 3. retention + groupnorm + silu-gate -> in-place on G segment
    retention_mfma<<<512, 256, 0, stream>>>(QKVG, Vt, gnw, gnb);
    // 4. WO split-K x2: partials into dead Q/K/V segment bytes of QKVG rows  [BK=64]
    mgemm_sk<<<512, 256, 0, stream>>>(
        QKVG + 4096, WOT, (float*)QKVG, 2048, 1024, 6144, 3072, 1024);
    // 5. combine + residual + LN2 -> X2 (fp32) and hb (bf16)
    ln2_combine<<<M, 256, 0, stream>>>((const float*)QKVG, X, ln2w, ln2b, X2, hb);
    // 6. mid = gelu_fast(hb @ W1 + b1)  bf16  [BK=64]
    mgemm<EPI_GELU_BIAS, 2><<<1024, 256, 0, stream>>>(
        hb, fw1T, mid, D, D, FFN, fb1, nullptr);
    // 7. FFN2 split-K x2: partials P0 [0,16), P1 [64,80) MB  [BK=64]
    mgemm_sk<<<512, 256, 0, stream>>>(
        mid, fw2T, PF, 4096, 2048, 4096, 1024, 16777216);
    // 8. combine + bias + X2 residual -> d_out (fp32)
    ffn2_combine<<<M, 256, 0, stream>>>(PF, fb2, X2, (float*)d_out);
}